// Round 11
// baseline (284.556 us; speedup 1.0000x reference)
//
#include <hip/hip_runtime.h>
#include <hip/hip_bf16.h>
#include <hip/hip_fp16.h>

#define N_NODES 20000
#define N_EDGES 640000
#define N_GRAPHS 256
#define NBUCK 313                    // ceil(20000/64) buckets of 64 dsts
#define NBP 320                      // padded bucket stride (histogram arrays)
#define NA 160                       // binA blocks per branch
#define NC 160                       // binC blocks per branch
#define EPC 4000                     // edges per binC block (160*4000 = 640000)
#define DCAP 2560                    // binD LDS record capacity
#define CURP 16                      // bcur padding: 16 ints = 64B per bucket

typedef short bf16v __attribute__((ext_vector_type(8)));   // 8 bf16 (4 VGPRs)
typedef float f32x4 __attribute__((ext_vector_type(4)));
typedef float f32x2 __attribute__((ext_vector_type(2)));

__device__ __forceinline__ float leaky02(float x){ return x > 0.f ? x : 0.2f*x; }
__device__ __forceinline__ float eluf(float x){ return x > 0.f ? x : (__expf(x) - 1.f); }
__device__ __forceinline__ unsigned short f2bf(float x){
  __hip_bfloat16 t = __float2bfloat16(x);
  return *reinterpret_cast<unsigned short*>(&t);
}
__device__ __forceinline__ unsigned short f2h(float x){
  __half t = __float2half(x);
  return *reinterpret_cast<unsigned short*>(&t);
}
__device__ __forceinline__ float f16hi(unsigned u){
  unsigned short s = (unsigned short)(u >> 16);
  return __half2float(*reinterpret_cast<__half*>(&s));
}
__device__ __forceinline__ float bflo(unsigned int u){ return __uint_as_float(u << 16); }
__device__ __forceinline__ float bfhi(unsigned int u){ return __uint_as_float(u & 0xffff0000u); }
__device__ __forceinline__ void pkfma(f32x2& acc, f32x2 a, f32x2 b){
  asm volatile("v_pk_fma_f32 %0, %1, %2, %0" : "+v"(acc) : "v"(a), "v"(b));
}

// ---------- scalar prep: c_l = dot(We_l, ae_l) ----------
__global__ void prep_c_kernel(const float* __restrict__ We1, const float* __restrict__ ae1,
                              const float* __restrict__ We2, const float* __restrict__ ae2,
                              const float* __restrict__ We3, const float* __restrict__ ae3,
                              float* __restrict__ scal){
  int tid = threadIdx.x;
  int wv = tid >> 6, lane = tid & 63;
  if (wv < 3){
    const float* We = wv==0 ? We1 : (wv==1 ? We2 : We3);
    const float* ae = wv==0 ? ae1 : (wv==1 ? ae2 : ae3);
    int F = (wv==2) ? 64 : 128;
    float s = 0.f;
    for (int i = lane; i < F; i += 64) s += We[i]*ae[i];
    for (int o = 32; o; o >>= 1) s += __shfl_down(s, o);
    if (lane == 0) scal[2+wv] = s;
  }
}

// ---------- binA: bucket histogram + ec partial sums ----------
__global__ __launch_bounds__(256) void binA_kernel(
    const int* __restrict__ ei0, const int* __restrict__ ei1,
    const float* __restrict__ ec0, const float* __restrict__ ec1,
    int* __restrict__ gcount, float* __restrict__ part)
{
  int b = blockIdx.y;
  const int* dstp = (b ? ei1 : ei0) + N_EDGES;
  const float* ec = b ? ec1 : ec0;
  __shared__ int hist[NBUCK];
  int tid = threadIdx.x;
  for (int j = tid; j < NBUCK; j += 256) hist[j] = 0;
  __syncthreads();
  float v = 0.f;
  for (int i = blockIdx.x*256 + tid; i < N_EDGES; i += NA*256){
    atomicAdd(&hist[dstp[i] >> 6], 1);
    v += ec[i];
  }
  __syncthreads();
  for (int j = tid; j < NBUCK; j += 256)
    if (hist[j]) atomicAdd(&gcount[b*NBP + j], hist[j]);
  for (int o = 32; o; o >>= 1) v += __shfl_down(v, o);
  __shared__ float wr[4];
  int lane = tid & 63, wv = tid >> 6;
  if (lane == 0) wr[wv] = v;
  __syncthreads();
  if (tid == 0) part[b*NA + blockIdx.x] = wr[0]+wr[1]+wr[2]+wr[3];
}

// ---------- binB: compact bucket scan + bcur init + ec total + graph bounds ----------
__global__ __launch_bounds__(512) void binB_kernel(
    const int* __restrict__ gcount, const float* __restrict__ part,
    const int* __restrict__ bat0, const int* __restrict__ bat1,
    int* __restrict__ bcur, int* __restrict__ cbase,
    int* __restrict__ gb, float* __restrict__ scal, int* __restrict__ rowp)
{
  int b = blockIdx.x;
  int tid = threadIdx.x;
  {
    float s = 0.f;
    for (int i = tid; i < NA; i += 512) s += part[b*NA + i];
    for (int o = 32; o; o >>= 1) s += __shfl_down(s, o);
    __shared__ float fr[8];
    if ((tid & 63) == 0) fr[tid >> 6] = s;
    __syncthreads();
    if (tid == 0){
      float t = 0.f;
      for (int i = 0; i < 8; ++i) t += fr[i];
      scal[b] = t;
    }
  }
  {
    const int* batch = b ? bat1 : bat0;
    int* gbb = gb + b*257;
    if (tid <= N_GRAPHS){
      int g = tid, lo = 0, hi = N_NODES;
      while (lo < hi){ int mid = (lo+hi) >> 1; if (batch[mid] < g) lo = mid+1; else hi = mid; }
      gbb[g] = lo;
    }
  }
  __shared__ int sc[512];
  int sz = (tid < NBUCK) ? gcount[b*NBP + tid] : 0;
  sc[tid] = sz;
  __syncthreads();
  for (int d = 1; d < 512; d <<= 1){
    int a2 = (tid >= d) ? sc[tid-d] : 0;
    __syncthreads();
    sc[tid] += a2;
    __syncthreads();
  }
  if (tid < NBUCK){
    int ecx = sc[tid] - sz;
    cbase[b*NBP + tid] = ecx;
    bcur[(b*NBUCK + tid)*CURP] = ecx;
  }
  if (tid == 0) rowp[b*(N_NODES+1) + N_NODES] = N_EDGES;
}

// ---------- binC: histogram-then-place LDS binning ----------
__global__ __launch_bounds__(256) void binC_kernel(
    const int* __restrict__ ei0, const int* __restrict__ ei1,
    const float* __restrict__ ec0, const float* __restrict__ ec1,
    int* __restrict__ bcur, uint2* __restrict__ stage)
{
  int b = blockIdx.y;
  const int* srcp = (b ? ei1 : ei0);
  const int* dstp = srcp + N_EDGES;
  const float* ec = b ? ec1 : ec0;
  int* bcurb = bcur + (size_t)b*NBUCK*CURP;
  uint2* stageb = stage + (size_t)b*N_EDGES;
  __shared__ uint2 recs[EPC];
  __shared__ int hist[NBUCK], rbase[NBUCK], rcur[NBUCK];
  int tid = threadIdx.x;
  for (int j = tid; j < NBUCK; j += 256){ hist[j] = 0; rcur[j] = 0; }
  __syncthreads();
  int e0 = blockIdx.x*EPC;
  for (int r = tid; r < EPC; r += 256){
    int i = e0 + r;
    int d = dstp[i];
    int bk = d >> 6;
    uint2 rec;
    rec.x = (unsigned)srcp[i] | ((unsigned)(d & 63) << 16);
    rec.y = ((unsigned)f2h(ec[i]) << 16) | (unsigned)bk;
    recs[r] = rec;
    atomicAdd(&hist[bk], 1);
  }
  __syncthreads();
  for (int j = tid; j < NBUCK; j += 256){
    int h = hist[j];
    rbase[j] = h ? atomicAdd(&bcurb[j*CURP], h) : 0;
  }
  __syncthreads();
  for (int r = tid; r < EPC; r += 256){
    uint2 rc = recs[r];
    int bk = (int)(rc.y & 0xFFFFu);
    int p = rbase[bk] + atomicAdd(&rcur[bk], 1);
    stageb[p] = rc;
  }
}

// ---------- binD: per-bucket counting sort -> compact CSR + rowp ----------
__global__ __launch_bounds__(256) void binD_kernel(
    const uint2* __restrict__ stage, const int* __restrict__ gcount,
    const int* __restrict__ cbase,
    unsigned* __restrict__ final_, int* __restrict__ rowp)
{
  int b = blockIdx.y;
  int g = blockIdx.x;
  int tid = threadIdx.x;
  const uint2* stageb = stage + (size_t)b*N_EDGES;
  unsigned* finb = final_ + (size_t)b*N_EDGES;
  int* rowb = rowp + b*(N_NODES+1);
  int n = min(gcount[b*NBP + g], DCAP);
  int cb = cbase[b*NBP + g];
  __shared__ uint2 recs[DCAP];
  __shared__ int cnt64[64], cur64[64], off64[64];
  if (tid < 64) cnt64[tid] = 0;
  __syncthreads();
  for (int r = tid; r < n; r += 256){
    uint2 rc = stageb[cb + r];
    recs[r] = rc;
    atomicAdd(&cnt64[(rc.x >> 16) & 63], 1);
  }
  __syncthreads();
  if (tid == 0){
    int acc = 0;
    for (int dl = 0; dl < 64; ++dl){
      off64[dl] = acc; cur64[dl] = acc; acc += cnt64[dl];
    }
  }
  __syncthreads();
  int nd = min(64, N_NODES - g*64);
  if (tid < nd) rowb[g*64 + tid] = cb + off64[tid];
  for (int r = tid; r < n; r += 256){
    uint2 rc = recs[r];
    int dl = (rc.x >> 16) & 63;
    int p = atomicAdd(&cur64[dl], 1);
    finb[cb + p] = (rc.y & 0xFFFF0000u) | (rc.x & 0xFFFFu);
  }
}

// ---------- layer 1: K=7 scalar GEMM + att dots, bf16 halves out ----------
template<int K, int F>
__global__ __launch_bounds__(256) void node_linear1_kernel(
    const float* __restrict__ x0, const float* __restrict__ x1,
    const float* __restrict__ W,
    const float* __restrict__ atts, const float* __restrict__ attd,
    unsigned short* __restrict__ loAll, unsigned short* __restrict__ hiAll,
    float* __restrict__ aSAll, float* __restrict__ aDAll)
{
  int b = blockIdx.y;
  const float* x = b ? x1 : x0;
  unsigned short* lo = loAll + (size_t)b*N_NODES*64;
  unsigned short* hi = hiAll + (size_t)b*N_NODES*64;
  float* a_s = aSAll + b*N_NODES;
  float* a_d = aDAll + b*N_NODES;
  constexpr int ROWS = 256 / F; // 2
  __shared__ float Wl[K*F];
  __shared__ float xl[ROWS*K];
  __shared__ float swv[4], dwv[4];
  int tid = threadIdx.x;
  for (int i = tid; i < K*F; i += 256) Wl[i] = W[i];
  int f = tid % F;
  int lr = tid / F;
  float vs = atts[f], vd = attd[f];
  const int ntiles = (N_NODES + ROWS - 1)/ROWS;
  for (int t = blockIdx.x; t < ntiles; t += gridDim.x){
    int r0 = t*ROWS;
    __syncthreads();
    for (int i = tid; i < ROWS*K; i += 256){
      int r = i / K, k = i % K;
      int row = r0 + r;
      xl[i] = (row < N_NODES) ? x[row*K + k] : 0.f;
    }
    __syncthreads();
    float acc = 0.f;
    #pragma unroll
    for (int k = 0; k < K; ++k) acc += xl[lr*K + k] * Wl[k*F + f];
    int row = r0 + lr;
    if (row < N_NODES){
      if (f < 64) lo[(size_t)row*64 + f] = f2bf(acc);
      else        hi[(size_t)row*64 + f - 64] = f2bf(acc);
    }
    float s = acc*vs, d = acc*vd;
    #pragma unroll
    for (int o = 32; o; o >>= 1){ s += __shfl_down(s, o); d += __shfl_down(d, o); }
    int wv = tid >> 6;
    if ((tid & 63) == 0){ swv[wv] = s; dwv[wv] = d; }
    __syncthreads();
    if (f == 0 && row < N_NODES){
      a_s[row] = swv[2*lr] + swv[2*lr+1];
      a_d[row] = dwv[2*lr] + dwv[2*lr+1];
    }
  }
}

// ---------- layers 2/3: MFMA GEMM on half tables, fused att dots ----------
template<int F>
__global__ __launch_bounds__(256) void gemm_mfma_kernel(
    const unsigned short* __restrict__ AloAll, const unsigned short* __restrict__ AhiAll,
    const float* __restrict__ W,
    const float* __restrict__ atts, const float* __restrict__ attd,
    unsigned short* __restrict__ OloAll, unsigned short* __restrict__ OhiAll,
    float* __restrict__ aSAll, float* __restrict__ aDAll)
{
  int b = blockIdx.y;
  const unsigned short* Alo = AloAll + (size_t)b*N_NODES*64;
  const unsigned short* Ahi = AhiAll + (size_t)b*N_NODES*64;
  unsigned short* Olo = OloAll + (size_t)b*N_NODES*64;
  unsigned short* Ohi = (F == 128) ? (OhiAll + (size_t)b*N_NODES*64) : nullptr;
  float* a_s = aSAll + b*N_NODES;
  float* a_d = aDAll + b*N_NODES;
  constexpr int NT = F/16;
  constexpr int KP = 136;
  __shared__ unsigned short Wb[F*KP];
  int tid = threadIdx.x;
  for (int idx = tid; idx < 128*F; idx += 256){
    int k = idx / F, col = idx % F;
    Wb[col*KP + k] = f2bf(W[idx]);
  }
  __syncthreads();
  int wave = tid >> 6, lane = tid & 63;
  int r0w = blockIdx.x*64 + wave*16;
  int arow = r0w + (lane & 15);
  bool av = arow < N_NODES;
  f32x4 acc[NT];
  #pragma unroll
  for (int nt = 0; nt < NT; ++nt) acc[nt] = 0.f;
  #pragma unroll
  for (int step = 0; step < 4; ++step){
    int kbase = step*32 + (lane>>4)*8;            // B index, 0..127
    int kb    = (step & 1)*32 + (lane>>4)*8;      // A index within half
    const unsigned short* As = (step < 2) ? Alo : Ahi;
    uint4 araw = av ? *reinterpret_cast<const uint4*>(&As[(size_t)arow*64 + kb])
                    : make_uint4(0,0,0,0);
    bf16v af = __builtin_bit_cast(bf16v, araw);
    #pragma unroll
    for (int nt = 0; nt < NT; ++nt){
      uint4 braw = *reinterpret_cast<const uint4*>(&Wb[(nt*16 + (lane&15))*KP + kbase]);
      bf16v bfr = __builtin_bit_cast(bf16v, braw);
      acc[nt] = __builtin_amdgcn_mfma_f32_16x16x32_bf16(af, bfr, acc[nt], 0, 0, 0);
    }
  }
  float ps[4] = {0,0,0,0}, pd[4] = {0,0,0,0};
  #pragma unroll
  for (int nt = 0; nt < NT; ++nt){
    int col = nt*16 + (lane&15);
    float vs = atts[col], vd = attd[col];
    unsigned short* O = (F == 64 || nt < 4) ? Olo : Ohi;
    int co = (F == 64 || nt < 4) ? col : col - 64;
    #pragma unroll
    for (int reg = 0; reg < 4; ++reg){
      int row = r0w + (lane>>4)*4 + reg;
      float v = acc[nt][reg];
      if (row < N_NODES) O[(size_t)row*64 + co] = f2bf(v);
      ps[reg] += v*vs;
      pd[reg] += v*vd;
    }
  }
  #pragma unroll
  for (int reg = 0; reg < 4; ++reg){
    float s = ps[reg], d = pd[reg];
    #pragma unroll
    for (int o = 1; o < 16; o <<= 1){ s += __shfl_xor(s, o); d += __shfl_xor(d, o); }
    int row = r0w + (lane>>4)*4 + reg;
    if ((lane & 15) == 0 && row < N_NODES){ a_s[row] = s; a_d[row] = d; }
  }
}

// ---------- alpha: per-dst softmax weights materialized as f16 ----------
__global__ __launch_bounds__(256) void alpha_kernel(
    const float* __restrict__ aSAll, const float* __restrict__ aDAll,
    const unsigned* __restrict__ edgAll, const int* __restrict__ rowpAll,
    const float* __restrict__ scal, int l,
    float* __restrict__ ptmpAll, unsigned* __restrict__ arecAll,
    float* __restrict__ aSelfAll)
{
  int b = blockIdx.y;
  const float* a_s = aSAll + b*N_NODES;
  const float* a_d = aDAll + b*N_NODES;
  const unsigned* edges = edgAll + (size_t)b*N_EDGES;
  const int* rowp = rowpAll + b*(N_NODES+1);
  float* ptmp = ptmpAll + (size_t)b*N_EDGES;
  unsigned* arec = arecAll + (size_t)b*N_EDGES;
  int wv = threadIdx.x >> 6, lane = threadIdx.x & 63;
  int d = blockIdx.x*4 + wv;
  if (d >= N_NODES) return;
  float c = scal[2+l];
  float ae_self = (scal[b] * (1.0f/N_EDGES)) * c;
  float add_ = a_d[d];
  float p_self = __expf(fminf(leaky02(a_s[d] + add_ + ae_self), 60.f));
  float denom = p_self;
  int e0 = rowp[d], e1 = rowp[d+1];
  for (int ch = e0; ch < e1; ch += 64){
    int n = min(64, e1 - ch);
    float p = 0.f;
    if (lane < n){
      unsigned e = edges[ch + lane];
      p = __expf(fminf(leaky02(a_s[e & 0xFFFFu] + add_ + c*f16hi(e)), 60.f));
      ptmp[ch + lane] = p;
    }
    float ds = p;
    #pragma unroll
    for (int o = 32; o; o >>= 1) ds += __shfl_xor(ds, o);
    denom += ds;
  }
  float inv = 1.0f/denom;
  if (lane == 0) aSelfAll[b*N_NODES + d] = p_self*inv;
  for (int i = e0 + lane; i < e1; i += 64){
    unsigned e = edges[i];
    arec[i] = (e & 0xFFFFu) | ((unsigned)f2h(ptmp[i]*inv) << 16);
  }
}

// ---------- gather: pre-normalized weighted gather over one 64-feature half ----------
// 8 lanes/edge x 16B, 8 edges/iter; table 2.56MB -> per-XCD L2 resident.
template<bool W32>
__global__ __launch_bounds__(256) void gather_kernel(
    const unsigned short* __restrict__ tabAll,
    const unsigned* __restrict__ arecAll, const int* __restrict__ rowpAll,
    const float* __restrict__ aSelfAll, const float* __restrict__ bias,
    float* __restrict__ out32All, unsigned short* __restrict__ outbAll)
{
  int b = blockIdx.y;
  const unsigned short* tab = tabAll + (size_t)b*N_NODES*64;
  const unsigned* arec = arecAll + (size_t)b*N_EDGES;
  const int* rowp = rowpAll + b*(N_NODES+1);
  __shared__ uint2 sp[4][72];
  int wv = threadIdx.x >> 6, lane = threadIdx.x & 63;
  int d = blockIdx.x*4 + wv;
  if (d >= N_NODES) return;
  int sub = lane & 7, grp = lane >> 3;   // 8 feats/lane, 8 edges/iter
  if (lane < 8) sp[wv][64 + lane] = make_uint2(0u, 0u);   // zero tail slots
  float aself = aSelfAll[b*N_NODES + d];
  f32x2 acc[4];
  #pragma unroll
  for (int i = 0; i < 4; ++i) acc[i] = (f32x2){0.f, 0.f};
  if (grp == 0){
    uint4 q = *reinterpret_cast<const uint4*>(&tab[(size_t)d*64 + 8*sub]);
    f32x2 aa = {aself, aself};
    pkfma(acc[0], (f32x2){bflo(q.x), bfhi(q.x)}, aa);
    pkfma(acc[1], (f32x2){bflo(q.y), bfhi(q.y)}, aa);
    pkfma(acc[2], (f32x2){bflo(q.z), bfhi(q.z)}, aa);
    pkfma(acc[3], (f32x2){bflo(q.w), bfhi(q.w)}, aa);
  }
  int e0 = rowp[d], e1 = rowp[d+1];
  for (int ch = e0; ch < e1; ch += 64){
    int n = min(64, e1 - ch);
    unsigned s0 = 0; float a0 = 0.f;
    if (lane < n){
      unsigned e = arec[ch + lane];
      s0 = e & 0xFFFFu;
      a0 = f16hi(e);
    }
    sp[wv][lane] = make_uint2(s0, __float_as_uint(a0));
    int niter = (n + 7) >> 3;
    #pragma unroll 4
    for (int k = 0; k < niter; ++k){
      uint2 r = sp[wv][8*k + grp];      // tail: zeroed slots (a=0, src=0)
      float a = __uint_as_float(r.y);
      f32x2 aa = {a, a};
      uint4 q = *reinterpret_cast<const uint4*>(&tab[(size_t)r.x*64 + 8*sub]);
      pkfma(acc[0], (f32x2){bflo(q.x), bfhi(q.x)}, aa);
      pkfma(acc[1], (f32x2){bflo(q.y), bfhi(q.y)}, aa);
      pkfma(acc[2], (f32x2){bflo(q.z), bfhi(q.z)}, aa);
      pkfma(acc[3], (f32x2){bflo(q.w), bfhi(q.w)}, aa);
    }
  }
  float vv[8];
  #pragma unroll
  for (int i = 0; i < 4; ++i){
    float v0 = acc[i].x, v1 = acc[i].y;
    v0 += __shfl_xor(v0, 8); v0 += __shfl_xor(v0, 16); v0 += __shfl_xor(v0, 32);
    v1 += __shfl_xor(v1, 8); v1 += __shfl_xor(v1, 16); v1 += __shfl_xor(v1, 32);
    vv[2*i]   = eluf(v0 + bias[8*sub + 2*i]);
    vv[2*i+1] = eluf(v1 + bias[8*sub + 2*i+1]);
  }
  if (grp == 0){
    if (W32){
      float* o = out32All + (size_t)b*N_NODES*64;
      *reinterpret_cast<float4*>(&o[(size_t)d*64 + 8*sub])     = make_float4(vv[0],vv[1],vv[2],vv[3]);
      *reinterpret_cast<float4*>(&o[(size_t)d*64 + 8*sub + 4]) = make_float4(vv[4],vv[5],vv[6],vv[7]);
    } else {
      unsigned short* o = outbAll + (size_t)b*N_NODES*64;
      uint4 w;
      w.x = (unsigned)f2bf(vv[0]) | ((unsigned)f2bf(vv[1]) << 16);
      w.y = (unsigned)f2bf(vv[2]) | ((unsigned)f2bf(vv[3]) << 16);
      w.z = (unsigned)f2bf(vv[4]) | ((unsigned)f2bf(vv[5]) << 16);
      w.w = (unsigned)f2bf(vv[6]) | ((unsigned)f2bf(vv[7]) << 16);
      *reinterpret_cast<uint4*>(&o[(size_t)d*64 + 8*sub]) = w;
    }
  }
}

// ---------- fused mean-pool + final linear ----------
__global__ __launch_bounds__(256) void pool_final_kernel(
    const float* __restrict__ buf0, const int* __restrict__ gb,
    const float* __restrict__ xn0, const float* __restrict__ xn1,
    const float* __restrict__ linW, const float* __restrict__ linb,
    float* __restrict__ out)
{
  int bg = blockIdx.x;
  int b = bg >> 8, g = bg & 255;
  __shared__ float Wl[80*64];
  __shared__ float red[4][64];
  __shared__ float mf[64];
  int tid = threadIdx.x;
  for (int i = tid; i < 80*64; i += 256) Wl[i] = linW[i];
  const float* x = buf0 + (size_t)b*N_NODES*64;
  const int* gbb = gb + b*257;
  int s = gbb[g], e = gbb[g+1];
  int f = tid & 63, rg = tid >> 6;
  float acc = 0.f;
  for (int r = s + rg; r < e; r += 4) acc += x[r*64 + f];
  red[rg][f] = acc;
  __syncthreads();
  if (rg == 0)
    mf[f] = (red[0][f]+red[1][f]+red[2][f]+red[3][f]) / fmaxf((float)(e - s), 1.0f);
  __syncthreads();
  if (tid < 64){
    int j = tid;
    const float* xn = b ? xn1 : xn0;
    float a2 = linb[j];
    #pragma unroll 8
    for (int k = 0; k < 64; ++k) a2 += mf[k] * Wl[k*64 + j];
    #pragma unroll
    for (int k = 0; k < 16; ++k) a2 += xn[g*16+k] * Wl[(64+k)*64 + j];
    out[(size_t)(b*N_GRAPHS + g)*64 + j] = a2;
  }
}

extern "C" void kernel_launch(void* const* d_in, const int* in_sizes, int n_in,
                              void* d_out, int out_size, void* d_ws, size_t ws_size,
                              hipStream_t stream)
{
  const float* x1   = (const float*)d_in[0];
  const float* x2   = (const float*)d_in[1];
  const int*   ei1  = (const int*)d_in[2];
  const int*   ei2  = (const int*)d_in[3];
  const int*   bat1 = (const int*)d_in[4];
  const int*   bat2 = (const int*)d_in[5];
  const float* xn1  = (const float*)d_in[6];
  const float* xn2  = (const float*)d_in[7];
  const float* ec1  = (const float*)d_in[8];
  const float* ec2  = (const float*)d_in[9];
  const float* W[3]   = {(const float*)d_in[10], (const float*)d_in[16], (const float*)d_in[22]};
  const float* as_[3] = {(const float*)d_in[11], (const float*)d_in[17], (const float*)d_in[23]};
  const float* ad_[3] = {(const float*)d_in[12], (const float*)d_in[18], (const float*)d_in[24]};
  const float* We[3]  = {(const float*)d_in[13], (const float*)d_in[19], (const float*)d_in[25]};
  const float* ae[3]  = {(const float*)d_in[14], (const float*)d_in[20], (const float*)d_in[26]};
  const float* bb[3]  = {(const float*)d_in[15], (const float*)d_in[21], (const float*)d_in[27]};
  const float* linW = (const float*)d_in[28];
  const float* linb = (const float*)d_in[29];
  float* out = (float*)d_out;

  char* ws = (char*)d_ws;
  size_t off = 0;
  auto alloc = [&](size_t bytes)->char*{
    char* p = ws + off;
    off = (off + bytes + 255) & ~(size_t)255;
    return p;
  };
  unsigned short* hbAlo = (unsigned short*)alloc((size_t)2*N_NODES*64*2);
  unsigned short* hbAhi = (unsigned short*)alloc((size_t)2*N_NODES*64*2);
  unsigned short* hbBlo = (unsigned short*)alloc((size_t)2*N_NODES*64*2);
  unsigned short* hbBhi = (unsigned short*)alloc((size_t)2*N_NODES*64*2);
  float* buf0 = (float*)alloc((size_t)2*N_NODES*64*4);
  float* aS    = (float*)alloc((size_t)2*N_NODES*4);
  float* aD    = (float*)alloc((size_t)2*N_NODES*4);
  float* aSelf = (float*)alloc((size_t)2*N_NODES*4);
  int* gcount = (int*)alloc((size_t)2*NBP*4);
  int* bcur   = (int*)alloc((size_t)2*NBUCK*CURP*4);
  int* cbase  = (int*)alloc((size_t)2*NBP*4);
  int* rowp   = (int*)alloc((size_t)2*(N_NODES+1)*4);
  uint2* stage = (uint2*)alloc((size_t)2*N_EDGES*8);   // reused as arec+ptmp after binD
  unsigned* final_ = (unsigned*)alloc((size_t)2*N_EDGES*4);
  float* part = (float*)alloc((size_t)2*NA*4);
  int* gb     = (int*)alloc((size_t)2*257*4);
  float* scal = (float*)alloc(64);

  // aliases (stage is dead after binD)
  unsigned* arec = (unsigned*)stage;                              // 2*E*4
  float*    ptmp = (float*)((char*)stage + (size_t)2*N_EDGES*4);  // 2*E*4

  hipMemsetAsync(gcount, 0, (size_t)2*NBP*4, stream);
  prep_c_kernel<<<1, 256, 0, stream>>>(We[0], ae[0], We[1], ae[1], We[2], ae[2], scal);
  binA_kernel<<<dim3(NA,2), 256, 0, stream>>>(ei1, ei2, ec1, ec2, gcount, part);
  binB_kernel<<<2, 512, 0, stream>>>(gcount, part, bat1, bat2, bcur, cbase, gb, scal, rowp);
  binC_kernel<<<dim3(NC,2), 256, 0, stream>>>(ei1, ei2, ec1, ec2, bcur, stage);
  binD_kernel<<<dim3(NBUCK,2), 256, 0, stream>>>(stage, gcount, cbase, final_, rowp);

  const int GAG = N_NODES/4;  // 5000

  // layer 1
  node_linear1_kernel<7,128><<<dim3(1024,2), 256, 0, stream>>>(
      x1, x2, W[0], as_[0], ad_[0], hbAlo, hbAhi, aS, aD);
  alpha_kernel<<<dim3(GAG,2), 256, 0, stream>>>(aS, aD, final_, rowp, scal, 0, ptmp, arec, aSelf);
  gather_kernel<false><<<dim3(GAG,2), 256, 0, stream>>>(hbAlo, arec, rowp, aSelf, bb[0],      nullptr, hbBlo);
  gather_kernel<false><<<dim3(GAG,2), 256, 0, stream>>>(hbAhi, arec, rowp, aSelf, bb[0]+64,   nullptr, hbBhi);

  // layer 2
  gemm_mfma_kernel<128><<<dim3((N_NODES+63)/64,2), 256, 0, stream>>>(
      hbBlo, hbBhi, W[1], as_[1], ad_[1], hbAlo, hbAhi, aS, aD);
  alpha_kernel<<<dim3(GAG,2), 256, 0, stream>>>(aS, aD, final_, rowp, scal, 1, ptmp, arec, aSelf);
  gather_kernel<false><<<dim3(GAG,2), 256, 0, stream>>>(hbAlo, arec, rowp, aSelf, bb[1],      nullptr, hbBlo);
  gather_kernel<false><<<dim3(GAG,2), 256, 0, stream>>>(hbAhi, arec, rowp, aSelf, bb[1]+64,   nullptr, hbBhi);

  // layer 3 (F=64: single half)
  gemm_mfma_kernel<64><<<dim3((N_NODES+63)/64,2), 256, 0, stream>>>(
      hbBlo, hbBhi, W[2], as_[2], ad_[2], hbAlo, nullptr, aS, aD);
  alpha_kernel<<<dim3(GAG,2), 256, 0, stream>>>(aS, aD, final_, rowp, scal, 2, ptmp, arec, aSelf);
  gather_kernel<true><<<dim3(GAG,2), 256, 0, stream>>>(hbAlo, arec, rowp, aSelf, bb[2], buf0, nullptr);

  pool_final_kernel<<<2*N_GRAPHS, 256, 0, stream>>>(
      buf0, gb, xn1, xn2, linW, linb, out);
}

// Round 12
// 220.452 us; speedup vs baseline: 1.2908x; 1.2908x over previous
//
#include <hip/hip_runtime.h>
#include <hip/hip_bf16.h>
#include <hip/hip_fp16.h>

#define N_NODES 20000
#define N_EDGES 640000
#define N_GRAPHS 256
#define NBUCK 313                    // ceil(20000/64) buckets of 64 dsts
#define NBP 320                      // padded bucket stride (histogram arrays)
#define NA 160                       // binA blocks per branch
#define NC 160                       // binC blocks per branch
#define EPC 4000                     // edges per binC block (160*4000 = 640000)
#define DCAP 2560                    // binD LDS record capacity
#define CURP 16                      // bcur padding: 16 ints = 64B per bucket

typedef short bf16v __attribute__((ext_vector_type(8)));   // 8 bf16 (4 VGPRs)
typedef float f32x4 __attribute__((ext_vector_type(4)));
typedef float f32x2 __attribute__((ext_vector_type(2)));

__device__ __forceinline__ float leaky02(float x){ return x > 0.f ? x : 0.2f*x; }
__device__ __forceinline__ float eluf(float x){ return x > 0.f ? x : (__expf(x) - 1.f); }
__device__ __forceinline__ unsigned short f2bf(float x){
  __hip_bfloat16 t = __float2bfloat16(x);
  return *reinterpret_cast<unsigned short*>(&t);
}
__device__ __forceinline__ unsigned short f2h(float x){
  __half t = __float2half(x);
  return *reinterpret_cast<unsigned short*>(&t);
}
__device__ __forceinline__ float f16hi(unsigned u){
  unsigned short s = (unsigned short)(u >> 16);
  return __half2float(*reinterpret_cast<__half*>(&s));
}
__device__ __forceinline__ float bflo(unsigned int u){ return __uint_as_float(u << 16); }
__device__ __forceinline__ float bfhi(unsigned int u){ return __uint_as_float(u & 0xffff0000u); }
__device__ __forceinline__ void pkfma(f32x2& acc, f32x2 a, f32x2 b){
  asm volatile("v_pk_fma_f32 %0, %1, %2, %0" : "+v"(acc) : "v"(a), "v"(b));
}

// ---------- scalar prep: c_l = dot(We_l, ae_l) ----------
__global__ void prep_c_kernel(const float* __restrict__ We1, const float* __restrict__ ae1,
                              const float* __restrict__ We2, const float* __restrict__ ae2,
                              const float* __restrict__ We3, const float* __restrict__ ae3,
                              float* __restrict__ scal){
  int tid = threadIdx.x;
  int wv = tid >> 6, lane = tid & 63;
  if (wv < 3){
    const float* We = wv==0 ? We1 : (wv==1 ? We2 : We3);
    const float* ae = wv==0 ? ae1 : (wv==1 ? ae2 : ae3);
    int F = (wv==2) ? 64 : 128;
    float s = 0.f;
    for (int i = lane; i < F; i += 64) s += We[i]*ae[i];
    for (int o = 32; o; o >>= 1) s += __shfl_down(s, o);
    if (lane == 0) scal[2+wv] = s;
  }
}

// ---------- binA: bucket histogram + ec partial sums ----------
__global__ __launch_bounds__(256) void binA_kernel(
    const int* __restrict__ ei0, const int* __restrict__ ei1,
    const float* __restrict__ ec0, const float* __restrict__ ec1,
    int* __restrict__ gcount, float* __restrict__ part)
{
  int b = blockIdx.y;
  const int* dstp = (b ? ei1 : ei0) + N_EDGES;
  const float* ec = b ? ec1 : ec0;
  __shared__ int hist[NBUCK];
  int tid = threadIdx.x;
  for (int j = tid; j < NBUCK; j += 256) hist[j] = 0;
  __syncthreads();
  float v = 0.f;
  for (int i = blockIdx.x*256 + tid; i < N_EDGES; i += NA*256){
    atomicAdd(&hist[dstp[i] >> 6], 1);
    v += ec[i];
  }
  __syncthreads();
  for (int j = tid; j < NBUCK; j += 256)
    if (hist[j]) atomicAdd(&gcount[b*NBP + j], hist[j]);
  for (int o = 32; o; o >>= 1) v += __shfl_down(v, o);
  __shared__ float wr[4];
  int lane = tid & 63, wv = tid >> 6;
  if (lane == 0) wr[wv] = v;
  __syncthreads();
  if (tid == 0) part[b*NA + blockIdx.x] = wr[0]+wr[1]+wr[2]+wr[3];
}

// ---------- binB: compact bucket scan + bcur init + ec total + graph bounds ----------
__global__ __launch_bounds__(512) void binB_kernel(
    const int* __restrict__ gcount, const float* __restrict__ part,
    const int* __restrict__ bat0, const int* __restrict__ bat1,
    int* __restrict__ bcur, int* __restrict__ cbase,
    int* __restrict__ gb, float* __restrict__ scal, int* __restrict__ rowp)
{
  int b = blockIdx.x;
  int tid = threadIdx.x;
  {
    float s = 0.f;
    for (int i = tid; i < NA; i += 512) s += part[b*NA + i];
    for (int o = 32; o; o >>= 1) s += __shfl_down(s, o);
    __shared__ float fr[8];
    if ((tid & 63) == 0) fr[tid >> 6] = s;
    __syncthreads();
    if (tid == 0){
      float t = 0.f;
      for (int i = 0; i < 8; ++i) t += fr[i];
      scal[b] = t;
    }
  }
  {
    const int* batch = b ? bat1 : bat0;
    int* gbb = gb + b*257;
    if (tid <= N_GRAPHS){
      int g = tid, lo = 0, hi = N_NODES;
      while (lo < hi){ int mid = (lo+hi) >> 1; if (batch[mid] < g) lo = mid+1; else hi = mid; }
      gbb[g] = lo;
    }
  }
  __shared__ int sc[512];
  int sz = (tid < NBUCK) ? gcount[b*NBP + tid] : 0;
  sc[tid] = sz;
  __syncthreads();
  for (int d = 1; d < 512; d <<= 1){
    int a2 = (tid >= d) ? sc[tid-d] : 0;
    __syncthreads();
    sc[tid] += a2;
    __syncthreads();
  }
  if (tid < NBUCK){
    int ecx = sc[tid] - sz;
    cbase[b*NBP + tid] = ecx;
    bcur[(b*NBUCK + tid)*CURP] = ecx;
  }
  if (tid == 0) rowp[b*(N_NODES+1) + N_NODES] = N_EDGES;
}

// ---------- binC: histogram-then-place LDS binning ----------
__global__ __launch_bounds__(256) void binC_kernel(
    const int* __restrict__ ei0, const int* __restrict__ ei1,
    const float* __restrict__ ec0, const float* __restrict__ ec1,
    int* __restrict__ bcur, uint2* __restrict__ stage)
{
  int b = blockIdx.y;
  const int* srcp = (b ? ei1 : ei0);
  const int* dstp = srcp + N_EDGES;
  const float* ec = b ? ec1 : ec0;
  int* bcurb = bcur + (size_t)b*NBUCK*CURP;
  uint2* stageb = stage + (size_t)b*N_EDGES;
  __shared__ uint2 recs[EPC];
  __shared__ int hist[NBUCK], rbase[NBUCK], rcur[NBUCK];
  int tid = threadIdx.x;
  for (int j = tid; j < NBUCK; j += 256){ hist[j] = 0; rcur[j] = 0; }
  __syncthreads();
  int e0 = blockIdx.x*EPC;
  for (int r = tid; r < EPC; r += 256){
    int i = e0 + r;
    int d = dstp[i];
    int bk = d >> 6;
    uint2 rec;
    rec.x = (unsigned)srcp[i] | ((unsigned)(d & 63) << 16);
    rec.y = ((unsigned)f2bf(ec[i]) << 16) | (unsigned)bk;
    recs[r] = rec;
    atomicAdd(&hist[bk], 1);
  }
  __syncthreads();
  for (int j = tid; j < NBUCK; j += 256){
    int h = hist[j];
    rbase[j] = h ? atomicAdd(&bcurb[j*CURP], h) : 0;
  }
  __syncthreads();
  for (int r = tid; r < EPC; r += 256){
    uint2 rc = recs[r];
    int bk = (int)(rc.y & 0xFFFFu);
    int p = rbase[bk] + atomicAdd(&rcur[bk], 1);
    stageb[p] = rc;
  }
}

// ---------- binD: per-bucket counting sort -> compact CSR + rowp ----------
__global__ __launch_bounds__(256) void binD_kernel(
    const uint2* __restrict__ stage, const int* __restrict__ gcount,
    const int* __restrict__ cbase,
    unsigned* __restrict__ final_, int* __restrict__ rowp)
{
  int b = blockIdx.y;
  int g = blockIdx.x;
  int tid = threadIdx.x;
  const uint2* stageb = stage + (size_t)b*N_EDGES;
  unsigned* finb = final_ + (size_t)b*N_EDGES;
  int* rowb = rowp + b*(N_NODES+1);
  int n = min(gcount[b*NBP + g], DCAP);
  int cb = cbase[b*NBP + g];
  __shared__ uint2 recs[DCAP];
  __shared__ int cnt64[64], cur64[64], off64[64];
  if (tid < 64) cnt64[tid] = 0;
  __syncthreads();
  for (int r = tid; r < n; r += 256){
    uint2 rc = stageb[cb + r];
    recs[r] = rc;
    atomicAdd(&cnt64[(rc.x >> 16) & 63], 1);
  }
  __syncthreads();
  if (tid == 0){
    int acc = 0;
    for (int dl = 0; dl < 64; ++dl){
      off64[dl] = acc; cur64[dl] = acc; acc += cnt64[dl];
    }
  }
  __syncthreads();
  int nd = min(64, N_NODES - g*64);
  if (tid < nd) rowb[g*64 + tid] = cb + off64[tid];
  for (int r = tid; r < n; r += 256){
    uint2 rc = recs[r];
    int dl = (rc.x >> 16) & 63;
    int p = atomicAdd(&cur64[dl], 1);
    finb[cb + p] = (rc.y & 0xFFFF0000u) | (rc.x & 0xFFFFu);
  }
}

// ---------- layer 1: K=7 scalar GEMM + att dots, bf16 out, both branches ----------
template<int K, int F>
__global__ __launch_bounds__(256) void node_linear1_kernel(
    const float* __restrict__ x0, const float* __restrict__ x1,
    const float* __restrict__ W,
    const float* __restrict__ atts, const float* __restrict__ attd,
    unsigned short* __restrict__ hbAll, float* __restrict__ aSAll, float* __restrict__ aDAll)
{
  int b = blockIdx.y;
  const float* x = b ? x1 : x0;
  unsigned short* hb = hbAll + (size_t)b*N_NODES*128;
  float* a_s = aSAll + b*N_NODES;
  float* a_d = aDAll + b*N_NODES;
  constexpr int ROWS = 256 / F; // 2
  __shared__ float Wl[K*F];
  __shared__ float xl[ROWS*K];
  __shared__ float swv[4], dwv[4];
  int tid = threadIdx.x;
  for (int i = tid; i < K*F; i += 256) Wl[i] = W[i];
  int f = tid % F;
  int lr = tid / F;
  float vs = atts[f], vd = attd[f];
  const int ntiles = (N_NODES + ROWS - 1)/ROWS;
  for (int t = blockIdx.x; t < ntiles; t += gridDim.x){
    int r0 = t*ROWS;
    __syncthreads();
    for (int i = tid; i < ROWS*K; i += 256){
      int r = i / K, k = i % K;
      int row = r0 + r;
      xl[i] = (row < N_NODES) ? x[row*K + k] : 0.f;
    }
    __syncthreads();
    float acc = 0.f;
    #pragma unroll
    for (int k = 0; k < K; ++k) acc += xl[lr*K + k] * Wl[k*F + f];
    int row = r0 + lr;
    if (row < N_NODES) hb[row*F + f] = f2bf(acc);
    float s = acc*vs, d = acc*vd;
    #pragma unroll
    for (int o = 32; o; o >>= 1){ s += __shfl_down(s, o); d += __shfl_down(d, o); }
    int wv = tid >> 6;
    if ((tid & 63) == 0){ swv[wv] = s; dwv[wv] = d; }
    __syncthreads();
    if (f == 0 && row < N_NODES){
      a_s[row] = swv[2*lr] + swv[2*lr+1];
      a_d[row] = dwv[2*lr] + dwv[2*lr+1];
    }
  }
}

// ---------- layers 2/3: MFMA GEMM (A bf16 -> bf16 out), fused att dots ----------
template<int F>
__global__ __launch_bounds__(256) void gemm_mfma_kernel(
    const unsigned short* __restrict__ AAll, const float* __restrict__ W,
    const float* __restrict__ atts, const float* __restrict__ attd,
    unsigned short* __restrict__ hbAll, float* __restrict__ aSAll, float* __restrict__ aDAll)
{
  int b = blockIdx.y;
  const unsigned short* A = AAll + (size_t)b*N_NODES*128;
  unsigned short* hb = hbAll + (size_t)b*N_NODES*128;
  float* a_s = aSAll + b*N_NODES;
  float* a_d = aDAll + b*N_NODES;
  constexpr int NT = F/16;
  constexpr int KP = 136;
  __shared__ unsigned short Wb[F*KP];
  int tid = threadIdx.x;
  for (int idx = tid; idx < 128*F; idx += 256){
    int k = idx / F, col = idx % F;
    Wb[col*KP + k] = f2bf(W[idx]);
  }
  __syncthreads();
  int wave = tid >> 6, lane = tid & 63;
  int r0w = blockIdx.x*64 + wave*16;
  int arow = r0w + (lane & 15);
  bool av = arow < N_NODES;
  f32x4 acc[NT];
  #pragma unroll
  for (int nt = 0; nt < NT; ++nt) acc[nt] = 0.f;
  #pragma unroll
  for (int step = 0; step < 4; ++step){
    int kbase = step*32 + (lane>>4)*8;
    uint4 araw = av ? *reinterpret_cast<const uint4*>(&A[(size_t)arow*128 + kbase])
                    : make_uint4(0,0,0,0);
    bf16v af = __builtin_bit_cast(bf16v, araw);
    #pragma unroll
    for (int nt = 0; nt < NT; ++nt){
      uint4 braw = *reinterpret_cast<const uint4*>(&Wb[(nt*16 + (lane&15))*KP + kbase]);
      bf16v bfr = __builtin_bit_cast(bf16v, braw);
      acc[nt] = __builtin_amdgcn_mfma_f32_16x16x32_bf16(af, bfr, acc[nt], 0, 0, 0);
    }
  }
  float ps[4] = {0,0,0,0}, pd[4] = {0,0,0,0};
  #pragma unroll
  for (int nt = 0; nt < NT; ++nt){
    int col = nt*16 + (lane&15);
    float vs = atts[col], vd = attd[col];
    #pragma unroll
    for (int reg = 0; reg < 4; ++reg){
      int row = r0w + (lane>>4)*4 + reg;
      float v = acc[nt][reg];
      if (row < N_NODES) hb[(size_t)row*F + col] = f2bf(v);
      ps[reg] += v*vs;
      pd[reg] += v*vd;
    }
  }
  #pragma unroll
  for (int reg = 0; reg < 4; ++reg){
    float s = ps[reg], d = pd[reg];
    #pragma unroll
    for (int o = 1; o < 16; o <<= 1){ s += __shfl_xor(s, o); d += __shfl_xor(d, o); }
    int row = r0w + (lane>>4)*4 + reg;
    if ((lane & 15) == 0 && row < N_NODES){ a_s[row] = s; a_d[row] = d; }
  }
}

// ---------- aggregation v3: no-max softmax, LDS (src,p) stage, BATCHED 4-load gather ----------
template<int F, bool W32>
__global__ __launch_bounds__(256) void aggregate_kernel(
    const unsigned short* __restrict__ hbAll,
    const float* __restrict__ aSAll, const float* __restrict__ aDAll,
    const unsigned* __restrict__ edgAll, const int* __restrict__ rowpAll,
    const float* __restrict__ scal, int l,
    const float* __restrict__ bias,
    float* __restrict__ out32All, unsigned short* __restrict__ outbAll)
{
  constexpr int PERL = F/16;   // 8 (F=128) or 4 (F=64)
  constexpr int PERH = PERL/2; // f32x2 accumulators
  int b = blockIdx.y;
  const unsigned short* hb = hbAll + (size_t)b*N_NODES*128;
  const float* a_s = aSAll + b*N_NODES;
  const float* a_d = aDAll + b*N_NODES;
  const unsigned* edges = edgAll + (size_t)b*N_EDGES;
  const int* rowp = rowpAll + b*(N_NODES+1);
  __shared__ uint2 sp[4][64];
  int wv = threadIdx.x >> 6;
  int lane = threadIdx.x & 63;
  int d = blockIdx.x*4 + wv;
  if (d >= N_NODES) return;
  int sub = lane & 15, grp = lane >> 4;
  float c = scal[2+l];
  float ae_self = (scal[b] * (1.0f/N_EDGES)) * c;
  float add_ = a_d[d];
  float p_self = __expf(fminf(leaky02(a_s[d] + add_ + ae_self), 60.f));
  float denom = p_self;
  f32x2 acc[PERH];
  #pragma unroll
  for (int i = 0; i < PERH; ++i) acc[i] = (f32x2){0.f, 0.f};
  if (grp == 0){
    f32x2 pself2 = {p_self, p_self};
    if (PERL == 8){
      uint4 q = *reinterpret_cast<const uint4*>(&hb[(size_t)d*F + 8*sub]);
      pkfma(acc[0], (f32x2){bflo(q.x), bfhi(q.x)}, pself2);
      pkfma(acc[1], (f32x2){bflo(q.y), bfhi(q.y)}, pself2);
      pkfma(acc[2], (f32x2){bflo(q.z), bfhi(q.z)}, pself2);
      pkfma(acc[3], (f32x2){bflo(q.w), bfhi(q.w)}, pself2);
    } else {
      uint2 q = *reinterpret_cast<const uint2*>(&hb[(size_t)d*F + 4*sub]);
      pkfma(acc[0], (f32x2){bflo(q.x), bfhi(q.x)}, pself2);
      pkfma(acc[1], (f32x2){bflo(q.y), bfhi(q.y)}, pself2);
    }
  }
  int e0 = rowp[d], e1 = rowp[d+1];
  for (int ch = e0; ch < e1; ch += 64){
    int n = min(64, e1 - ch);
    // phase 1: parallel p = exp(logit), denom reduce; sp slots >= n hold (0, 0.0)
    unsigned s0 = 0;
    float p0 = 0.f;
    if (lane < n){
      unsigned e = edges[ch + lane];
      s0 = e & 0xFFFFu;
      p0 = __expf(fminf(leaky02(a_s[s0] + add_ + c*bfhi(e)), 60.f));
    }
    float ds = p0;
    #pragma unroll
    for (int o = 32; o; o >>= 1) ds += __shfl_xor(ds, o);
    denom += ds;
    sp[wv][lane] = make_uint2(s0, __float_as_uint(p0));
    // phase 2: 16 edges per outer iter -> 4 independent uint4/uint2 loads in flight
    #pragma unroll 2
    for (int e4 = 0; e4 < n; e4 += 16){
      uint2 r0 = sp[wv][e4 + grp];
      uint2 r1 = sp[wv][e4 + 4 + grp];
      uint2 r2 = sp[wv][e4 + 8 + grp];
      uint2 r3 = sp[wv][e4 + 12 + grp];
      f32x2 a0 = {__uint_as_float(r0.y), __uint_as_float(r0.y)};
      f32x2 a1 = {__uint_as_float(r1.y), __uint_as_float(r1.y)};
      f32x2 a2 = {__uint_as_float(r2.y), __uint_as_float(r2.y)};
      f32x2 a3 = {__uint_as_float(r3.y), __uint_as_float(r3.y)};
      if (PERL == 8){
        uint4 q0 = *reinterpret_cast<const uint4*>(&hb[(size_t)r0.x*F + 8*sub]);
        uint4 q1 = *reinterpret_cast<const uint4*>(&hb[(size_t)r1.x*F + 8*sub]);
        uint4 q2 = *reinterpret_cast<const uint4*>(&hb[(size_t)r2.x*F + 8*sub]);
        uint4 q3 = *reinterpret_cast<const uint4*>(&hb[(size_t)r3.x*F + 8*sub]);
        pkfma(acc[0], (f32x2){bflo(q0.x), bfhi(q0.x)}, a0);
        pkfma(acc[1], (f32x2){bflo(q0.y), bfhi(q0.y)}, a0);
        pkfma(acc[2], (f32x2){bflo(q0.z), bfhi(q0.z)}, a0);
        pkfma(acc[3], (f32x2){bflo(q0.w), bfhi(q0.w)}, a0);
        pkfma(acc[0], (f32x2){bflo(q1.x), bfhi(q1.x)}, a1);
        pkfma(acc[1], (f32x2){bflo(q1.y), bfhi(q1.y)}, a1);
        pkfma(acc[2], (f32x2){bflo(q1.z), bfhi(q1.z)}, a1);
        pkfma(acc[3], (f32x2){bflo(q1.w), bfhi(q1.w)}, a1);
        pkfma(acc[0], (f32x2){bflo(q2.x), bfhi(q2.x)}, a2);
        pkfma(acc[1], (f32x2){bflo(q2.y), bfhi(q2.y)}, a2);
        pkfma(acc[2], (f32x2){bflo(q2.z), bfhi(q2.z)}, a2);
        pkfma(acc[3], (f32x2){bflo(q2.w), bfhi(q2.w)}, a2);
        pkfma(acc[0], (f32x2){bflo(q3.x), bfhi(q3.x)}, a3);
        pkfma(acc[1], (f32x2){bflo(q3.y), bfhi(q3.y)}, a3);
        pkfma(acc[2], (f32x2){bflo(q3.z), bfhi(q3.z)}, a3);
        pkfma(acc[3], (f32x2){bflo(q3.w), bfhi(q3.w)}, a3);
      } else {
        uint2 q0 = *reinterpret_cast<const uint2*>(&hb[(size_t)r0.x*F + 4*sub]);
        uint2 q1 = *reinterpret_cast<const uint2*>(&hb[(size_t)r1.x*F + 4*sub]);
        uint2 q2 = *reinterpret_cast<const uint2*>(&hb[(size_t)r2.x*F + 4*sub]);
        uint2 q3 = *reinterpret_cast<const uint2*>(&hb[(size_t)r3.x*F + 4*sub]);
        pkfma(acc[0], (f32x2){bflo(q0.x), bfhi(q0.x)}, a0);
        pkfma(acc[1], (f32x2){bflo(q0.y), bfhi(q0.y)}, a0);
        pkfma(acc[0], (f32x2){bflo(q1.x), bfhi(q1.x)}, a1);
        pkfma(acc[1], (f32x2){bflo(q1.y), bfhi(q1.y)}, a1);
        pkfma(acc[0], (f32x2){bflo(q2.x), bfhi(q2.x)}, a2);
        pkfma(acc[1], (f32x2){bflo(q2.y), bfhi(q2.y)}, a2);
        pkfma(acc[0], (f32x2){bflo(q3.x), bfhi(q3.x)}, a3);
        pkfma(acc[1], (f32x2){bflo(q3.y), bfhi(q3.y)}, a3);
      }
    }
  }
  // cross-group reduce + epilogue
  float inv = 1.0f/denom;
  float vv[PERL];
  #pragma unroll
  for (int i = 0; i < PERH; ++i){
    float v0 = acc[i].x, v1 = acc[i].y;
    v0 += __shfl_xor(v0, 16); v0 += __shfl_xor(v0, 32);
    v1 += __shfl_xor(v1, 16); v1 += __shfl_xor(v1, 32);
    vv[2*i]   = eluf(v0*inv + bias[PERL*sub + 2*i]);
    vv[2*i+1] = eluf(v1*inv + bias[PERL*sub + 2*i+1]);
  }
  if (grp == 0){
    if (W32){
      float* out32 = out32All + (size_t)b*N_NODES*64;
      *reinterpret_cast<float4*>(&out32[(size_t)d*64 + 4*sub]) = make_float4(vv[0],vv[1],vv[2],vv[3]);
    } else {
      unsigned short* outb = outbAll + (size_t)b*N_NODES*128;
      if (PERL == 8){
        uint4 o;
        o.x = (unsigned int)f2bf(vv[0]) | ((unsigned int)f2bf(vv[1]) << 16);
        o.y = (unsigned int)f2bf(vv[2]) | ((unsigned int)f2bf(vv[3]) << 16);
        o.z = (unsigned int)f2bf(vv[4]) | ((unsigned int)f2bf(vv[5]) << 16);
        o.w = (unsigned int)f2bf(vv[6]) | ((unsigned int)f2bf(vv[7]) << 16);
        *reinterpret_cast<uint4*>(&outb[(size_t)d*F + 8*sub]) = o;
      } else {
        uint2 o;
        o.x = (unsigned int)f2bf(vv[0]) | ((unsigned int)f2bf(vv[1]) << 16);
        o.y = (unsigned int)f2bf(vv[2]) | ((unsigned int)f2bf(vv[3]) << 16);
        *reinterpret_cast<uint2*>(&outb[(size_t)d*F + 4*sub]) = o;
      }
    }
  }
}

// ---------- fused mean-pool + final linear ----------
__global__ __launch_bounds__(256) void pool_final_kernel(
    const float* __restrict__ buf0, const int* __restrict__ gb,
    const float* __restrict__ xn0, const float* __restrict__ xn1,
    const float* __restrict__ linW, const float* __restrict__ linb,
    float* __restrict__ out)
{
  int bg = blockIdx.x;
  int b = bg >> 8, g = bg & 255;
  __shared__ float Wl[80*64];
  __shared__ float red[4][64];
  __shared__ float mf[64];
  int tid = threadIdx.x;
  for (int i = tid; i < 80*64; i += 256) Wl[i] = linW[i];
  const float* x = buf0 + (size_t)b*N_NODES*64;
  const int* gbb = gb + b*257;
  int s = gbb[g], e = gbb[g+1];
  int f = tid & 63, rg = tid >> 6;
  float acc = 0.f;
  for (int r = s + rg; r < e; r += 4) acc += x[r*64 + f];
  red[rg][f] = acc;
  __syncthreads();
  if (rg == 0)
    mf[f] = (red[0][f]+red[1][f]+red[2][f]+red[3][f]) / fmaxf((float)(e - s), 1.0f);
  __syncthreads();
  if (tid < 64){
    int j = tid;
    const float* xn = b ? xn1 : xn0;
    float a2 = linb[j];
    #pragma unroll 8
    for (int k = 0; k < 64; ++k) a2 += mf[k] * Wl[k*64 + j];
    #pragma unroll
    for (int k = 0; k < 16; ++k) a2 += xn[g*16+k] * Wl[(64+k)*64 + j];
    out[(size_t)(b*N_GRAPHS + g)*64 + j] = a2;
  }
}

extern "C" void kernel_launch(void* const* d_in, const int* in_sizes, int n_in,
                              void* d_out, int out_size, void* d_ws, size_t ws_size,
                              hipStream_t stream)
{
  const float* x1   = (const float*)d_in[0];
  const float* x2   = (const float*)d_in[1];
  const int*   ei1  = (const int*)d_in[2];
  const int*   ei2  = (const int*)d_in[3];
  const int*   bat1 = (const int*)d_in[4];
  const int*   bat2 = (const int*)d_in[5];
  const float* xn1  = (const float*)d_in[6];
  const float* xn2  = (const float*)d_in[7];
  const float* ec1  = (const float*)d_in[8];
  const float* ec2  = (const float*)d_in[9];
  const float* W[3]   = {(const float*)d_in[10], (const float*)d_in[16], (const float*)d_in[22]};
  const float* as_[3] = {(const float*)d_in[11], (const float*)d_in[17], (const float*)d_in[23]};
  const float* ad_[3] = {(const float*)d_in[12], (const float*)d_in[18], (const float*)d_in[24]};
  const float* We[3]  = {(const float*)d_in[13], (const float*)d_in[19], (const float*)d_in[25]};
  const float* ae[3]  = {(const float*)d_in[14], (const float*)d_in[20], (const float*)d_in[26]};
  const float* bb[3]  = {(const float*)d_in[15], (const float*)d_in[21], (const float*)d_in[27]};
  const float* linW = (const float*)d_in[28];
  const float* linb = (const float*)d_in[29];
  float* out = (float*)d_out;

  char* ws = (char*)d_ws;
  size_t off = 0;
  auto alloc = [&](size_t bytes)->char*{
    char* p = ws + off;
    off = (off + bytes + 255) & ~(size_t)255;
    return p;
  };
  unsigned short* hbA = (unsigned short*)alloc((size_t)2*N_NODES*128*2);
  unsigned short* hbB = (unsigned short*)alloc((size_t)2*N_NODES*128*2);
  float* buf0 = (float*)alloc((size_t)2*N_NODES*64*4);
  float* aS   = (float*)alloc((size_t)2*N_NODES*4);
  float* aD   = (float*)alloc((size_t)2*N_NODES*4);
  int* gcount = (int*)alloc((size_t)2*NBP*4);
  int* bcur   = (int*)alloc((size_t)2*NBUCK*CURP*4);
  int* cbase  = (int*)alloc((size_t)2*NBP*4);
  int* rowp   = (int*)alloc((size_t)2*(N_NODES+1)*4);
  uint2* stage = (uint2*)alloc((size_t)2*N_EDGES*8);
  unsigned* final_ = (unsigned*)alloc((size_t)2*N_EDGES*4);
  float* part = (float*)alloc((size_t)2*NA*4);
  int* gb     = (int*)alloc((size_t)2*257*4);
  float* scal = (float*)alloc(64);

  hipMemsetAsync(gcount, 0, (size_t)2*NBP*4, stream);
  prep_c_kernel<<<1, 256, 0, stream>>>(We[0], ae[0], We[1], ae[1], We[2], ae[2], scal);
  binA_kernel<<<dim3(NA,2), 256, 0, stream>>>(ei1, ei2, ec1, ec2, gcount, part);
  binB_kernel<<<2, 512, 0, stream>>>(gcount, part, bat1, bat2, bcur, cbase, gb, scal, rowp);
  binC_kernel<<<dim3(NC,2), 256, 0, stream>>>(ei1, ei2, ec1, ec2, bcur, stage);
  binD_kernel<<<dim3(NBUCK,2), 256, 0, stream>>>(stage, gcount, cbase, final_, rowp);

  // layer 1: K=7 -> F=128
  node_linear1_kernel<7,128><<<dim3(1024,2), 256, 0, stream>>>(
      x1, x2, W[0], as_[0], ad_[0], hbA, aS, aD);
  aggregate_kernel<128,false><<<dim3(N_NODES/4,2), 256, 0, stream>>>(
      hbA, aS, aD, final_, rowp, scal, 0, bb[0], nullptr, hbB);

  // layer 2: MFMA 128->128
  gemm_mfma_kernel<128><<<dim3((N_NODES+63)/64,2), 256, 0, stream>>>(
      hbB, W[1], as_[1], ad_[1], hbA, aS, aD);
  aggregate_kernel<128,false><<<dim3(N_NODES/4,2), 256, 0, stream>>>(
      hbA, aS, aD, final_, rowp, scal, 1, bb[1], nullptr, hbB);

  // layer 3: MFMA 128->64
  gemm_mfma_kernel<64><<<dim3((N_NODES+63)/64,2), 256, 0, stream>>>(
      hbB, W[2], as_[2], ad_[2], hbA, aS, aD);
  aggregate_kernel<64,true><<<dim3(N_NODES/4,2), 256, 0, stream>>>(
      hbA, aS, aD, final_, rowp, scal, 2, bb[2], buf0, nullptr);

  pool_final_kernel<<<2*N_GRAPHS, 256, 0, stream>>>(
      buf0, gb, xn1, xn2, linW, linb, out);
}

// Round 13
// 214.294 us; speedup vs baseline: 1.3279x; 1.0287x over previous
//
#include <hip/hip_runtime.h>
#include <hip/hip_bf16.h>
#include <hip/hip_fp16.h>

#define N_NODES 20000
#define N_EDGES 640000
#define N_GRAPHS 256
#define NBUCK 313                    // ceil(20000/64) buckets of 64 dsts
#define NBP 320                      // padded bucket stride (histogram arrays)
#define NA 160                       // binA blocks per branch
#define NC 160                       // binC blocks per branch
#define EPC 4000                     // edges per binC block (160*4000 = 640000)
#define DCAP 2560                    // binD LDS record capacity
#define CURP 16                      // bcur padding: 16 ints = 64B per bucket

typedef short bf16v __attribute__((ext_vector_type(8)));   // 8 bf16 (4 VGPRs)
typedef float f32x4 __attribute__((ext_vector_type(4)));
typedef float f32x2 __attribute__((ext_vector_type(2)));

__device__ __forceinline__ float leaky02(float x){ return x > 0.f ? x : 0.2f*x; }
__device__ __forceinline__ float eluf(float x){ return x > 0.f ? x : (__expf(x) - 1.f); }
__device__ __forceinline__ unsigned short f2bf(float x){
  __hip_bfloat16 t = __float2bfloat16(x);
  return *reinterpret_cast<unsigned short*>(&t);
}
__device__ __forceinline__ float bflo(unsigned int u){ return __uint_as_float(u << 16); }
__device__ __forceinline__ float bfhi(unsigned int u){ return __uint_as_float(u & 0xffff0000u); }
__device__ __forceinline__ void pkfma(f32x2& acc, f32x2 a, f32x2 b){
  asm volatile("v_pk_fma_f32 %0, %1, %2, %0" : "+v"(acc) : "v"(a), "v"(b));
}

// ---------- binA: bucket histogram + ec partial sums ----------
__global__ __launch_bounds__(256) void binA_kernel(
    const int* __restrict__ ei0, const int* __restrict__ ei1,
    const float* __restrict__ ec0, const float* __restrict__ ec1,
    int* __restrict__ gcount, float* __restrict__ part)
{
  int b = blockIdx.y;
  const int* dstp = (b ? ei1 : ei0) + N_EDGES;
  const float* ec = b ? ec1 : ec0;
  __shared__ int hist[NBUCK];
  int tid = threadIdx.x;
  for (int j = tid; j < NBUCK; j += 256) hist[j] = 0;
  __syncthreads();
  float v = 0.f;
  for (int i = blockIdx.x*256 + tid; i < N_EDGES; i += NA*256){
    atomicAdd(&hist[dstp[i] >> 6], 1);
    v += ec[i];
  }
  __syncthreads();
  for (int j = tid; j < NBUCK; j += 256)
    if (hist[j]) atomicAdd(&gcount[b*NBP + j], hist[j]);
  for (int o = 32; o; o >>= 1) v += __shfl_down(v, o);
  __shared__ float wr[4];
  int lane = tid & 63, wv = tid >> 6;
  if (lane == 0) wr[wv] = v;
  __syncthreads();
  if (tid == 0) part[b*NA + blockIdx.x] = wr[0]+wr[1]+wr[2]+wr[3];
}

// ---------- binB: bucket scan + bcur init + ec total + graph bounds + prep_c ----------
__global__ __launch_bounds__(512) void binB_kernel(
    const int* __restrict__ gcount, const float* __restrict__ part,
    const int* __restrict__ bat0, const int* __restrict__ bat1,
    const float* __restrict__ We1, const float* __restrict__ ae1,
    const float* __restrict__ We2, const float* __restrict__ ae2,
    const float* __restrict__ We3, const float* __restrict__ ae3,
    int* __restrict__ bcur, int* __restrict__ cbase,
    int* __restrict__ gb, float* __restrict__ scal, int* __restrict__ rowp)
{
  int b = blockIdx.x;
  int tid = threadIdx.x;
  // prep_c (block 0 only): scal[2+l] = dot(We_l, ae_l)
  if (b == 0){
    int wv = tid >> 6, lane = tid & 63;
    if (wv < 3){
      const float* We = wv==0 ? We1 : (wv==1 ? We2 : We3);
      const float* ae = wv==0 ? ae1 : (wv==1 ? ae2 : ae3);
      int F = (wv==2) ? 64 : 128;
      float s = 0.f;
      for (int i = lane; i < F; i += 64) s += We[i]*ae[i];
      for (int o = 32; o; o >>= 1) s += __shfl_down(s, o);
      if (lane == 0) scal[2+wv] = s;
    }
  }
  {
    float s = 0.f;
    for (int i = tid; i < NA; i += 512) s += part[b*NA + i];
    for (int o = 32; o; o >>= 1) s += __shfl_down(s, o);
    __shared__ float fr[8];
    if ((tid & 63) == 0) fr[tid >> 6] = s;
    __syncthreads();
    if (tid == 0){
      float t = 0.f;
      for (int i = 0; i < 8; ++i) t += fr[i];
      scal[b] = t;
    }
  }
  {
    const int* batch = b ? bat1 : bat0;
    int* gbb = gb + b*257;
    if (tid <= N_GRAPHS){
      int g = tid, lo = 0, hi = N_NODES;
      while (lo < hi){ int mid = (lo+hi) >> 1; if (batch[mid] < g) lo = mid+1; else hi = mid; }
      gbb[g] = lo;
    }
  }
  __shared__ int sc[512];
  int sz = (tid < NBUCK) ? gcount[b*NBP + tid] : 0;
  sc[tid] = sz;
  __syncthreads();
  for (int d = 1; d < 512; d <<= 1){
    int a2 = (tid >= d) ? sc[tid-d] : 0;
    __syncthreads();
    sc[tid] += a2;
    __syncthreads();
  }
  if (tid < NBUCK){
    int ecx = sc[tid] - sz;
    cbase[b*NBP + tid] = ecx;
    bcur[(b*NBUCK + tid)*CURP] = ecx;
  }
  if (tid == 0) rowp[b*(N_NODES+1) + N_NODES] = N_EDGES;
}

// ---------- binC: histogram-then-place LDS binning ----------
__global__ __launch_bounds__(256) void binC_kernel(
    const int* __restrict__ ei0, const int* __restrict__ ei1,
    const float* __restrict__ ec0, const float* __restrict__ ec1,
    int* __restrict__ bcur, uint2* __restrict__ stage)
{
  int b = blockIdx.y;
  const int* srcp = (b ? ei1 : ei0);
  const int* dstp = srcp + N_EDGES;
  const float* ec = b ? ec1 : ec0;
  int* bcurb = bcur + (size_t)b*NBUCK*CURP;
  uint2* stageb = stage + (size_t)b*N_EDGES;
  __shared__ uint2 recs[EPC];
  __shared__ int hist[NBUCK], rbase[NBUCK], rcur[NBUCK];
  int tid = threadIdx.x;
  for (int j = tid; j < NBUCK; j += 256){ hist[j] = 0; rcur[j] = 0; }
  __syncthreads();
  int e0 = blockIdx.x*EPC;
  for (int r = tid; r < EPC; r += 256){
    int i = e0 + r;
    int d = dstp[i];
    int bk = d >> 6;
    uint2 rec;
    rec.x = (unsigned)srcp[i] | ((unsigned)(d & 63) << 16);
    rec.y = ((unsigned)f2bf(ec[i]) << 16) | (unsigned)bk;
    recs[r] = rec;
    atomicAdd(&hist[bk], 1);
  }
  __syncthreads();
  for (int j = tid; j < NBUCK; j += 256){
    int h = hist[j];
    rbase[j] = h ? atomicAdd(&bcurb[j*CURP], h) : 0;
  }
  __syncthreads();
  for (int r = tid; r < EPC; r += 256){
    uint2 rc = recs[r];
    int bk = (int)(rc.y & 0xFFFFu);
    int p = rbase[bk] + atomicAdd(&rcur[bk], 1);
    stageb[p] = rc;
  }
}

// ---------- binD: per-bucket counting sort -> compact CSR + rowp ----------
__global__ __launch_bounds__(256) void binD_kernel(
    const uint2* __restrict__ stage, const int* __restrict__ gcount,
    const int* __restrict__ cbase,
    unsigned* __restrict__ final_, int* __restrict__ rowp)
{
  int b = blockIdx.y;
  int g = blockIdx.x;
  int tid = threadIdx.x;
  const uint2* stageb = stage + (size_t)b*N_EDGES;
  unsigned* finb = final_ + (size_t)b*N_EDGES;
  int* rowb = rowp + b*(N_NODES+1);
  int n = min(gcount[b*NBP + g], DCAP);
  int cb = cbase[b*NBP + g];
  __shared__ uint2 recs[DCAP];
  __shared__ int cnt64[64], cur64[64], off64[64];
  if (tid < 64) cnt64[tid] = 0;
  __syncthreads();
  for (int r = tid; r < n; r += 256){
    uint2 rc = stageb[cb + r];
    recs[r] = rc;
    atomicAdd(&cnt64[(rc.x >> 16) & 63], 1);
  }
  __syncthreads();
  if (tid == 0){
    int acc = 0;
    for (int dl = 0; dl < 64; ++dl){
      off64[dl] = acc; cur64[dl] = acc; acc += cnt64[dl];
    }
  }
  __syncthreads();
  int nd = min(64, N_NODES - g*64);
  if (tid < nd) rowb[g*64 + tid] = cb + off64[tid];
  for (int r = tid; r < n; r += 256){
    uint2 rc = recs[r];
    int dl = (rc.x >> 16) & 63;
    int p = atomicAdd(&cur64[dl], 1);
    finb[cb + p] = (rc.y & 0xFFFF0000u) | (rc.x & 0xFFFFu);
  }
}

// ---------- layer 1: K=7 scalar GEMM + att dots, bf16 out, both branches ----------
template<int K, int F>
__global__ __launch_bounds__(256) void node_linear1_kernel(
    const float* __restrict__ x0, const float* __restrict__ x1,
    const float* __restrict__ W,
    const float* __restrict__ atts, const float* __restrict__ attd,
    unsigned short* __restrict__ hbAll, float* __restrict__ aSAll, float* __restrict__ aDAll)
{
  int b = blockIdx.y;
  const float* x = b ? x1 : x0;
  unsigned short* hb = hbAll + (size_t)b*N_NODES*128;
  float* a_s = aSAll + b*N_NODES;
  float* a_d = aDAll + b*N_NODES;
  constexpr int ROWS = 256 / F; // 2
  __shared__ float Wl[K*F];
  __shared__ float xl[ROWS*K];
  __shared__ float swv[4], dwv[4];
  int tid = threadIdx.x;
  for (int i = tid; i < K*F; i += 256) Wl[i] = W[i];
  int f = tid % F;
  int lr = tid / F;
  float vs = atts[f], vd = attd[f];
  const int ntiles = (N_NODES + ROWS - 1)/ROWS;
  for (int t = blockIdx.x; t < ntiles; t += gridDim.x){
    int r0 = t*ROWS;
    __syncthreads();
    for (int i = tid; i < ROWS*K; i += 256){
      int r = i / K, k = i % K;
      int row = r0 + r;
      xl[i] = (row < N_NODES) ? x[row*K + k] : 0.f;
    }
    __syncthreads();
    float acc = 0.f;
    #pragma unroll
    for (int k = 0; k < K; ++k) acc += xl[lr*K + k] * Wl[k*F + f];
    int row = r0 + lr;
    if (row < N_NODES) hb[row*F + f] = f2bf(acc);
    float s = acc*vs, d = acc*vd;
    #pragma unroll
    for (int o = 32; o; o >>= 1){ s += __shfl_down(s, o); d += __shfl_down(d, o); }
    int wv = tid >> 6;
    if ((tid & 63) == 0){ swv[wv] = s; dwv[wv] = d; }
    __syncthreads();
    if (f == 0 && row < N_NODES){
      a_s[row] = swv[2*lr] + swv[2*lr+1];
      a_d[row] = dwv[2*lr] + dwv[2*lr+1];
    }
  }
}

// ---------- layers 2/3: MFMA GEMM (A bf16 -> bf16 out), fused att dots ----------
template<int F>
__global__ __launch_bounds__(256) void gemm_mfma_kernel(
    const unsigned short* __restrict__ AAll, const float* __restrict__ W,
    const float* __restrict__ atts, const float* __restrict__ attd,
    unsigned short* __restrict__ hbAll, float* __restrict__ aSAll, float* __restrict__ aDAll)
{
  int b = blockIdx.y;
  const unsigned short* A = AAll + (size_t)b*N_NODES*128;
  unsigned short* hb = hbAll + (size_t)b*N_NODES*128;
  float* a_s = aSAll + b*N_NODES;
  float* a_d = aDAll + b*N_NODES;
  constexpr int NT = F/16;
  constexpr int KP = 136;
  __shared__ unsigned short Wb[F*KP];
  int tid = threadIdx.x;
  for (int idx = tid; idx < 128*F; idx += 256){
    int k = idx / F, col = idx % F;
    Wb[col*KP + k] = f2bf(W[idx]);
  }
  __syncthreads();
  int wave = tid >> 6, lane = tid & 63;
  int r0w = blockIdx.x*64 + wave*16;
  int arow = r0w + (lane & 15);
  bool av = arow < N_NODES;
  f32x4 acc[NT];
  #pragma unroll
  for (int nt = 0; nt < NT; ++nt) acc[nt] = 0.f;
  #pragma unroll
  for (int step = 0; step < 4; ++step){
    int kbase = step*32 + (lane>>4)*8;
    uint4 araw = av ? *reinterpret_cast<const uint4*>(&A[(size_t)arow*128 + kbase])
                    : make_uint4(0,0,0,0);
    bf16v af = __builtin_bit_cast(bf16v, araw);
    #pragma unroll
    for (int nt = 0; nt < NT; ++nt){
      uint4 braw = *reinterpret_cast<const uint4*>(&Wb[(nt*16 + (lane&15))*KP + kbase]);
      bf16v bfr = __builtin_bit_cast(bf16v, braw);
      acc[nt] = __builtin_amdgcn_mfma_f32_16x16x32_bf16(af, bfr, acc[nt], 0, 0, 0);
    }
  }
  float ps[4] = {0,0,0,0}, pd[4] = {0,0,0,0};
  #pragma unroll
  for (int nt = 0; nt < NT; ++nt){
    int col = nt*16 + (lane&15);
    float vs = atts[col], vd = attd[col];
    #pragma unroll
    for (int reg = 0; reg < 4; ++reg){
      int row = r0w + (lane>>4)*4 + reg;
      float v = acc[nt][reg];
      if (row < N_NODES) hb[(size_t)row*F + col] = f2bf(v);
      ps[reg] += v*vs;
      pd[reg] += v*vd;
    }
  }
  #pragma unroll
  for (int reg = 0; reg < 4; ++reg){
    float s = ps[reg], d = pd[reg];
    #pragma unroll
    for (int o = 1; o < 16; o <<= 1){ s += __shfl_xor(s, o); d += __shfl_xor(d, o); }
    int row = r0w + (lane>>4)*4 + reg;
    if ((lane & 15) == 0 && row < N_NODES){ a_s[row] = s; a_d[row] = d; }
  }
}

// ---------- aggregation v4: branch-parity XCD pinning, late denom, unroll 4 ----------
// grid: 1-D, 2*(N_NODES/4) blocks; branch = bid&1 so each XCD (bid%8) serves ONE branch.
template<int F, bool W32>
__global__ __launch_bounds__(256) void aggregate_kernel(
    const unsigned short* __restrict__ hbAll,
    const float* __restrict__ aSAll, const float* __restrict__ aDAll,
    const unsigned* __restrict__ edgAll, const int* __restrict__ rowpAll,
    const float* __restrict__ scal, int l,
    const float* __restrict__ bias,
    float* __restrict__ out32All, unsigned short* __restrict__ outbAll)
{
  constexpr int PERL = F/16;   // 8 (F=128) or 4 (F=64)
  constexpr int PERH = PERL/2; // f32x2 accumulators
  int bid = blockIdx.x;
  int b = bid & 1;
  const unsigned short* hb = hbAll + (size_t)b*N_NODES*128;
  const float* a_s = aSAll + b*N_NODES;
  const float* a_d = aDAll + b*N_NODES;
  const unsigned* edges = edgAll + (size_t)b*N_EDGES;
  const int* rowp = rowpAll + b*(N_NODES+1);
  __shared__ uint2 sp[4][64];
  int wv = threadIdx.x >> 6;
  int lane = threadIdx.x & 63;
  int d = (bid >> 1)*4 + wv;
  if (d >= N_NODES) return;
  int sub = lane & 15, grp = lane >> 4;
  float c = scal[2+l];
  float ae_self = (scal[b] * (1.0f/N_EDGES)) * c;
  float add_ = a_d[d];
  float p_self = __expf(fminf(leaky02(a_s[d] + add_ + ae_self), 60.f));
  float dsum = 0.f;                           // per-lane p accumulator (late reduce)
  f32x2 acc[PERH];
  #pragma unroll
  for (int i = 0; i < PERH; ++i) acc[i] = (f32x2){0.f, 0.f};
  if (grp == 0){
    f32x2 pself2 = {p_self, p_self};
    if (PERL == 8){
      uint4 q = *reinterpret_cast<const uint4*>(&hb[(size_t)d*F + 8*sub]);
      pkfma(acc[0], (f32x2){bflo(q.x), bfhi(q.x)}, pself2);
      pkfma(acc[1], (f32x2){bflo(q.y), bfhi(q.y)}, pself2);
      pkfma(acc[2], (f32x2){bflo(q.z), bfhi(q.z)}, pself2);
      pkfma(acc[3], (f32x2){bflo(q.w), bfhi(q.w)}, pself2);
    } else {
      uint2 q = *reinterpret_cast<const uint2*>(&hb[(size_t)d*F + 4*sub]);
      pkfma(acc[0], (f32x2){bflo(q.x), bfhi(q.x)}, pself2);
      pkfma(acc[1], (f32x2){bflo(q.y), bfhi(q.y)}, pself2);
    }
  }
  int e0 = rowp[d], e1 = rowp[d+1];
  for (int ch = e0; ch < e1; ch += 64){
    int n = min(64, e1 - ch);
    // phase 1: p = exp(logit); stage (src,p); NO reduce here (late denom)
    unsigned s0 = 0;
    float p0 = 0.f;
    if (lane < n){
      unsigned e = edges[ch + lane];
      s0 = e & 0xFFFFu;
      p0 = __expf(fminf(leaky02(a_s[s0] + add_ + c*bfhi(e)), 60.f));
    }
    dsum += p0;
    sp[wv][lane] = make_uint2(s0, __float_as_uint(p0));
    // phase 2: 16 edges per iter, 4 independent loads, unroll 4
    #pragma unroll 4
    for (int e4 = 0; e4 < n; e4 += 16){
      uint2 r0 = sp[wv][e4 + grp];
      uint2 r1 = sp[wv][e4 + 4 + grp];
      uint2 r2 = sp[wv][e4 + 8 + grp];
      uint2 r3 = sp[wv][e4 + 12 + grp];
      f32x2 a0 = {__uint_as_float(r0.y), __uint_as_float(r0.y)};
      f32x2 a1 = {__uint_as_float(r1.y), __uint_as_float(r1.y)};
      f32x2 a2 = {__uint_as_float(r2.y), __uint_as_float(r2.y)};
      f32x2 a3 = {__uint_as_float(r3.y), __uint_as_float(r3.y)};
      if (PERL == 8){
        uint4 q0 = *reinterpret_cast<const uint4*>(&hb[(size_t)r0.x*F + 8*sub]);
        uint4 q1 = *reinterpret_cast<const uint4*>(&hb[(size_t)r1.x*F + 8*sub]);
        uint4 q2 = *reinterpret_cast<const uint4*>(&hb[(size_t)r2.x*F + 8*sub]);
        uint4 q3 = *reinterpret_cast<const uint4*>(&hb[(size_t)r3.x*F + 8*sub]);
        pkfma(acc[0], (f32x2){bflo(q0.x), bfhi(q0.x)}, a0);
        pkfma(acc[1], (f32x2){bflo(q0.y), bfhi(q0.y)}, a0);
        pkfma(acc[2], (f32x2){bflo(q0.z), bfhi(q0.z)}, a0);
        pkfma(acc[3], (f32x2){bflo(q0.w), bfhi(q0.w)}, a0);
        pkfma(acc[0], (f32x2){bflo(q1.x), bfhi(q1.x)}, a1);
        pkfma(acc[1], (f32x2){bflo(q1.y), bfhi(q1.y)}, a1);
        pkfma(acc[2], (f32x2){bflo(q1.z), bfhi(q1.z)}, a1);
        pkfma(acc[3], (f32x2){bflo(q1.w), bfhi(q1.w)}, a1);
        pkfma(acc[0], (f32x2){bflo(q2.x), bfhi(q2.x)}, a2);
        pkfma(acc[1], (f32x2){bflo(q2.y), bfhi(q2.y)}, a2);
        pkfma(acc[2], (f32x2){bflo(q2.z), bfhi(q2.z)}, a2);
        pkfma(acc[3], (f32x2){bflo(q2.w), bfhi(q2.w)}, a2);
        pkfma(acc[0], (f32x2){bflo(q3.x), bfhi(q3.x)}, a3);
        pkfma(acc[1], (f32x2){bflo(q3.y), bfhi(q3.y)}, a3);
        pkfma(acc[2], (f32x2){bflo(q3.z), bfhi(q3.z)}, a3);
        pkfma(acc[3], (f32x2){bflo(q3.w), bfhi(q3.w)}, a3);
      } else {
        uint2 q0 = *reinterpret_cast<const uint2*>(&hb[(size_t)r0.x*F + 4*sub]);
        uint2 q1 = *reinterpret_cast<const uint2*>(&hb[(size_t)r1.x*F + 4*sub]);
        uint2 q2 = *reinterpret_cast<const uint2*>(&hb[(size_t)r2.x*F + 4*sub]);
        uint2 q3 = *reinterpret_cast<const uint2*>(&hb[(size_t)r3.x*F + 4*sub]);
        pkfma(acc[0], (f32x2){bflo(q0.x), bfhi(q0.x)}, a0);
        pkfma(acc[1], (f32x2){bflo(q0.y), bfhi(q0.y)}, a0);
        pkfma(acc[0], (f32x2){bflo(q1.x), bfhi(q1.x)}, a1);
        pkfma(acc[1], (f32x2){bflo(q1.y), bfhi(q1.y)}, a1);
        pkfma(acc[0], (f32x2){bflo(q2.x), bfhi(q2.x)}, a2);
        pkfma(acc[1], (f32x2){bflo(q2.y), bfhi(q2.y)}, a2);
        pkfma(acc[0], (f32x2){bflo(q3.x), bfhi(q3.x)}, a3);
        pkfma(acc[1], (f32x2){bflo(q3.y), bfhi(q3.y)}, a3);
      }
    }
  }
  // late denom reduce (once per dst)
  #pragma unroll
  for (int o = 32; o; o >>= 1) dsum += __shfl_xor(dsum, o);
  float denom = p_self + dsum;
  float inv = 1.0f/denom;
  float vv[PERL];
  #pragma unroll
  for (int i = 0; i < PERH; ++i){
    float v0 = acc[i].x, v1 = acc[i].y;
    v0 += __shfl_xor(v0, 16); v0 += __shfl_xor(v0, 32);
    v1 += __shfl_xor(v1, 16); v1 += __shfl_xor(v1, 32);
    vv[2*i]   = eluf(v0*inv + bias[PERL*sub + 2*i]);
    vv[2*i+1] = eluf(v1*inv + bias[PERL*sub + 2*i+1]);
  }
  if (grp == 0){
    if (W32){
      float* out32 = out32All + (size_t)b*N_NODES*64;
      *reinterpret_cast<float4*>(&out32[(size_t)d*64 + 4*sub]) = make_float4(vv[0],vv[1],vv[2],vv[3]);
    } else {
      unsigned short* outb = outbAll + (size_t)b*N_NODES*128;
      if (PERL == 8){
        uint4 o;
        o.x = (unsigned int)f2bf(vv[0]) | ((unsigned int)f2bf(vv[1]) << 16);
        o.y = (unsigned int)f2bf(vv[2]) | ((unsigned int)f2bf(vv[3]) << 16);
        o.z = (unsigned int)f2bf(vv[4]) | ((unsigned int)f2bf(vv[5]) << 16);
        o.w = (unsigned int)f2bf(vv[6]) | ((unsigned int)f2bf(vv[7]) << 16);
        *reinterpret_cast<uint4*>(&outb[(size_t)d*F + 8*sub]) = o;
      } else {
        uint2 o;
        o.x = (unsigned int)f2bf(vv[0]) | ((unsigned int)f2bf(vv[1]) << 16);
        o.y = (unsigned int)f2bf(vv[2]) | ((unsigned int)f2bf(vv[3]) << 16);
        *reinterpret_cast<uint2*>(&outb[(size_t)d*F + 4*sub]) = o;
      }
    }
  }
}

// ---------- fused mean-pool + final linear ----------
__global__ __launch_bounds__(256) void pool_final_kernel(
    const float* __restrict__ buf0, const int* __restrict__ gb,
    const float* __restrict__ xn0, const float* __restrict__ xn1,
    const float* __restrict__ linW, const float* __restrict__ linb,
    float* __restrict__ out)
{
  int bg = blockIdx.x;
  int b = bg >> 8, g = bg & 255;
  __shared__ float Wl[80*64];
  __shared__ float red[4][64];
  __shared__ float mf[64];
  int tid = threadIdx.x;
  for (int i = tid; i < 80*64; i += 256) Wl[i] = linW[i];
  const float* x = buf0 + (size_t)b*N_NODES*64;
  const int* gbb = gb + b*257;
  int s = gbb[g], e = gbb[g+1];
  int f = tid & 63, rg = tid >> 6;
  float acc = 0.f;
  for (int r = s + rg; r < e; r += 4) acc += x[r*64 + f];
  red[rg][f] = acc;
  __syncthreads();
  if (rg == 0)
    mf[f] = (red[0][f]+red[1][f]+red[2][f]+red[3][f]) / fmaxf((float)(e - s), 1.0f);
  __syncthreads();
  if (tid < 64){
    int j = tid;
    const float* xn = b ? xn1 : xn0;
    float a2 = linb[j];
    #pragma unroll 8
    for (int k = 0; k < 64; ++k) a2 += mf[k] * Wl[k*64 + j];
    #pragma unroll
    for (int k = 0; k < 16; ++k) a2 += xn[g*16+k] * Wl[(64+k)*64 + j];
    out[(size_t)(b*N_GRAPHS + g)*64 + j] = a2;
  }
}

extern "C" void kernel_launch(void* const* d_in, const int* in_sizes, int n_in,
                              void* d_out, int out_size, void* d_ws, size_t ws_size,
                              hipStream_t stream)
{
  const float* x1   = (const float*)d_in[0];
  const float* x2   = (const float*)d_in[1];
  const int*   ei1  = (const int*)d_in[2];
  const int*   ei2  = (const int*)d_in[3];
  const int*   bat1 = (const int*)d_in[4];
  const int*   bat2 = (const int*)d_in[5];
  const float* xn1  = (const float*)d_in[6];
  const float* xn2  = (const float*)d_in[7];
  const float* ec1  = (const float*)d_in[8];
  const float* ec2  = (const float*)d_in[9];
  const float* W[3]   = {(const float*)d_in[10], (const float*)d_in[16], (const float*)d_in[22]};
  const float* as_[3] = {(const float*)d_in[11], (const float*)d_in[17], (const float*)d_in[23]};
  const float* ad_[3] = {(const float*)d_in[12], (const float*)d_in[18], (const float*)d_in[24]};
  const float* We[3]  = {(const float*)d_in[13], (const float*)d_in[19], (const float*)d_in[25]};
  const float* ae[3]  = {(const float*)d_in[14], (const float*)d_in[20], (const float*)d_in[26]};
  const float* bb[3]  = {(const float*)d_in[15], (const float*)d_in[21], (const float*)d_in[27]};
  const float* linW = (const float*)d_in[28];
  const float* linb = (const float*)d_in[29];
  float* out = (float*)d_out;

  char* ws = (char*)d_ws;
  size_t off = 0;
  auto alloc = [&](size_t bytes)->char*{
    char* p = ws + off;
    off = (off + bytes + 255) & ~(size_t)255;
    return p;
  };
  unsigned short* hbA = (unsigned short*)alloc((size_t)2*N_NODES*128*2);
  unsigned short* hbB = (unsigned short*)alloc((size_t)2*N_NODES*128*2);
  float* buf0 = (float*)alloc((size_t)2*N_NODES*64*4);
  float* aS   = (float*)alloc((size_t)2*N_NODES*4);
  float* aD   = (float*)alloc((size_t)2*N_NODES*4);
  int* gcount = (int*)alloc((size_t)2*NBP*4);
  int* bcur   = (int*)alloc((size_t)2*NBUCK*CURP*4);
  int* cbase  = (int*)alloc((size_t)2*NBP*4);
  int* rowp   = (int*)alloc((size_t)2*(N_NODES+1)*4);
  uint2* stage = (uint2*)alloc((size_t)2*N_EDGES*8);
  unsigned* final_ = (unsigned*)alloc((size_t)2*N_EDGES*4);
  float* part = (float*)alloc((size_t)2*NA*4);
  int* gb     = (int*)alloc((size_t)2*257*4);
  float* scal = (float*)alloc(64);

  hipMemsetAsync(gcount, 0, (size_t)2*NBP*4, stream);
  binA_kernel<<<dim3(NA,2), 256, 0, stream>>>(ei1, ei2, ec1, ec2, gcount, part);
  binB_kernel<<<2, 512, 0, stream>>>(gcount, part, bat1, bat2,
      We[0], ae[0], We[1], ae[1], We[2], ae[2],
      bcur, cbase, gb, scal, rowp);
  binC_kernel<<<dim3(NC,2), 256, 0, stream>>>(ei1, ei2, ec1, ec2, bcur, stage);
  binD_kernel<<<dim3(NBUCK,2), 256, 0, stream>>>(stage, gcount, cbase, final_, rowp);

  const int AGG = 2*(N_NODES/4);  // 10000 blocks, branch = bid&1

  // layer 1: K=7 -> F=128
  node_linear1_kernel<7,128><<<dim3(1024,2), 256, 0, stream>>>(
      x1, x2, W[0], as_[0], ad_[0], hbA, aS, aD);
  aggregate_kernel<128,false><<<AGG, 256, 0, stream>>>(
      hbA, aS, aD, final_, rowp, scal, 0, bb[0], nullptr, hbB);

  // layer 2: MFMA 128->128
  gemm_mfma_kernel<128><<<dim3((N_NODES+63)/64,2), 256, 0, stream>>>(
      hbB, W[1], as_[1], ad_[1], hbA, aS, aD);
  aggregate_kernel<128,false><<<AGG, 256, 0, stream>>>(
      hbA, aS, aD, final_, rowp, scal, 1, bb[1], nullptr, hbB);

  // layer 3: MFMA 128->64
  gemm_mfma_kernel<64><<<dim3((N_NODES+63)/64,2), 256, 0, stream>>>(
      hbB, W[2], as_[2], ad_[2], hbA, aS, aD);
  aggregate_kernel<64,true><<<AGG, 256, 0, stream>>>(
      hbA, aS, aD, final_, rowp, scal, 2, bb[2], buf0, nullptr);

  pool_final_kernel<<<2*N_GRAPHS, 256, 0, stream>>>(
      buf0, gb, xn1, xn2, linW, linb, out);
}

// Round 14
// 211.852 us; speedup vs baseline: 1.3432x; 1.0115x over previous
//
#include <hip/hip_runtime.h>
#include <hip/hip_bf16.h>
#include <hip/hip_fp16.h>

#define N_NODES 20000
#define N_EDGES 640000
#define N_GRAPHS 256
#define NBUCK 313                    // ceil(20000/64) buckets of 64 dsts
#define NBP 320                      // padded bucket stride (histogram arrays)
#define NA 160                       // binA blocks per branch
#define NC 160                       // binC blocks per branch
#define EPC 4000                     // edges per binC block (160*4000 = 640000)
#define DCAP 2560                    // binD LDS record capacity
#define CURP 16                      // bcur padding: 16 ints = 64B per bucket

typedef short bf16v __attribute__((ext_vector_type(8)));   // 8 bf16 (4 VGPRs)
typedef float f32x4 __attribute__((ext_vector_type(4)));
typedef float f32x2 __attribute__((ext_vector_type(2)));

__device__ __forceinline__ float leaky02(float x){ return x > 0.f ? x : 0.2f*x; }
__device__ __forceinline__ float eluf(float x){ return x > 0.f ? x : (__expf(x) - 1.f); }
__device__ __forceinline__ unsigned short f2bf(float x){
  __hip_bfloat16 t = __float2bfloat16(x);
  return *reinterpret_cast<unsigned short*>(&t);
}
__device__ __forceinline__ float bflo(unsigned int u){ return __uint_as_float(u << 16); }
__device__ __forceinline__ float bfhi(unsigned int u){ return __uint_as_float(u & 0xffff0000u); }
__device__ __forceinline__ void pkfma(f32x2& acc, f32x2 a, f32x2 b){
  asm volatile("v_pk_fma_f32 %0, %1, %2, %0" : "+v"(acc) : "v"(a), "v"(b));
}

// ---------- binA: bucket histogram + ec partial sums ----------
__global__ __launch_bounds__(256) void binA_kernel(
    const int* __restrict__ ei0, const int* __restrict__ ei1,
    const float* __restrict__ ec0, const float* __restrict__ ec1,
    int* __restrict__ gcount, float* __restrict__ part)
{
  int b = blockIdx.y;
  const int* dstp = (b ? ei1 : ei0) + N_EDGES;
  const float* ec = b ? ec1 : ec0;
  __shared__ int hist[NBUCK];
  int tid = threadIdx.x;
  for (int j = tid; j < NBUCK; j += 256) hist[j] = 0;
  __syncthreads();
  float v = 0.f;
  for (int i = blockIdx.x*256 + tid; i < N_EDGES; i += NA*256){
    atomicAdd(&hist[dstp[i] >> 6], 1);
    v += ec[i];
  }
  __syncthreads();
  for (int j = tid; j < NBUCK; j += 256)
    if (hist[j]) atomicAdd(&gcount[b*NBP + j], hist[j]);
  for (int o = 32; o; o >>= 1) v += __shfl_down(v, o);
  __shared__ float wr[4];
  int lane = tid & 63, wv = tid >> 6;
  if (lane == 0) wr[wv] = v;
  __syncthreads();
  if (tid == 0) part[b*NA + blockIdx.x] = wr[0]+wr[1]+wr[2]+wr[3];
}

// ---------- binB: bucket scan + bcur init + ec total + graph bounds + prep_c ----------
__global__ __launch_bounds__(512) void binB_kernel(
    const int* __restrict__ gcount, const float* __restrict__ part,
    const int* __restrict__ bat0, const int* __restrict__ bat1,
    const float* __restrict__ We1, const float* __restrict__ ae1,
    const float* __restrict__ We2, const float* __restrict__ ae2,
    const float* __restrict__ We3, const float* __restrict__ ae3,
    int* __restrict__ bcur, int* __restrict__ cbase,
    int* __restrict__ gb, float* __restrict__ scal, int* __restrict__ rowp)
{
  int b = blockIdx.x;
  int tid = threadIdx.x;
  // prep_c (block 0 only): scal[2+l] = dot(We_l, ae_l)
  if (b == 0){
    int wv = tid >> 6, lane = tid & 63;
    if (wv < 3){
      const float* We = wv==0 ? We1 : (wv==1 ? We2 : We3);
      const float* ae = wv==0 ? ae1 : (wv==1 ? ae2 : ae3);
      int F = (wv==2) ? 64 : 128;
      float s = 0.f;
      for (int i = lane; i < F; i += 64) s += We[i]*ae[i];
      for (int o = 32; o; o >>= 1) s += __shfl_down(s, o);
      if (lane == 0) scal[2+wv] = s;
    }
  }
  {
    float s = 0.f;
    for (int i = tid; i < NA; i += 512) s += part[b*NA + i];
    for (int o = 32; o; o >>= 1) s += __shfl_down(s, o);
    __shared__ float fr[8];
    if ((tid & 63) == 0) fr[tid >> 6] = s;
    __syncthreads();
    if (tid == 0){
      float t = 0.f;
      for (int i = 0; i < 8; ++i) t += fr[i];
      scal[b] = t;
    }
  }
  {
    const int* batch = b ? bat1 : bat0;
    int* gbb = gb + b*257;
    if (tid <= N_GRAPHS){
      int g = tid, lo = 0, hi = N_NODES;
      while (lo < hi){ int mid = (lo+hi) >> 1; if (batch[mid] < g) lo = mid+1; else hi = mid; }
      gbb[g] = lo;
    }
  }
  __shared__ int sc[512];
  int sz = (tid < NBUCK) ? gcount[b*NBP + tid] : 0;
  sc[tid] = sz;
  __syncthreads();
  for (int d = 1; d < 512; d <<= 1){
    int a2 = (tid >= d) ? sc[tid-d] : 0;
    __syncthreads();
    sc[tid] += a2;
    __syncthreads();
  }
  if (tid < NBUCK){
    int ecx = sc[tid] - sz;
    cbase[b*NBP + tid] = ecx;
    bcur[(b*NBUCK + tid)*CURP] = ecx;
  }
  if (tid == 0) rowp[b*(N_NODES+1) + N_NODES] = N_EDGES;
}

// ---------- binC: histogram-then-place LDS binning ----------
__global__ __launch_bounds__(256) void binC_kernel(
    const int* __restrict__ ei0, const int* __restrict__ ei1,
    const float* __restrict__ ec0, const float* __restrict__ ec1,
    int* __restrict__ bcur, uint2* __restrict__ stage)
{
  int b = blockIdx.y;
  const int* srcp = (b ? ei1 : ei0);
  const int* dstp = srcp + N_EDGES;
  const float* ec = b ? ec1 : ec0;
  int* bcurb = bcur + (size_t)b*NBUCK*CURP;
  uint2* stageb = stage + (size_t)b*N_EDGES;
  __shared__ uint2 recs[EPC];
  __shared__ int hist[NBUCK], rbase[NBUCK], rcur[NBUCK];
  int tid = threadIdx.x;
  for (int j = tid; j < NBUCK; j += 256){ hist[j] = 0; rcur[j] = 0; }
  __syncthreads();
  int e0 = blockIdx.x*EPC;
  for (int r = tid; r < EPC; r += 256){
    int i = e0 + r;
    int d = dstp[i];
    int bk = d >> 6;
    uint2 rec;
    rec.x = (unsigned)srcp[i] | ((unsigned)(d & 63) << 16);
    rec.y = ((unsigned)f2bf(ec[i]) << 16) | (unsigned)bk;
    recs[r] = rec;
    atomicAdd(&hist[bk], 1);
  }
  __syncthreads();
  for (int j = tid; j < NBUCK; j += 256){
    int h = hist[j];
    rbase[j] = h ? atomicAdd(&bcurb[j*CURP], h) : 0;
  }
  __syncthreads();
  for (int r = tid; r < EPC; r += 256){
    uint2 rc = recs[r];
    int bk = (int)(rc.y & 0xFFFFu);
    int p = rbase[bk] + atomicAdd(&rcur[bk], 1);
    stageb[p] = rc;
  }
}

// ---------- binD: per-bucket counting sort -> compact CSR + rowp ----------
__global__ __launch_bounds__(256) void binD_kernel(
    const uint2* __restrict__ stage, const int* __restrict__ gcount,
    const int* __restrict__ cbase,
    unsigned* __restrict__ final_, int* __restrict__ rowp)
{
  int b = blockIdx.y;
  int g = blockIdx.x;
  int tid = threadIdx.x;
  const uint2* stageb = stage + (size_t)b*N_EDGES;
  unsigned* finb = final_ + (size_t)b*N_EDGES;
  int* rowb = rowp + b*(N_NODES+1);
  int n = min(gcount[b*NBP + g], DCAP);
  int cb = cbase[b*NBP + g];
  __shared__ uint2 recs[DCAP];
  __shared__ int cnt64[64], cur64[64], off64[64];
  if (tid < 64) cnt64[tid] = 0;
  __syncthreads();
  for (int r = tid; r < n; r += 256){
    uint2 rc = stageb[cb + r];
    recs[r] = rc;
    atomicAdd(&cnt64[(rc.x >> 16) & 63], 1);
  }
  __syncthreads();
  if (tid == 0){
    int acc = 0;
    for (int dl = 0; dl < 64; ++dl){
      off64[dl] = acc; cur64[dl] = acc; acc += cnt64[dl];
    }
  }
  __syncthreads();
  int nd = min(64, N_NODES - g*64);
  if (tid < nd) rowb[g*64 + tid] = cb + off64[tid];
  for (int r = tid; r < n; r += 256){
    uint2 rc = recs[r];
    int dl = (rc.x >> 16) & 63;
    int p = atomicAdd(&cur64[dl], 1);
    finb[cb + p] = (rc.y & 0xFFFF0000u) | (rc.x & 0xFFFFu);
  }
}

// ---------- layer 1: K=7 scalar GEMM + att dots, bf16 out, both branches ----------
template<int K, int F>
__global__ __launch_bounds__(256) void node_linear1_kernel(
    const float* __restrict__ x0, const float* __restrict__ x1,
    const float* __restrict__ W,
    const float* __restrict__ atts, const float* __restrict__ attd,
    unsigned short* __restrict__ hbAll, float* __restrict__ aSAll, float* __restrict__ aDAll)
{
  int b = blockIdx.y;
  const float* x = b ? x1 : x0;
  unsigned short* hb = hbAll + (size_t)b*N_NODES*128;
  float* a_s = aSAll + b*N_NODES;
  float* a_d = aDAll + b*N_NODES;
  constexpr int ROWS = 256 / F; // 2
  __shared__ float Wl[K*F];
  __shared__ float xl[ROWS*K];
  __shared__ float swv[4], dwv[4];
  int tid = threadIdx.x;
  for (int i = tid; i < K*F; i += 256) Wl[i] = W[i];
  int f = tid % F;
  int lr = tid / F;
  float vs = atts[f], vd = attd[f];
  const int ntiles = (N_NODES + ROWS - 1)/ROWS;
  for (int t = blockIdx.x; t < ntiles; t += gridDim.x){
    int r0 = t*ROWS;
    __syncthreads();
    for (int i = tid; i < ROWS*K; i += 256){
      int r = i / K, k = i % K;
      int row = r0 + r;
      xl[i] = (row < N_NODES) ? x[row*K + k] : 0.f;
    }
    __syncthreads();
    float acc = 0.f;
    #pragma unroll
    for (int k = 0; k < K; ++k) acc += xl[lr*K + k] * Wl[k*F + f];
    int row = r0 + lr;
    if (row < N_NODES) hb[row*F + f] = f2bf(acc);
    float s = acc*vs, d = acc*vd;
    #pragma unroll
    for (int o = 32; o; o >>= 1){ s += __shfl_down(s, o); d += __shfl_down(d, o); }
    int wv = tid >> 6;
    if ((tid & 63) == 0){ swv[wv] = s; dwv[wv] = d; }
    __syncthreads();
    if (f == 0 && row < N_NODES){
      a_s[row] = swv[2*lr] + swv[2*lr+1];
      a_d[row] = dwv[2*lr] + dwv[2*lr+1];
    }
  }
}

// ---------- layers 2/3: MFMA GEMM (A bf16 -> bf16 out), fused att dots ----------
template<int F>
__global__ __launch_bounds__(256) void gemm_mfma_kernel(
    const unsigned short* __restrict__ AAll, const float* __restrict__ W,
    const float* __restrict__ atts, const float* __restrict__ attd,
    unsigned short* __restrict__ hbAll, float* __restrict__ aSAll, float* __restrict__ aDAll)
{
  int b = blockIdx.y;
  const unsigned short* A = AAll + (size_t)b*N_NODES*128;
  unsigned short* hb = hbAll + (size_t)b*N_NODES*128;
  float* a_s = aSAll + b*N_NODES;
  float* a_d = aDAll + b*N_NODES;
  constexpr int NT = F/16;
  constexpr int KP = 136;
  __shared__ unsigned short Wb[F*KP];
  int tid = threadIdx.x;
  for (int idx = tid; idx < 128*F; idx += 256){
    int k = idx / F, col = idx % F;
    Wb[col*KP + k] = f2bf(W[idx]);
  }
  __syncthreads();
  int wave = tid >> 6, lane = tid & 63;
  int r0w = blockIdx.x*64 + wave*16;
  int arow = r0w + (lane & 15);
  bool av = arow < N_NODES;
  f32x4 acc[NT];
  #pragma unroll
  for (int nt = 0; nt < NT; ++nt) acc[nt] = 0.f;
  #pragma unroll
  for (int step = 0; step < 4; ++step){
    int kbase = step*32 + (lane>>4)*8;
    uint4 araw = av ? *reinterpret_cast<const uint4*>(&A[(size_t)arow*128 + kbase])
                    : make_uint4(0,0,0,0);
    bf16v af = __builtin_bit_cast(bf16v, araw);
    #pragma unroll
    for (int nt = 0; nt < NT; ++nt){
      uint4 braw = *reinterpret_cast<const uint4*>(&Wb[(nt*16 + (lane&15))*KP + kbase]);
      bf16v bfr = __builtin_bit_cast(bf16v, braw);
      acc[nt] = __builtin_amdgcn_mfma_f32_16x16x32_bf16(af, bfr, acc[nt], 0, 0, 0);
    }
  }
  float ps[4] = {0,0,0,0}, pd[4] = {0,0,0,0};
  #pragma unroll
  for (int nt = 0; nt < NT; ++nt){
    int col = nt*16 + (lane&15);
    float vs = atts[col], vd = attd[col];
    #pragma unroll
    for (int reg = 0; reg < 4; ++reg){
      int row = r0w + (lane>>4)*4 + reg;
      float v = acc[nt][reg];
      if (row < N_NODES) hb[(size_t)row*F + col] = f2bf(v);
      ps[reg] += v*vs;
      pd[reg] += v*vd;
    }
  }
  #pragma unroll
  for (int reg = 0; reg < 4; ++reg){
    float s = ps[reg], d = pd[reg];
    #pragma unroll
    for (int o = 1; o < 16; o <<= 1){ s += __shfl_xor(s, o); d += __shfl_xor(d, o); }
    int row = r0w + (lane>>4)*4 + reg;
    if ((lane & 15) == 0 && row < N_NODES){ a_s[row] = s; a_d[row] = d; }
  }
}

// ---------- aggregation v5: byte-offset LDS staging, XCD parity, late denom ----------
// grid: 1-D, 2*(N_NODES/4) blocks; branch = bid&1 so each XCD (bid%8) serves ONE branch.
template<int F, bool W32>
__global__ __launch_bounds__(256) void aggregate_kernel(
    const unsigned short* __restrict__ hbAll,
    const float* __restrict__ aSAll, const float* __restrict__ aDAll,
    const unsigned* __restrict__ edgAll, const int* __restrict__ rowpAll,
    const float* __restrict__ scal, int l,
    const float* __restrict__ bias,
    float* __restrict__ out32All, unsigned short* __restrict__ outbAll)
{
  constexpr int PERL = F/16;   // 8 (F=128) or 4 (F=64)
  constexpr int PERH = PERL/2; // f32x2 accumulators
  constexpr int RSH = (F == 128) ? 8 : 7;   // row byte-shift: src*2F
  constexpr int SUBB = (F == 128) ? 16 : 8; // bytes per lane slice
  int bid = blockIdx.x;
  int b = bid & 1;
  const unsigned short* hb = hbAll + (size_t)b*N_NODES*128;
  const float* a_s = aSAll + b*N_NODES;
  const float* a_d = aDAll + b*N_NODES;
  const unsigned* edges = edgAll + (size_t)b*N_EDGES;
  const int* rowp = rowpAll + b*(N_NODES+1);
  __shared__ uint2 sp[4][64];
  int wv = threadIdx.x >> 6;
  int lane = threadIdx.x & 63;
  int d = (bid >> 1)*4 + wv;
  if (d >= N_NODES) return;
  int sub = lane & 15, grp = lane >> 4;
  const char* hb2 = (const char*)hb + sub*SUBB;   // pre-offset base: addr = hb2 + rowoff
  float c = scal[2+l];
  float ae_self = (scal[b] * (1.0f/N_EDGES)) * c;
  float add_ = a_d[d];
  float p_self = __expf(fminf(leaky02(a_s[d] + add_ + ae_self), 60.f));
  float dsum = 0.f;
  f32x2 acc[PERH];
  #pragma unroll
  for (int i = 0; i < PERH; ++i) acc[i] = (f32x2){0.f, 0.f};
  if (grp == 0){
    f32x2 pself2 = {p_self, p_self};
    if (PERL == 8){
      uint4 q = *reinterpret_cast<const uint4*>(hb2 + ((unsigned)d << RSH));
      pkfma(acc[0], (f32x2){bflo(q.x), bfhi(q.x)}, pself2);
      pkfma(acc[1], (f32x2){bflo(q.y), bfhi(q.y)}, pself2);
      pkfma(acc[2], (f32x2){bflo(q.z), bfhi(q.z)}, pself2);
      pkfma(acc[3], (f32x2){bflo(q.w), bfhi(q.w)}, pself2);
    } else {
      uint2 q = *reinterpret_cast<const uint2*>(hb2 + ((unsigned)d << RSH));
      pkfma(acc[0], (f32x2){bflo(q.x), bfhi(q.x)}, pself2);
      pkfma(acc[1], (f32x2){bflo(q.y), bfhi(q.y)}, pself2);
    }
  }
  int e0 = rowp[d], e1 = rowp[d+1];
  for (int ch = e0; ch < e1; ch += 64){
    int n = min(64, e1 - ch);
    // phase 1: p = exp(logit); stage (row-byte-offset, p); late denom
    unsigned off0 = 0;
    float p0 = 0.f;
    if (lane < n){
      unsigned e = edges[ch + lane];
      unsigned s0 = e & 0xFFFFu;
      p0 = __expf(fminf(leaky02(a_s[s0] + add_ + c*bfhi(e)), 60.f));
      off0 = s0 << RSH;
    }
    dsum += p0;
    sp[wv][lane] = make_uint2(off0, __float_as_uint(p0));
    // phase 2: 16 edges per iter, 4 independent loads (single-add addressing), unroll 4
    #pragma unroll 4
    for (int e4 = 0; e4 < n; e4 += 16){
      uint2 r0 = sp[wv][e4 + grp];
      uint2 r1 = sp[wv][e4 + 4 + grp];
      uint2 r2 = sp[wv][e4 + 8 + grp];
      uint2 r3 = sp[wv][e4 + 12 + grp];
      f32x2 a0 = {__uint_as_float(r0.y), __uint_as_float(r0.y)};
      f32x2 a1 = {__uint_as_float(r1.y), __uint_as_float(r1.y)};
      f32x2 a2 = {__uint_as_float(r2.y), __uint_as_float(r2.y)};
      f32x2 a3 = {__uint_as_float(r3.y), __uint_as_float(r3.y)};
      if (PERL == 8){
        uint4 q0 = *reinterpret_cast<const uint4*>(hb2 + r0.x);
        uint4 q1 = *reinterpret_cast<const uint4*>(hb2 + r1.x);
        uint4 q2 = *reinterpret_cast<const uint4*>(hb2 + r2.x);
        uint4 q3 = *reinterpret_cast<const uint4*>(hb2 + r3.x);
        pkfma(acc[0], (f32x2){bflo(q0.x), bfhi(q0.x)}, a0);
        pkfma(acc[1], (f32x2){bflo(q0.y), bfhi(q0.y)}, a0);
        pkfma(acc[2], (f32x2){bflo(q0.z), bfhi(q0.z)}, a0);
        pkfma(acc[3], (f32x2){bflo(q0.w), bfhi(q0.w)}, a0);
        pkfma(acc[0], (f32x2){bflo(q1.x), bfhi(q1.x)}, a1);
        pkfma(acc[1], (f32x2){bflo(q1.y), bfhi(q1.y)}, a1);
        pkfma(acc[2], (f32x2){bflo(q1.z), bfhi(q1.z)}, a1);
        pkfma(acc[3], (f32x2){bflo(q1.w), bfhi(q1.w)}, a1);
        pkfma(acc[0], (f32x2){bflo(q2.x), bfhi(q2.x)}, a2);
        pkfma(acc[1], (f32x2){bflo(q2.y), bfhi(q2.y)}, a2);
        pkfma(acc[2], (f32x2){bflo(q2.z), bfhi(q2.z)}, a2);
        pkfma(acc[3], (f32x2){bflo(q2.w), bfhi(q2.w)}, a2);
        pkfma(acc[0], (f32x2){bflo(q3.x), bfhi(q3.x)}, a3);
        pkfma(acc[1], (f32x2){bflo(q3.y), bfhi(q3.y)}, a3);
        pkfma(acc[2], (f32x2){bflo(q3.z), bfhi(q3.z)}, a3);
        pkfma(acc[3], (f32x2){bflo(q3.w), bfhi(q3.w)}, a3);
      } else {
        uint2 q0 = *reinterpret_cast<const uint2*>(hb2 + r0.x);
        uint2 q1 = *reinterpret_cast<const uint2*>(hb2 + r1.x);
        uint2 q2 = *reinterpret_cast<const uint2*>(hb2 + r2.x);
        uint2 q3 = *reinterpret_cast<const uint2*>(hb2 + r3.x);
        pkfma(acc[0], (f32x2){bflo(q0.x), bfhi(q0.x)}, a0);
        pkfma(acc[1], (f32x2){bflo(q0.y), bfhi(q0.y)}, a0);
        pkfma(acc[0], (f32x2){bflo(q1.x), bfhi(q1.x)}, a1);
        pkfma(acc[1], (f32x2){bflo(q1.y), bfhi(q1.y)}, a1);
        pkfma(acc[0], (f32x2){bflo(q2.x), bfhi(q2.x)}, a2);
        pkfma(acc[1], (f32x2){bflo(q2.y), bfhi(q2.y)}, a2);
        pkfma(acc[0], (f32x2){bflo(q3.x), bfhi(q3.x)}, a3);
        pkfma(acc[1], (f32x2){bflo(q3.y), bfhi(q3.y)}, a3);
      }
    }
  }
  // late denom reduce
  #pragma unroll
  for (int o = 32; o; o >>= 1) dsum += __shfl_xor(dsum, o);
  float denom = p_self + dsum;
  float inv = 1.0f/denom;
  float vv[PERL];
  #pragma unroll
  for (int i = 0; i < PERH; ++i){
    float v0 = acc[i].x, v1 = acc[i].y;
    v0 += __shfl_xor(v0, 16); v0 += __shfl_xor(v0, 32);
    v1 += __shfl_xor(v1, 16); v1 += __shfl_xor(v1, 32);
    vv[2*i]   = eluf(v0*inv + bias[PERL*sub + 2*i]);
    vv[2*i+1] = eluf(v1*inv + bias[PERL*sub + 2*i+1]);
  }
  if (grp == 0){
    if (W32){
      float* out32 = out32All + (size_t)b*N_NODES*64;
      *reinterpret_cast<float4*>(&out32[(size_t)d*64 + 4*sub]) = make_float4(vv[0],vv[1],vv[2],vv[3]);
    } else {
      unsigned short* outb = outbAll + (size_t)b*N_NODES*128;
      if (PERL == 8){
        uint4 o;
        o.x = (unsigned int)f2bf(vv[0]) | ((unsigned int)f2bf(vv[1]) << 16);
        o.y = (unsigned int)f2bf(vv[2]) | ((unsigned int)f2bf(vv[3]) << 16);
        o.z = (unsigned int)f2bf(vv[4]) | ((unsigned int)f2bf(vv[5]) << 16);
        o.w = (unsigned int)f2bf(vv[6]) | ((unsigned int)f2bf(vv[7]) << 16);
        *reinterpret_cast<uint4*>(&outb[(size_t)d*F + 8*sub]) = o;
      } else {
        uint2 o;
        o.x = (unsigned int)f2bf(vv[0]) | ((unsigned int)f2bf(vv[1]) << 16);
        o.y = (unsigned int)f2bf(vv[2]) | ((unsigned int)f2bf(vv[3]) << 16);
        *reinterpret_cast<uint2*>(&outb[(size_t)d*F + 4*sub]) = o;
      }
    }
  }
}

// ---------- fused mean-pool + final linear ----------
__global__ __launch_bounds__(256) void pool_final_kernel(
    const float* __restrict__ buf0, const int* __restrict__ gb,
    const float* __restrict__ xn0, const float* __restrict__ xn1,
    const float* __restrict__ linW, const float* __restrict__ linb,
    float* __restrict__ out)
{
  int bg = blockIdx.x;
  int b = bg >> 8, g = bg & 255;
  __shared__ float Wl[80*64];
  __shared__ float red[4][64];
  __shared__ float mf[64];
  int tid = threadIdx.x;
  for (int i = tid; i < 80*64; i += 256) Wl[i] = linW[i];
  const float* x = buf0 + (size_t)b*N_NODES*64;
  const int* gbb = gb + b*257;
  int s = gbb[g], e = gbb[g+1];
  int f = tid & 63, rg = tid >> 6;
  float acc = 0.f;
  for (int r = s + rg; r < e; r += 4) acc += x[r*64 + f];
  red[rg][f] = acc;
  __syncthreads();
  if (rg == 0)
    mf[f] = (red[0][f]+red[1][f]+red[2][f]+red[3][f]) / fmaxf((float)(e - s), 1.0f);
  __syncthreads();
  if (tid < 64){
    int j = tid;
    const float* xn = b ? xn1 : xn0;
    float a2 = linb[j];
    #pragma unroll 8
    for (int k = 0; k < 64; ++k) a2 += mf[k] * Wl[k*64 + j];
    #pragma unroll
    for (int k = 0; k < 16; ++k) a2 += xn[g*16+k] * Wl[(64+k)*64 + j];
    out[(size_t)(b*N_GRAPHS + g)*64 + j] = a2;
  }
}

extern "C" void kernel_launch(void* const* d_in, const int* in_sizes, int n_in,
                              void* d_out, int out_size, void* d_ws, size_t ws_size,
                              hipStream_t stream)
{
  const float* x1   = (const float*)d_in[0];
  const float* x2   = (const float*)d_in[1];
  const int*   ei1  = (const int*)d_in[2];
  const int*   ei2  = (const int*)d_in[3];
  const int*   bat1 = (const int*)d_in[4];
  const int*   bat2 = (const int*)d_in[5];
  const float* xn1  = (const float*)d_in[6];
  const float* xn2  = (const float*)d_in[7];
  const float* ec1  = (const float*)d_in[8];
  const float* ec2  = (const float*)d_in[9];
  const float* W[3]   = {(const float*)d_in[10], (const float*)d_in[16], (const float*)d_in[22]};
  const float* as_[3] = {(const float*)d_in[11], (const float*)d_in[17], (const float*)d_in[23]};
  const float* ad_[3] = {(const float*)d_in[12], (const float*)d_in[18], (const float*)d_in[24]};
  const float* We[3]  = {(const float*)d_in[13], (const float*)d_in[19], (const float*)d_in[25]};
  const float* ae[3]  = {(const float*)d_in[14], (const float*)d_in[20], (const float*)d_in[26]};
  const float* bb[3]  = {(const float*)d_in[15], (const float*)d_in[21], (const float*)d_in[27]};
  const float* linW = (const float*)d_in[28];
  const float* linb = (const float*)d_in[29];
  float* out = (float*)d_out;

  char* ws = (char*)d_ws;
  size_t off = 0;
  auto alloc = [&](size_t bytes)->char*{
    char* p = ws + off;
    off = (off + bytes + 255) & ~(size_t)255;
    return p;
  };
  unsigned short* hbA = (unsigned short*)alloc((size_t)2*N_NODES*128*2);
  unsigned short* hbB = (unsigned short*)alloc((size_t)2*N_NODES*128*2);
  float* buf0 = (float*)alloc((size_t)2*N_NODES*64*4);
  float* aS   = (float*)alloc((size_t)2*N_NODES*4);
  float* aD   = (float*)alloc((size_t)2*N_NODES*4);
  int* gcount = (int*)alloc((size_t)2*NBP*4);
  int* bcur   = (int*)alloc((size_t)2*NBUCK*CURP*4);
  int* cbase  = (int*)alloc((size_t)2*NBP*4);
  int* rowp   = (int*)alloc((size_t)2*(N_NODES+1)*4);
  uint2* stage = (uint2*)alloc((size_t)2*N_EDGES*8);
  unsigned* final_ = (unsigned*)alloc((size_t)2*N_EDGES*4);
  float* part = (float*)alloc((size_t)2*NA*4);
  int* gb     = (int*)alloc((size_t)2*257*4);
  float* scal = (float*)alloc(64);

  hipMemsetAsync(gcount, 0, (size_t)2*NBP*4, stream);
  binA_kernel<<<dim3(NA,2), 256, 0, stream>>>(ei1, ei2, ec1, ec2, gcount, part);
  binB_kernel<<<2, 512, 0, stream>>>(gcount, part, bat1, bat2,
      We[0], ae[0], We[1], ae[1], We[2], ae[2],
      bcur, cbase, gb, scal, rowp);
  binC_kernel<<<dim3(NC,2), 256, 0, stream>>>(ei1, ei2, ec1, ec2, bcur, stage);
  binD_kernel<<<dim3(NBUCK,2), 256, 0, stream>>>(stage, gcount, cbase, final_, rowp);

  const int AGG = 2*(N_NODES/4);  // 10000 blocks, branch = bid&1

  // layer 1: K=7 -> F=128
  node_linear1_kernel<7,128><<<dim3(1024,2), 256, 0, stream>>>(
      x1, x2, W[0], as_[0], ad_[0], hbA, aS, aD);
  aggregate_kernel<128,false><<<AGG, 256, 0, stream>>>(
      hbA, aS, aD, final_, rowp, scal, 0, bb[0], nullptr, hbB);

  // layer 2: MFMA 128->128
  gemm_mfma_kernel<128><<<dim3((N_NODES+63)/64,2), 256, 0, stream>>>(
      hbB, W[1], as_[1], ad_[1], hbA, aS, aD);
  aggregate_kernel<128,false><<<AGG, 256, 0, stream>>>(
      hbA, aS, aD, final_, rowp, scal, 1, bb[1], nullptr, hbB);

  // layer 3: MFMA 128->64
  gemm_mfma_kernel<64><<<dim3((N_NODES+63)/64,2), 256, 0, stream>>>(
      hbB, W[2], as_[2], ad_[2], hbA, aS, aD);
  aggregate_kernel<64,true><<<AGG, 256, 0, stream>>>(
      hbA, aS, aD, final_, rowp, scal, 2, bb[2], buf0, nullptr);

  pool_final_kernel<<<2*N_GRAPHS, 256, 0, stream>>>(
      buf0, gb, xn1, xn2, linW, linb, out);
}

// Round 15
// 199.967 us; speedup vs baseline: 1.4230x; 1.0594x over previous
//
#include <hip/hip_runtime.h>
#include <hip/hip_bf16.h>
#include <hip/hip_fp16.h>

#define N_NODES 20000
#define N_EDGES 640000
#define N_GRAPHS 256
#define NBUCK 313                    // ceil(20000/64) buckets of 64 dsts
#define NC 160                       // binC blocks per branch
#define EPC 4000                     // edges per binC block (160*4000 = 640000)
#define DCAP 2560                    // per-bucket region capacity (mean 2045 + 11 sigma)
#define CURP 16                      // bcur padding: 16 ints = 64B per bucket
#define STAGEN ((size_t)NBUCK*DCAP)  // 801,280 records per branch

typedef short bf16v __attribute__((ext_vector_type(8)));   // 8 bf16 (4 VGPRs)
typedef float f32x4 __attribute__((ext_vector_type(4)));
typedef float f32x2 __attribute__((ext_vector_type(2)));

__device__ __forceinline__ float leaky02(float x){ return x > 0.f ? x : 0.2f*x; }
__device__ __forceinline__ float eluf(float x){ return x > 0.f ? x : (__expf(x) - 1.f); }
__device__ __forceinline__ unsigned short f2bf(float x){
  __hip_bfloat16 t = __float2bfloat16(x);
  return *reinterpret_cast<unsigned short*>(&t);
}
__device__ __forceinline__ float bflo(unsigned int u){ return __uint_as_float(u << 16); }
__device__ __forceinline__ float bfhi(unsigned int u){ return __uint_as_float(u & 0xffff0000u); }
__device__ __forceinline__ void pkfma(f32x2& acc, f32x2 a, f32x2 b){
  asm volatile("v_pk_fma_f32 %0, %1, %2, %0" : "+v"(acc) : "v"(a), "v"(b));
}

// ---------- init: bucket cursors at region bases ----------
__global__ void init_kernel(int* __restrict__ bcur){
  int i = blockIdx.x*256 + threadIdx.x;       // i in [0, 2*NBUCK)
  if (i < 2*NBUCK){
    int b = i / NBUCK, j = i % NBUCK;
    bcur[((size_t)b*NBUCK + j)*CURP] = j*DCAP;
  }
}

// ---------- binC: histogram-then-place LDS binning into padded regions + ec partials ----------
__global__ __launch_bounds__(256) void binC_kernel(
    const int* __restrict__ ei0, const int* __restrict__ ei1,
    const float* __restrict__ ec0, const float* __restrict__ ec1,
    int* __restrict__ bcur, uint2* __restrict__ stage, float* __restrict__ part)
{
  int b = blockIdx.y;
  const int* srcp = (b ? ei1 : ei0);
  const int* dstp = srcp + N_EDGES;
  const float* ec = b ? ec1 : ec0;
  int* bcurb = bcur + (size_t)b*NBUCK*CURP;
  uint2* stageb = stage + (size_t)b*STAGEN;
  __shared__ uint2 recs[EPC];
  __shared__ int hist[NBUCK], rbase[NBUCK], rcur[NBUCK];
  int tid = threadIdx.x;
  for (int j = tid; j < NBUCK; j += 256){ hist[j] = 0; rcur[j] = 0; }
  __syncthreads();
  int e0 = blockIdx.x*EPC;
  float v = 0.f;
  for (int r = tid; r < EPC; r += 256){
    int i = e0 + r;
    int d = dstp[i];
    int bk = d >> 6;
    uint2 rec;
    rec.x = (unsigned)srcp[i] | ((unsigned)(d & 63) << 16);
    float e = ec[i];
    v += e;
    rec.y = ((unsigned)f2bf(e) << 16) | (unsigned)bk;
    recs[r] = rec;
    atomicAdd(&hist[bk], 1);
  }
  __syncthreads();
  for (int j = tid; j < NBUCK; j += 256){
    int h = hist[j];
    rbase[j] = h ? atomicAdd(&bcurb[j*CURP], h) : 0;
  }
  __syncthreads();
  for (int r = tid; r < EPC; r += 256){
    uint2 rc = recs[r];
    int bk = (int)(rc.y & 0xFFFFu);
    int p = rbase[bk] + atomicAdd(&rcur[bk], 1);
    if (p < (bk + 1)*DCAP) stageb[p] = rc;   // overflow clamp (11-sigma margin)
  }
  // ec partial sum
  for (int o = 32; o; o >>= 1) v += __shfl_down(v, o);
  __shared__ float wr[4];
  int lane = tid & 63, wv = tid >> 6;
  if (lane == 0) wr[wv] = v;
  __syncthreads();
  if (tid == 0) part[b*NC + blockIdx.x] = wr[0]+wr[1]+wr[2]+wr[3];
}

// ---------- binB: ec total + graph bounds + prep_c (runs after binC) ----------
__global__ __launch_bounds__(512) void binB_kernel(
    const float* __restrict__ part,
    const int* __restrict__ bat0, const int* __restrict__ bat1,
    const float* __restrict__ We1, const float* __restrict__ ae1,
    const float* __restrict__ We2, const float* __restrict__ ae2,
    const float* __restrict__ We3, const float* __restrict__ ae3,
    int* __restrict__ gb, float* __restrict__ scal)
{
  int b = blockIdx.x;
  int tid = threadIdx.x;
  if (b == 0){
    int wv = tid >> 6, lane = tid & 63;
    if (wv < 3){
      const float* We = wv==0 ? We1 : (wv==1 ? We2 : We3);
      const float* ae = wv==0 ? ae1 : (wv==1 ? ae2 : ae3);
      int F = (wv==2) ? 64 : 128;
      float s = 0.f;
      for (int i = lane; i < F; i += 64) s += We[i]*ae[i];
      for (int o = 32; o; o >>= 1) s += __shfl_down(s, o);
      if (lane == 0) scal[2+wv] = s;
    }
  }
  {
    float s = 0.f;
    for (int i = tid; i < NC; i += 512) s += part[b*NC + i];
    for (int o = 32; o; o >>= 1) s += __shfl_down(s, o);
    __shared__ float fr[8];
    if ((tid & 63) == 0) fr[tid >> 6] = s;
    __syncthreads();
    if (tid == 0){
      float t = 0.f;
      for (int i = 0; i < 8; ++i) t += fr[i];
      scal[b] = t;
    }
  }
  {
    const int* batch = b ? bat1 : bat0;
    int* gbb = gb + b*257;
    if (tid <= N_GRAPHS){
      int g = tid, lo = 0, hi = N_NODES;
      while (lo < hi){ int mid = (lo+hi) >> 1; if (batch[mid] < g) lo = mid+1; else hi = mid; }
      gbb[g] = lo;
    }
  }
}

// ---------- binD: per-bucket counting sort -> padded CSR + int2 rowp2 ----------
__global__ __launch_bounds__(256) void binD_kernel(
    const uint2* __restrict__ stage, const int* __restrict__ bcur,
    unsigned* __restrict__ final_, int2* __restrict__ rowp2)
{
  int b = blockIdx.y;
  int g = blockIdx.x;
  int tid = threadIdx.x;
  const uint2* stageb = stage + (size_t)b*STAGEN;
  unsigned* finb = final_ + (size_t)b*STAGEN;
  int2* rowb = rowp2 + (size_t)b*N_NODES;
  int cb = g*DCAP;
  int n = min(bcur[((size_t)b*NBUCK + g)*CURP] - cb, DCAP);
  __shared__ uint2 recs[DCAP];
  __shared__ int cnt64[64], cur64[64], off64[64];
  if (tid < 64) cnt64[tid] = 0;
  __syncthreads();
  for (int r = tid; r < n; r += 256){
    uint2 rc = stageb[cb + r];
    recs[r] = rc;
    atomicAdd(&cnt64[(rc.x >> 16) & 63], 1);
  }
  __syncthreads();
  if (tid == 0){
    int acc = 0;
    for (int dl = 0; dl < 64; ++dl){
      off64[dl] = acc; cur64[dl] = acc; acc += cnt64[dl];
    }
  }
  __syncthreads();
  int nd = min(64, N_NODES - g*64);
  if (tid < nd)
    rowb[g*64 + tid] = make_int2(cb + off64[tid], cb + off64[tid] + cnt64[tid]);
  for (int r = tid; r < n; r += 256){
    uint2 rc = recs[r];
    int dl = (rc.x >> 16) & 63;
    int p = atomicAdd(&cur64[dl], 1);
    finb[cb + p] = (rc.y & 0xFFFF0000u) | (rc.x & 0xFFFFu);
  }
}

// ---------- layer 1: K=7 scalar GEMM + att dots, bf16 out, both branches ----------
template<int K, int F>
__global__ __launch_bounds__(256) void node_linear1_kernel(
    const float* __restrict__ x0, const float* __restrict__ x1,
    const float* __restrict__ W,
    const float* __restrict__ atts, const float* __restrict__ attd,
    unsigned short* __restrict__ hbAll, float* __restrict__ aSAll, float* __restrict__ aDAll)
{
  int b = blockIdx.y;
  const float* x = b ? x1 : x0;
  unsigned short* hb = hbAll + (size_t)b*N_NODES*128;
  float* a_s = aSAll + b*N_NODES;
  float* a_d = aDAll + b*N_NODES;
  constexpr int ROWS = 256 / F; // 2
  __shared__ float Wl[K*F];
  __shared__ float xl[ROWS*K];
  __shared__ float swv[4], dwv[4];
  int tid = threadIdx.x;
  for (int i = tid; i < K*F; i += 256) Wl[i] = W[i];
  int f = tid % F;
  int lr = tid / F;
  float vs = atts[f], vd = attd[f];
  const int ntiles = (N_NODES + ROWS - 1)/ROWS;
  for (int t = blockIdx.x; t < ntiles; t += gridDim.x){
    int r0 = t*ROWS;
    __syncthreads();
    for (int i = tid; i < ROWS*K; i += 256){
      int r = i / K, k = i % K;
      int row = r0 + r;
      xl[i] = (row < N_NODES) ? x[row*K + k] : 0.f;
    }
    __syncthreads();
    float acc = 0.f;
    #pragma unroll
    for (int k = 0; k < K; ++k) acc += xl[lr*K + k] * Wl[k*F + f];
    int row = r0 + lr;
    if (row < N_NODES) hb[row*F + f] = f2bf(acc);
    float s = acc*vs, d = acc*vd;
    #pragma unroll
    for (int o = 32; o; o >>= 1){ s += __shfl_down(s, o); d += __shfl_down(d, o); }
    int wv = tid >> 6;
    if ((tid & 63) == 0){ swv[wv] = s; dwv[wv] = d; }
    __syncthreads();
    if (f == 0 && row < N_NODES){
      a_s[row] = swv[2*lr] + swv[2*lr+1];
      a_d[row] = dwv[2*lr] + dwv[2*lr+1];
    }
  }
}

// ---------- layers 2/3: MFMA GEMM (A bf16 -> bf16 out), fused att dots ----------
template<int F>
__global__ __launch_bounds__(256) void gemm_mfma_kernel(
    const unsigned short* __restrict__ AAll, const float* __restrict__ W,
    const float* __restrict__ atts, const float* __restrict__ attd,
    unsigned short* __restrict__ hbAll, float* __restrict__ aSAll, float* __restrict__ aDAll)
{
  int b = blockIdx.y;
  const unsigned short* A = AAll + (size_t)b*N_NODES*128;
  unsigned short* hb = hbAll + (size_t)b*N_NODES*128;
  float* a_s = aSAll + b*N_NODES;
  float* a_d = aDAll + b*N_NODES;
  constexpr int NT = F/16;
  constexpr int KP = 136;
  __shared__ unsigned short Wb[F*KP];
  int tid = threadIdx.x;
  for (int idx = tid; idx < 128*F; idx += 256){
    int k = idx / F, col = idx % F;
    Wb[col*KP + k] = f2bf(W[idx]);
  }
  __syncthreads();
  int wave = tid >> 6, lane = tid & 63;
  int r0w = blockIdx.x*64 + wave*16;
  int arow = r0w + (lane & 15);
  bool av = arow < N_NODES;
  f32x4 acc[NT];
  #pragma unroll
  for (int nt = 0; nt < NT; ++nt) acc[nt] = 0.f;
  #pragma unroll
  for (int step = 0; step < 4; ++step){
    int kbase = step*32 + (lane>>4)*8;
    uint4 araw = av ? *reinterpret_cast<const uint4*>(&A[(size_t)arow*128 + kbase])
                    : make_uint4(0,0,0,0);
    bf16v af = __builtin_bit_cast(bf16v, araw);
    #pragma unroll
    for (int nt = 0; nt < NT; ++nt){
      uint4 braw = *reinterpret_cast<const uint4*>(&Wb[(nt*16 + (lane&15))*KP + kbase]);
      bf16v bfr = __builtin_bit_cast(bf16v, braw);
      acc[nt] = __builtin_amdgcn_mfma_f32_16x16x32_bf16(af, bfr, acc[nt], 0, 0, 0);
    }
  }
  float ps[4] = {0,0,0,0}, pd[4] = {0,0,0,0};
  #pragma unroll
  for (int nt = 0; nt < NT; ++nt){
    int col = nt*16 + (lane&15);
    float vs = atts[col], vd = attd[col];
    #pragma unroll
    for (int reg = 0; reg < 4; ++reg){
      int row = r0w + (lane>>4)*4 + reg;
      float v = acc[nt][reg];
      if (row < N_NODES) hb[(size_t)row*F + col] = f2bf(v);
      ps[reg] += v*vs;
      pd[reg] += v*vd;
    }
  }
  #pragma unroll
  for (int reg = 0; reg < 4; ++reg){
    float s = ps[reg], d = pd[reg];
    #pragma unroll
    for (int o = 1; o < 16; o <<= 1){ s += __shfl_xor(s, o); d += __shfl_xor(d, o); }
    int row = r0w + (lane>>4)*4 + reg;
    if ((lane & 15) == 0 && row < N_NODES){ a_s[row] = s; a_d[row] = d; }
  }
}

// ---------- aggregation v5: byte-offset LDS staging, XCD parity, late denom ----------
template<int F, bool W32>
__global__ __launch_bounds__(256) void aggregate_kernel(
    const unsigned short* __restrict__ hbAll,
    const float* __restrict__ aSAll, const float* __restrict__ aDAll,
    const unsigned* __restrict__ edgAll, const int2* __restrict__ rowp2All,
    const float* __restrict__ scal, int l,
    const float* __restrict__ bias,
    float* __restrict__ out32All, unsigned short* __restrict__ outbAll)
{
  constexpr int PERL = F/16;   // 8 (F=128) or 4 (F=64)
  constexpr int PERH = PERL/2;
  constexpr int RSH = (F == 128) ? 8 : 7;
  constexpr int SUBB = (F == 128) ? 16 : 8;
  int bid = blockIdx.x;
  int b = bid & 1;
  const unsigned short* hb = hbAll + (size_t)b*N_NODES*128;
  const float* a_s = aSAll + b*N_NODES;
  const float* a_d = aDAll + b*N_NODES;
  const unsigned* edges = edgAll + (size_t)b*STAGEN;
  const int2* rowp2 = rowp2All + (size_t)b*N_NODES;
  __shared__ uint2 sp[4][64];
  int wv = threadIdx.x >> 6;
  int lane = threadIdx.x & 63;
  int d = (bid >> 1)*4 + wv;
  if (d >= N_NODES) return;
  int sub = lane & 15, grp = lane >> 4;
  const char* hb2 = (const char*)hb + sub*SUBB;
  float c = scal[2+l];
  float ae_self = (scal[b] * (1.0f/N_EDGES)) * c;
  float add_ = a_d[d];
  float p_self = __expf(fminf(leaky02(a_s[d] + add_ + ae_self), 60.f));
  float dsum = 0.f;
  f32x2 acc[PERH];
  #pragma unroll
  for (int i = 0; i < PERH; ++i) acc[i] = (f32x2){0.f, 0.f};
  if (grp == 0){
    f32x2 pself2 = {p_self, p_self};
    if (PERL == 8){
      uint4 q = *reinterpret_cast<const uint4*>(hb2 + ((unsigned)d << RSH));
      pkfma(acc[0], (f32x2){bflo(q.x), bfhi(q.x)}, pself2);
      pkfma(acc[1], (f32x2){bflo(q.y), bfhi(q.y)}, pself2);
      pkfma(acc[2], (f32x2){bflo(q.z), bfhi(q.z)}, pself2);
      pkfma(acc[3], (f32x2){bflo(q.w), bfhi(q.w)}, pself2);
    } else {
      uint2 q = *reinterpret_cast<const uint2*>(hb2 + ((unsigned)d << RSH));
      pkfma(acc[0], (f32x2){bflo(q.x), bfhi(q.x)}, pself2);
      pkfma(acc[1], (f32x2){bflo(q.y), bfhi(q.y)}, pself2);
    }
  }
  int2 r2 = rowp2[d];
  int e0 = r2.x, e1 = r2.y;
  for (int ch = e0; ch < e1; ch += 64){
    int n = min(64, e1 - ch);
    unsigned off0 = 0;
    float p0 = 0.f;
    if (lane < n){
      unsigned e = edges[ch + lane];
      unsigned s0 = e & 0xFFFFu;
      p0 = __expf(fminf(leaky02(a_s[s0] + add_ + c*bfhi(e)), 60.f));
      off0 = s0 << RSH;
    }
    dsum += p0;
    sp[wv][lane] = make_uint2(off0, __float_as_uint(p0));
    #pragma unroll 4
    for (int e4 = 0; e4 < n; e4 += 16){
      uint2 r0 = sp[wv][e4 + grp];
      uint2 r1 = sp[wv][e4 + 4 + grp];
      uint2 rr2 = sp[wv][e4 + 8 + grp];
      uint2 r3 = sp[wv][e4 + 12 + grp];
      f32x2 a0 = {__uint_as_float(r0.y), __uint_as_float(r0.y)};
      f32x2 a1 = {__uint_as_float(r1.y), __uint_as_float(r1.y)};
      f32x2 a2 = {__uint_as_float(rr2.y), __uint_as_float(rr2.y)};
      f32x2 a3 = {__uint_as_float(r3.y), __uint_as_float(r3.y)};
      if (PERL == 8){
        uint4 q0 = *reinterpret_cast<const uint4*>(hb2 + r0.x);
        uint4 q1 = *reinterpret_cast<const uint4*>(hb2 + r1.x);
        uint4 q2 = *reinterpret_cast<const uint4*>(hb2 + rr2.x);
        uint4 q3 = *reinterpret_cast<const uint4*>(hb2 + r3.x);
        pkfma(acc[0], (f32x2){bflo(q0.x), bfhi(q0.x)}, a0);
        pkfma(acc[1], (f32x2){bflo(q0.y), bfhi(q0.y)}, a0);
        pkfma(acc[2], (f32x2){bflo(q0.z), bfhi(q0.z)}, a0);
        pkfma(acc[3], (f32x2){bflo(q0.w), bfhi(q0.w)}, a0);
        pkfma(acc[0], (f32x2){bflo(q1.x), bfhi(q1.x)}, a1);
        pkfma(acc[1], (f32x2){bflo(q1.y), bfhi(q1.y)}, a1);
        pkfma(acc[2], (f32x2){bflo(q1.z), bfhi(q1.z)}, a1);
        pkfma(acc[3], (f32x2){bflo(q1.w), bfhi(q1.w)}, a1);
        pkfma(acc[0], (f32x2){bflo(q2.x), bfhi(q2.x)}, a2);
        pkfma(acc[1], (f32x2){bflo(q2.y), bfhi(q2.y)}, a2);
        pkfma(acc[2], (f32x2){bflo(q2.z), bfhi(q2.z)}, a2);
        pkfma(acc[3], (f32x2){bflo(q2.w), bfhi(q2.w)}, a2);
        pkfma(acc[0], (f32x2){bflo(q3.x), bfhi(q3.x)}, a3);
        pkfma(acc[1], (f32x2){bflo(q3.y), bfhi(q3.y)}, a3);
        pkfma(acc[2], (f32x2){bflo(q3.z), bfhi(q3.z)}, a3);
        pkfma(acc[3], (f32x2){bflo(q3.w), bfhi(q3.w)}, a3);
      } else {
        uint2 q0 = *reinterpret_cast<const uint2*>(hb2 + r0.x);
        uint2 q1 = *reinterpret_cast<const uint2*>(hb2 + r1.x);
        uint2 q2 = *reinterpret_cast<const uint2*>(hb2 + rr2.x);
        uint2 q3 = *reinterpret_cast<const uint2*>(hb2 + r3.x);
        pkfma(acc[0], (f32x2){bflo(q0.x), bfhi(q0.x)}, a0);
        pkfma(acc[1], (f32x2){bflo(q0.y), bfhi(q0.y)}, a0);
        pkfma(acc[0], (f32x2){bflo(q1.x), bfhi(q1.x)}, a1);
        pkfma(acc[1], (f32x2){bflo(q1.y), bfhi(q1.y)}, a1);
        pkfma(acc[0], (f32x2){bflo(q2.x), bfhi(q2.x)}, a2);
        pkfma(acc[1], (f32x2){bflo(q2.y), bfhi(q2.y)}, a2);
        pkfma(acc[0], (f32x2){bflo(q3.x), bfhi(q3.x)}, a3);
        pkfma(acc[1], (f32x2){bflo(q3.y), bfhi(q3.y)}, a3);
      }
    }
  }
  #pragma unroll
  for (int o = 32; o; o >>= 1) dsum += __shfl_xor(dsum, o);
  float denom = p_self + dsum;
  float inv = 1.0f/denom;
  float vv[PERL];
  #pragma unroll
  for (int i = 0; i < PERH; ++i){
    float v0 = acc[i].x, v1 = acc[i].y;
    v0 += __shfl_xor(v0, 16); v0 += __shfl_xor(v0, 32);
    v1 += __shfl_xor(v1, 16); v1 += __shfl_xor(v1, 32);
    vv[2*i]   = eluf(v0*inv + bias[PERL*sub + 2*i]);
    vv[2*i+1] = eluf(v1*inv + bias[PERL*sub + 2*i+1]);
  }
  if (grp == 0){
    if (W32){
      float* out32 = out32All + (size_t)b*N_NODES*64;
      *reinterpret_cast<float4*>(&out32[(size_t)d*64 + 4*sub]) = make_float4(vv[0],vv[1],vv[2],vv[3]);
    } else {
      unsigned short* outb = outbAll + (size_t)b*N_NODES*128;
      if (PERL == 8){
        uint4 o;
        o.x = (unsigned int)f2bf(vv[0]) | ((unsigned int)f2bf(vv[1]) << 16);
        o.y = (unsigned int)f2bf(vv[2]) | ((unsigned int)f2bf(vv[3]) << 16);
        o.z = (unsigned int)f2bf(vv[4]) | ((unsigned int)f2bf(vv[5]) << 16);
        o.w = (unsigned int)f2bf(vv[6]) | ((unsigned int)f2bf(vv[7]) << 16);
        *reinterpret_cast<uint4*>(&outb[(size_t)d*F + 8*sub]) = o;
      } else {
        uint2 o;
        o.x = (unsigned int)f2bf(vv[0]) | ((unsigned int)f2bf(vv[1]) << 16);
        o.y = (unsigned int)f2bf(vv[2]) | ((unsigned int)f2bf(vv[3]) << 16);
        *reinterpret_cast<uint2*>(&outb[(size_t)d*F + 4*sub]) = o;
      }
    }
  }
}

// ---------- fused mean-pool + final linear ----------
__global__ __launch_bounds__(256) void pool_final_kernel(
    const float* __restrict__ buf0, const int* __restrict__ gb,
    const float* __restrict__ xn0, const float* __restrict__ xn1,
    const float* __restrict__ linW, const float* __restrict__ linb,
    float* __restrict__ out)
{
  int bg = blockIdx.x;
  int b = bg >> 8, g = bg & 255;
  __shared__ float Wl[80*64];
  __shared__ float red[4][64];
  __shared__ float mf[64];
  int tid = threadIdx.x;
  for (int i = tid; i < 80*64; i += 256) Wl[i] = linW[i];
  const float* x = buf0 + (size_t)b*N_NODES*64;
  const int* gbb = gb + b*257;
  int s = gbb[g], e = gbb[g+1];
  int f = tid & 63, rg = tid >> 6;
  float acc = 0.f;
  for (int r = s + rg; r < e; r += 4) acc += x[r*64 + f];
  red[rg][f] = acc;
  __syncthreads();
  if (rg == 0)
    mf[f] = (red[0][f]+red[1][f]+red[2][f]+red[3][f]) / fmaxf((float)(e - s), 1.0f);
  __syncthreads();
  if (tid < 64){
    int j = tid;
    const float* xn = b ? xn1 : xn0;
    float a2 = linb[j];
    #pragma unroll 8
    for (int k = 0; k < 64; ++k) a2 += mf[k] * Wl[k*64 + j];
    #pragma unroll
    for (int k = 0; k < 16; ++k) a2 += xn[g*16+k] * Wl[(64+k)*64 + j];
    out[(size_t)(b*N_GRAPHS + g)*64 + j] = a2;
  }
}

extern "C" void kernel_launch(void* const* d_in, const int* in_sizes, int n_in,
                              void* d_out, int out_size, void* d_ws, size_t ws_size,
                              hipStream_t stream)
{
  const float* x1   = (const float*)d_in[0];
  const float* x2   = (const float*)d_in[1];
  const int*   ei1  = (const int*)d_in[2];
  const int*   ei2  = (const int*)d_in[3];
  const int*   bat1 = (const int*)d_in[4];
  const int*   bat2 = (const int*)d_in[5];
  const float* xn1  = (const float*)d_in[6];
  const float* xn2  = (const float*)d_in[7];
  const float* ec1  = (const float*)d_in[8];
  const float* ec2  = (const float*)d_in[9];
  const float* W[3]   = {(const float*)d_in[10], (const float*)d_in[16], (const float*)d_in[22]};
  const float* as_[3] = {(const float*)d_in[11], (const float*)d_in[17], (const float*)d_in[23]};
  const float* ad_[3] = {(const float*)d_in[12], (const float*)d_in[18], (const float*)d_in[24]};
  const float* We[3]  = {(const float*)d_in[13], (const float*)d_in[19], (const float*)d_in[25]};
  const float* ae[3]  = {(const float*)d_in[14], (const float*)d_in[20], (const float*)d_in[26]};
  const float* bb[3]  = {(const float*)d_in[15], (const float*)d_in[21], (const float*)d_in[27]};
  const float* linW = (const float*)d_in[28];
  const float* linb = (const float*)d_in[29];
  float* out = (float*)d_out;

  char* ws = (char*)d_ws;
  size_t off = 0;
  auto alloc = [&](size_t bytes)->char*{
    char* p = ws + off;
    off = (off + bytes + 255) & ~(size_t)255;
    return p;
  };
  unsigned short* hbA = (unsigned short*)alloc((size_t)2*N_NODES*128*2);
  unsigned short* hbB = (unsigned short*)alloc((size_t)2*N_NODES*128*2);
  float* buf0 = (float*)alloc((size_t)2*N_NODES*64*4);
  float* aS   = (float*)alloc((size_t)2*N_NODES*4);
  float* aD   = (float*)alloc((size_t)2*N_NODES*4);
  int* bcur   = (int*)alloc((size_t)2*NBUCK*CURP*4);
  int2* rowp2 = (int2*)alloc((size_t)2*N_NODES*8);
  uint2* stage = (uint2*)alloc((size_t)2*STAGEN*8);
  unsigned* final_ = (unsigned*)alloc((size_t)2*STAGEN*4);
  float* part = (float*)alloc((size_t)2*NC*4);
  int* gb     = (int*)alloc((size_t)2*257*4);
  float* scal = (float*)alloc(64);

  init_kernel<<<(2*NBUCK + 255)/256, 256, 0, stream>>>(bcur);
  binC_kernel<<<dim3(NC,2), 256, 0, stream>>>(ei1, ei2, ec1, ec2, bcur, stage, part);
  binB_kernel<<<2, 512, 0, stream>>>(part, bat1, bat2,
      We[0], ae[0], We[1], ae[1], We[2], ae[2], gb, scal);
  binD_kernel<<<dim3(NBUCK,2), 256, 0, stream>>>(stage, bcur, final_, rowp2);

  const int AGG = 2*(N_NODES/4);  // 10000 blocks, branch = bid&1

  // layer 1: K=7 -> F=128
  node_linear1_kernel<7,128><<<dim3(1024,2), 256, 0, stream>>>(
      x1, x2, W[0], as_[0], ad_[0], hbA, aS, aD);
  aggregate_kernel<128,false><<<AGG, 256, 0, stream>>>(
      hbA, aS, aD, final_, rowp2, scal, 0, bb[0], nullptr, hbB);

  // layer 2: MFMA 128->128
  gemm_mfma_kernel<128><<<dim3((N_NODES+63)/64,2), 256, 0, stream>>>(
      hbB, W[1], as_[1], ad_[1], hbA, aS, aD);
  aggregate_kernel<128,false><<<AGG, 256, 0, stream>>>(
      hbA, aS, aD, final_, rowp2, scal, 1, bb[1], nullptr, hbB);

  // layer 3: MFMA 128->64
  gemm_mfma_kernel<64><<<dim3((N_NODES+63)/64,2), 256, 0, stream>>>(
      hbB, W[2], as_[2], ad_[2], hbA, aS, aD);
  aggregate_kernel<64,true><<<AGG, 256, 0, stream>>>(
      hbA, aS, aD, final_, rowp2, scal, 2, bb[2], buf0, nullptr);

  pool_final_kernel<<<2*N_GRAPHS, 256, 0, stream>>>(
      buf0, gb, xn1, xn2, linW, linb, out);
}

// Round 16
// 188.449 us; speedup vs baseline: 1.5100x; 1.0611x over previous
//
#include <hip/hip_runtime.h>
#include <hip/hip_bf16.h>
#include <hip/hip_fp16.h>

#define N_NODES 20000
#define N_EDGES 640000
#define N_GRAPHS 256
#define NBUCK 313                    // ceil(20000/64) buckets of 64 dsts
#define NC 160                       // binC blocks per branch
#define EPC 4000                     // edges per binC block (160*4000 = 640000)
#define DCAP 2560                    // per-bucket region capacity (mean 2045 + 11 sigma)
#define CURP 16                      // bcur padding: 16 ints = 64B per bucket
#define STAGEN ((size_t)NBUCK*DCAP)  // 801,280 records per branch

typedef short bf16v __attribute__((ext_vector_type(8)));   // 8 bf16 (4 VGPRs)
typedef float f32x4 __attribute__((ext_vector_type(4)));
typedef float f32x2 __attribute__((ext_vector_type(2)));

__device__ __forceinline__ float leaky02(float x){ return x > 0.f ? x : 0.2f*x; }
__device__ __forceinline__ float eluf(float x){ return x > 0.f ? x : (__expf(x) - 1.f); }
__device__ __forceinline__ unsigned short f2bf(float x){
  __hip_bfloat16 t = __float2bfloat16(x);
  return *reinterpret_cast<unsigned short*>(&t);
}
__device__ __forceinline__ float bflo(unsigned int u){ return __uint_as_float(u << 16); }
__device__ __forceinline__ float bfhi(unsigned int u){ return __uint_as_float(u & 0xffff0000u); }
__device__ __forceinline__ void pkfma(f32x2& acc, f32x2 a, f32x2 b){
  asm volatile("v_pk_fma_f32 %0, %1, %2, %0" : "+v"(acc) : "v"(a), "v"(b));
}

// ---------- init: bucket cursors at region bases ----------
__global__ void init_kernel(int* __restrict__ bcur){
  int i = blockIdx.x*256 + threadIdx.x;       // i in [0, 2*NBUCK)
  if (i < 2*NBUCK){
    int b = i / NBUCK, j = i % NBUCK;
    bcur[((size_t)b*NBUCK + j)*CURP] = j*DCAP;
  }
}

// ---------- binC: histogram-then-place LDS binning into padded regions + ec partials ----------
__global__ __launch_bounds__(256) void binC_kernel(
    const int* __restrict__ ei0, const int* __restrict__ ei1,
    const float* __restrict__ ec0, const float* __restrict__ ec1,
    int* __restrict__ bcur, uint2* __restrict__ stage, float* __restrict__ part)
{
  int b = blockIdx.y;
  const int* srcp = (b ? ei1 : ei0);
  const int* dstp = srcp + N_EDGES;
  const float* ec = b ? ec1 : ec0;
  int* bcurb = bcur + (size_t)b*NBUCK*CURP;
  uint2* stageb = stage + (size_t)b*STAGEN;
  __shared__ uint2 recs[EPC];
  __shared__ int hist[NBUCK], rbase[NBUCK], rcur[NBUCK];
  int tid = threadIdx.x;
  for (int j = tid; j < NBUCK; j += 256){ hist[j] = 0; rcur[j] = 0; }
  __syncthreads();
  int e0 = blockIdx.x*EPC;
  float v = 0.f;
  for (int r = tid; r < EPC; r += 256){
    int i = e0 + r;
    int d = dstp[i];
    int bk = d >> 6;
    uint2 rec;
    rec.x = (unsigned)srcp[i] | ((unsigned)(d & 63) << 16);
    float e = ec[i];
    v += e;
    rec.y = ((unsigned)f2bf(e) << 16) | (unsigned)bk;
    recs[r] = rec;
    atomicAdd(&hist[bk], 1);
  }
  __syncthreads();
  for (int j = tid; j < NBUCK; j += 256){
    int h = hist[j];
    rbase[j] = h ? atomicAdd(&bcurb[j*CURP], h) : 0;
  }
  __syncthreads();
  for (int r = tid; r < EPC; r += 256){
    uint2 rc = recs[r];
    int bk = (int)(rc.y & 0xFFFFu);
    int p = rbase[bk] + atomicAdd(&rcur[bk], 1);
    if (p < (bk + 1)*DCAP) stageb[p] = rc;   // overflow clamp (11-sigma margin)
  }
  // ec partial sum
  for (int o = 32; o; o >>= 1) v += __shfl_down(v, o);
  __shared__ float wr[4];
  int lane = tid & 63, wv = tid >> 6;
  if (lane == 0) wr[wv] = v;
  __syncthreads();
  if (tid == 0) part[b*NC + blockIdx.x] = wr[0]+wr[1]+wr[2]+wr[3];
}

// ---------- binB: ec total + graph bounds + prep_c (runs after binC) ----------
__global__ __launch_bounds__(512) void binB_kernel(
    const float* __restrict__ part,
    const int* __restrict__ bat0, const int* __restrict__ bat1,
    const float* __restrict__ We1, const float* __restrict__ ae1,
    const float* __restrict__ We2, const float* __restrict__ ae2,
    const float* __restrict__ We3, const float* __restrict__ ae3,
    int* __restrict__ gb, float* __restrict__ scal)
{
  int b = blockIdx.x;
  int tid = threadIdx.x;
  if (b == 0){
    int wv = tid >> 6, lane = tid & 63;
    if (wv < 3){
      const float* We = wv==0 ? We1 : (wv==1 ? We2 : We3);
      const float* ae = wv==0 ? ae1 : (wv==1 ? ae2 : ae3);
      int F = (wv==2) ? 64 : 128;
      float s = 0.f;
      for (int i = lane; i < F; i += 64) s += We[i]*ae[i];
      for (int o = 32; o; o >>= 1) s += __shfl_down(s, o);
      if (lane == 0) scal[2+wv] = s;
    }
  }
  {
    float s = 0.f;
    for (int i = tid; i < NC; i += 512) s += part[b*NC + i];
    for (int o = 32; o; o >>= 1) s += __shfl_down(s, o);
    __shared__ float fr[8];
    if ((tid & 63) == 0) fr[tid >> 6] = s;
    __syncthreads();
    if (tid == 0){
      float t = 0.f;
      for (int i = 0; i < 8; ++i) t += fr[i];
      scal[b] = t;
    }
  }
  {
    const int* batch = b ? bat1 : bat0;
    int* gbb = gb + b*257;
    if (tid <= N_GRAPHS){
      int g = tid, lo = 0, hi = N_NODES;
      while (lo < hi){ int mid = (lo+hi) >> 1; if (batch[mid] < g) lo = mid+1; else hi = mid; }
      gbb[g] = lo;
    }
  }
}

// ---------- binD: per-bucket counting sort -> padded CSR + int2 rowp2 ----------
__global__ __launch_bounds__(256) void binD_kernel(
    const uint2* __restrict__ stage, const int* __restrict__ bcur,
    unsigned* __restrict__ final_, int2* __restrict__ rowp2)
{
  int b = blockIdx.y;
  int g = blockIdx.x;
  int tid = threadIdx.x;
  const uint2* stageb = stage + (size_t)b*STAGEN;
  unsigned* finb = final_ + (size_t)b*STAGEN;
  int2* rowb = rowp2 + (size_t)b*N_NODES;
  int cb = g*DCAP;
  int n = min(bcur[((size_t)b*NBUCK + g)*CURP] - cb, DCAP);
  __shared__ uint2 recs[DCAP];
  __shared__ int cnt64[64], cur64[64], off64[64];
  if (tid < 64) cnt64[tid] = 0;
  __syncthreads();
  for (int r = tid; r < n; r += 256){
    uint2 rc = stageb[cb + r];
    recs[r] = rc;
    atomicAdd(&cnt64[(rc.x >> 16) & 63], 1);
  }
  __syncthreads();
  if (tid == 0){
    int acc = 0;
    for (int dl = 0; dl < 64; ++dl){
      off64[dl] = acc; cur64[dl] = acc; acc += cnt64[dl];
    }
  }
  __syncthreads();
  int nd = min(64, N_NODES - g*64);
  if (tid < nd)
    rowb[g*64 + tid] = make_int2(cb + off64[tid], cb + off64[tid] + cnt64[tid]);
  for (int r = tid; r < n; r += 256){
    uint2 rc = recs[r];
    int dl = (rc.x >> 16) & 63;
    int p = atomicAdd(&cur64[dl], 1);
    finb[cb + p] = (rc.y & 0xFFFF0000u) | (rc.x & 0xFFFFu);
  }
}

// ---------- layer 1: K=7 scalar GEMM + att dots, bf16 out, both branches ----------
template<int K, int F>
__global__ __launch_bounds__(256) void node_linear1_kernel(
    const float* __restrict__ x0, const float* __restrict__ x1,
    const float* __restrict__ W,
    const float* __restrict__ atts, const float* __restrict__ attd,
    unsigned short* __restrict__ hbAll, float* __restrict__ aSAll, float* __restrict__ aDAll)
{
  int b = blockIdx.y;
  const float* x = b ? x1 : x0;
  unsigned short* hb = hbAll + (size_t)b*N_NODES*128;
  float* a_s = aSAll + b*N_NODES;
  float* a_d = aDAll + b*N_NODES;
  constexpr int ROWS = 256 / F; // 2
  __shared__ float Wl[K*F];
  __shared__ float xl[ROWS*K];
  __shared__ float swv[4], dwv[4];
  int tid = threadIdx.x;
  for (int i = tid; i < K*F; i += 256) Wl[i] = W[i];
  int f = tid % F;
  int lr = tid / F;
  float vs = atts[f], vd = attd[f];
  const int ntiles = (N_NODES + ROWS - 1)/ROWS;
  for (int t = blockIdx.x; t < ntiles; t += gridDim.x){
    int r0 = t*ROWS;
    __syncthreads();
    for (int i = tid; i < ROWS*K; i += 256){
      int r = i / K, k = i % K;
      int row = r0 + r;
      xl[i] = (row < N_NODES) ? x[row*K + k] : 0.f;
    }
    __syncthreads();
    float acc = 0.f;
    #pragma unroll
    for (int k = 0; k < K; ++k) acc += xl[lr*K + k] * Wl[k*F + f];
    int row = r0 + lr;
    if (row < N_NODES) hb[row*F + f] = f2bf(acc);
    float s = acc*vs, d = acc*vd;
    #pragma unroll
    for (int o = 32; o; o >>= 1){ s += __shfl_down(s, o); d += __shfl_down(d, o); }
    int wv = tid >> 6;
    if ((tid & 63) == 0){ swv[wv] = s; dwv[wv] = d; }
    __syncthreads();
    if (f == 0 && row < N_NODES){
      a_s[row] = swv[2*lr] + swv[2*lr+1];
      a_d[row] = dwv[2*lr] + dwv[2*lr+1];
    }
  }
}

// ---------- layers 2/3: MFMA GEMM (A bf16 -> bf16 out), fused att dots ----------
template<int F>
__global__ __launch_bounds__(256) void gemm_mfma_kernel(
    const unsigned short* __restrict__ AAll, const float* __restrict__ W,
    const float* __restrict__ atts, const float* __restrict__ attd,
    unsigned short* __restrict__ hbAll, float* __restrict__ aSAll, float* __restrict__ aDAll)
{
  int b = blockIdx.y;
  const unsigned short* A = AAll + (size_t)b*N_NODES*128;
  unsigned short* hb = hbAll + (size_t)b*N_NODES*128;
  float* a_s = aSAll + b*N_NODES;
  float* a_d = aDAll + b*N_NODES;
  constexpr int NT = F/16;
  constexpr int KP = 136;
  __shared__ unsigned short Wb[F*KP];
  int tid = threadIdx.x;
  for (int idx = tid; idx < 128*F; idx += 256){
    int k = idx / F, col = idx % F;
    Wb[col*KP + k] = f2bf(W[idx]);
  }
  __syncthreads();
  int wave = tid >> 6, lane = tid & 63;
  int r0w = blockIdx.x*64 + wave*16;
  int arow = r0w + (lane & 15);
  bool av = arow < N_NODES;
  f32x4 acc[NT];
  #pragma unroll
  for (int nt = 0; nt < NT; ++nt) acc[nt] = 0.f;
  #pragma unroll
  for (int step = 0; step < 4; ++step){
    int kbase = step*32 + (lane>>4)*8;
    uint4 araw = av ? *reinterpret_cast<const uint4*>(&A[(size_t)arow*128 + kbase])
                    : make_uint4(0,0,0,0);
    bf16v af = __builtin_bit_cast(bf16v, araw);
    #pragma unroll
    for (int nt = 0; nt < NT; ++nt){
      uint4 braw = *reinterpret_cast<const uint4*>(&Wb[(nt*16 + (lane&15))*KP + kbase]);
      bf16v bfr = __builtin_bit_cast(bf16v, braw);
      acc[nt] = __builtin_amdgcn_mfma_f32_16x16x32_bf16(af, bfr, acc[nt], 0, 0, 0);
    }
  }
  float ps[4] = {0,0,0,0}, pd[4] = {0,0,0,0};
  #pragma unroll
  for (int nt = 0; nt < NT; ++nt){
    int col = nt*16 + (lane&15);
    float vs = atts[col], vd = attd[col];
    #pragma unroll
    for (int reg = 0; reg < 4; ++reg){
      int row = r0w + (lane>>4)*4 + reg;
      float v = acc[nt][reg];
      if (row < N_NODES) hb[(size_t)row*F + col] = f2bf(v);
      ps[reg] += v*vs;
      pd[reg] += v*vd;
    }
  }
  #pragma unroll
  for (int reg = 0; reg < 4; ++reg){
    float s = ps[reg], d = pd[reg];
    #pragma unroll
    for (int o = 1; o < 16; o <<= 1){ s += __shfl_xor(s, o); d += __shfl_xor(d, o); }
    int row = r0w + (lane>>4)*4 + reg;
    if ((lane & 15) == 0 && row < N_NODES){ a_s[row] = s; a_d[row] = d; }
  }
}

// ---------- aggregation v6: 2 dsts/wave (32 lanes each), byte-offset staging, XCD parity ----------
// grid: 1-D, 2*(N_NODES/8) blocks; branch = bid&1. Each wave: dstA = lanes 0-31, dstB = 32-63.
template<int F, bool W32>
__global__ __launch_bounds__(256) void aggregate_kernel(
    const unsigned short* __restrict__ hbAll,
    const float* __restrict__ aSAll, const float* __restrict__ aDAll,
    const unsigned* __restrict__ edgAll, const int2* __restrict__ rowp2All,
    const float* __restrict__ scal, int l,
    const float* __restrict__ bias,
    float* __restrict__ out32All, unsigned short* __restrict__ outbAll)
{
  constexpr int PERL = F/16;   // 8 (F=128) or 4 (F=64)
  constexpr int PERH = PERL/2;
  constexpr int RSH = (F == 128) ? 8 : 7;
  constexpr int SUBB = (F == 128) ? 16 : 8;
  int bid = blockIdx.x;
  int b = bid & 1;
  const unsigned short* hb = hbAll + (size_t)b*N_NODES*128;
  const float* a_s = aSAll + b*N_NODES;
  const float* a_d = aDAll + b*N_NODES;
  const unsigned* edges = edgAll + (size_t)b*STAGEN;
  const int2* rowp2 = rowp2All + (size_t)b*N_NODES;
  __shared__ uint2 sp[4][64];
  int wv = threadIdx.x >> 6;
  int lane = threadIdx.x & 63;
  int half = lane >> 5;        // 0 = dstA, 1 = dstB
  int hl = lane & 31;
  int d = (bid >> 1)*8 + wv*2 + half;   // 20000 % 8 == 0: always valid
  int sub = hl & 15, grp = hl >> 4;     // grp in {0,1}
  const char* hb2 = (const char*)hb + sub*SUBB;
  float c = scal[2+l];
  float ae_self = (scal[b] * (1.0f/N_EDGES)) * c;
  float add_ = a_d[d];
  float p_self = __expf(fminf(leaky02(a_s[d] + add_ + ae_self), 60.f));
  float dsum = 0.f;
  f32x2 acc[PERH];
  #pragma unroll
  for (int i = 0; i < PERH; ++i) acc[i] = (f32x2){0.f, 0.f};
  if (grp == 0){
    f32x2 pself2 = {p_self, p_self};
    if (PERL == 8){
      uint4 q = *reinterpret_cast<const uint4*>(hb2 + ((unsigned)d << RSH));
      pkfma(acc[0], (f32x2){bflo(q.x), bfhi(q.x)}, pself2);
      pkfma(acc[1], (f32x2){bflo(q.y), bfhi(q.y)}, pself2);
      pkfma(acc[2], (f32x2){bflo(q.z), bfhi(q.z)}, pself2);
      pkfma(acc[3], (f32x2){bflo(q.w), bfhi(q.w)}, pself2);
    } else {
      uint2 q = *reinterpret_cast<const uint2*>(hb2 + ((unsigned)d << RSH));
      pkfma(acc[0], (f32x2){bflo(q.x), bfhi(q.x)}, pself2);
      pkfma(acc[1], (f32x2){bflo(q.y), bfhi(q.y)}, pself2);
    }
  }
  int2 r2 = rowp2[d];
  int e0 = r2.x, deg = r2.y - r2.x;
  int degmax = max(deg, __shfl_xor(deg, 32));
  for (int ch = 0; ch < degmax; ch += 32){
    int n = deg - ch;                     // this half's remaining (may be <=0)
    // phase 1: 32 lanes per dst compute p in parallel
    unsigned off0 = 0;
    float p0 = 0.f;
    if (hl < n){
      unsigned e = edges[e0 + ch + hl];
      unsigned s0 = e & 0xFFFFu;
      p0 = __expf(fminf(leaky02(a_s[s0] + add_ + c*bfhi(e)), 60.f));
      off0 = s0 << RSH;
    }
    dsum += p0;
    sp[wv][lane] = make_uint2(off0, __float_as_uint(p0));
    // phase 2: 8 edges/dst per step (4 wave-wide loads = 16 edge-rows in flight)
    int nmax = min(32, degmax - ch);
    #pragma unroll 4
    for (int e8 = 0; e8 < nmax; e8 += 8){
      int base = half*32 + e8 + grp;
      uint2 r0 = sp[wv][base];
      uint2 r1 = sp[wv][base + 2];
      uint2 rr2 = sp[wv][base + 4];
      uint2 r3 = sp[wv][base + 6];
      f32x2 a0 = {__uint_as_float(r0.y), __uint_as_float(r0.y)};
      f32x2 a1 = {__uint_as_float(r1.y), __uint_as_float(r1.y)};
      f32x2 a2 = {__uint_as_float(rr2.y), __uint_as_float(rr2.y)};
      f32x2 a3 = {__uint_as_float(r3.y), __uint_as_float(r3.y)};
      if (PERL == 8){
        uint4 q0 = *reinterpret_cast<const uint4*>(hb2 + r0.x);
        uint4 q1 = *reinterpret_cast<const uint4*>(hb2 + r1.x);
        uint4 q2 = *reinterpret_cast<const uint4*>(hb2 + rr2.x);
        uint4 q3 = *reinterpret_cast<const uint4*>(hb2 + r3.x);
        pkfma(acc[0], (f32x2){bflo(q0.x), bfhi(q0.x)}, a0);
        pkfma(acc[1], (f32x2){bflo(q0.y), bfhi(q0.y)}, a0);
        pkfma(acc[2], (f32x2){bflo(q0.z), bfhi(q0.z)}, a0);
        pkfma(acc[3], (f32x2){bflo(q0.w), bfhi(q0.w)}, a0);
        pkfma(acc[0], (f32x2){bflo(q1.x), bfhi(q1.x)}, a1);
        pkfma(acc[1], (f32x2){bflo(q1.y), bfhi(q1.y)}, a1);
        pkfma(acc[2], (f32x2){bflo(q1.z), bfhi(q1.z)}, a1);
        pkfma(acc[3], (f32x2){bflo(q1.w), bfhi(q1.w)}, a1);
        pkfma(acc[0], (f32x2){bflo(q2.x), bfhi(q2.x)}, a2);
        pkfma(acc[1], (f32x2){bflo(q2.y), bfhi(q2.y)}, a2);
        pkfma(acc[2], (f32x2){bflo(q2.z), bfhi(q2.z)}, a2);
        pkfma(acc[3], (f32x2){bflo(q2.w), bfhi(q2.w)}, a2);
        pkfma(acc[0], (f32x2){bflo(q3.x), bfhi(q3.x)}, a3);
        pkfma(acc[1], (f32x2){bflo(q3.y), bfhi(q3.y)}, a3);
        pkfma(acc[2], (f32x2){bflo(q3.z), bfhi(q3.z)}, a3);
        pkfma(acc[3], (f32x2){bflo(q3.w), bfhi(q3.w)}, a3);
      } else {
        uint2 q0 = *reinterpret_cast<const uint2*>(hb2 + r0.x);
        uint2 q1 = *reinterpret_cast<const uint2*>(hb2 + r1.x);
        uint2 q2 = *reinterpret_cast<const uint2*>(hb2 + rr2.x);
        uint2 q3 = *reinterpret_cast<const uint2*>(hb2 + r3.x);
        pkfma(acc[0], (f32x2){bflo(q0.x), bfhi(q0.x)}, a0);
        pkfma(acc[1], (f32x2){bflo(q0.y), bfhi(q0.y)}, a0);
        pkfma(acc[0], (f32x2){bflo(q1.x), bfhi(q1.x)}, a1);
        pkfma(acc[1], (f32x2){bflo(q1.y), bfhi(q1.y)}, a1);
        pkfma(acc[0], (f32x2){bflo(q2.x), bfhi(q2.x)}, a2);
        pkfma(acc[1], (f32x2){bflo(q2.y), bfhi(q2.y)}, a2);
        pkfma(acc[0], (f32x2){bflo(q3.x), bfhi(q3.x)}, a3);
        pkfma(acc[1], (f32x2){bflo(q3.y), bfhi(q3.y)}, a3);
      }
    }
  }
  // denom reduce within 32-lane half (offsets 16..1 stay inside the half)
  #pragma unroll
  for (int o = 16; o; o >>= 1) dsum += __shfl_xor(dsum, o);
  float denom = p_self + dsum;
  float inv = 1.0f/denom;
  float vv[PERL];
  #pragma unroll
  for (int i = 0; i < PERH; ++i){
    float v0 = acc[i].x, v1 = acc[i].y;
    v0 += __shfl_xor(v0, 16);     // combine grp0+grp1 within the half
    v1 += __shfl_xor(v1, 16);
    vv[2*i]   = eluf(v0*inv + bias[PERL*sub + 2*i]);
    vv[2*i+1] = eluf(v1*inv + bias[PERL*sub + 2*i+1]);
  }
  if (grp == 0){
    if (W32){
      float* out32 = out32All + (size_t)b*N_NODES*64;
      *reinterpret_cast<float4*>(&out32[(size_t)d*64 + 4*sub]) = make_float4(vv[0],vv[1],vv[2],vv[3]);
    } else {
      unsigned short* outb = outbAll + (size_t)b*N_NODES*128;
      if (PERL == 8){
        uint4 o;
        o.x = (unsigned int)f2bf(vv[0]) | ((unsigned int)f2bf(vv[1]) << 16);
        o.y = (unsigned int)f2bf(vv[2]) | ((unsigned int)f2bf(vv[3]) << 16);
        o.z = (unsigned int)f2bf(vv[4]) | ((unsigned int)f2bf(vv[5]) << 16);
        o.w = (unsigned int)f2bf(vv[6]) | ((unsigned int)f2bf(vv[7]) << 16);
        *reinterpret_cast<uint4*>(&outb[(size_t)d*F + 8*sub]) = o;
      } else {
        uint2 o;
        o.x = (unsigned int)f2bf(vv[0]) | ((unsigned int)f2bf(vv[1]) << 16);
        o.y = (unsigned int)f2bf(vv[2]) | ((unsigned int)f2bf(vv[3]) << 16);
        *reinterpret_cast<uint2*>(&outb[(size_t)d*F + 4*sub]) = o;
      }
    }
  }
}

// ---------- fused mean-pool + final linear ----------
__global__ __launch_bounds__(256) void pool_final_kernel(
    const float* __restrict__ buf0, const int* __restrict__ gb,
    const float* __restrict__ xn0, const float* __restrict__ xn1,
    const float* __restrict__ linW, const float* __restrict__ linb,
    float* __restrict__ out)
{
  int bg = blockIdx.x;
  int b = bg >> 8, g = bg & 255;
  __shared__ float Wl[80*64];
  __shared__ float red[4][64];
  __shared__ float mf[64];
  int tid = threadIdx.x;
  for (int i = tid; i < 80*64; i += 256) Wl[i] = linW[i];
  const float* x = buf0 + (size_t)b*N_NODES*64;
  const int* gbb = gb + b*257;
  int s = gbb[g], e = gbb[g+1];
  int f = tid & 63, rg = tid >> 6;
  float acc = 0.f;
  for (int r = s + rg; r < e; r += 4) acc += x[r*64 + f];
  red[rg][f] = acc;
  __syncthreads();
  if (rg == 0)
    mf[f] = (red[0][f]+red[1][f]+red[2][f]+red[3][f]) / fmaxf((float)(e - s), 1.0f);
  __syncthreads();
  if (tid < 64){
    int j = tid;
    const float* xn = b ? xn1 : xn0;
    float a2 = linb[j];
    #pragma unroll 8
    for (int k = 0; k < 64; ++k) a2 += mf[k] * Wl[k*64 + j];
    #pragma unroll
    for (int k = 0; k < 16; ++k) a2 += xn[g*16+k] * Wl[(64+k)*64 + j];
    out[(size_t)(b*N_GRAPHS + g)*64 + j] = a2;
  }
}

extern "C" void kernel_launch(void* const* d_in, const int* in_sizes, int n_in,
                              void* d_out, int out_size, void* d_ws, size_t ws_size,
                              hipStream_t stream)
{
  const float* x1   = (const float*)d_in[0];
  const float* x2   = (const float*)d_in[1];
  const int*   ei1  = (const int*)d_in[2];
  const int*   ei2  = (const int*)d_in[3];
  const int*   bat1 = (const int*)d_in[4];
  const int*   bat2 = (const int*)d_in[5];
  const float* xn1  = (const float*)d_in[6];
  const float* xn2  = (const float*)d_in[7];
  const float* ec1  = (const float*)d_in[8];
  const float* ec2  = (const float*)d_in[9];
  const float* W[3]   = {(const float*)d_in[10], (const float*)d_in[16], (const float*)d_in[22]};
  const float* as_[3] = {(const float*)d_in[11], (const float*)d_in[17], (const float*)d_in[23]};
  const float* ad_[3] = {(const float*)d_in[12], (const float*)d_in[18], (const float*)d_in[24]};
  const float* We[3]  = {(const float*)d_in[13], (const float*)d_in[19], (const float*)d_in[25]};
  const float* ae[3]  = {(const float*)d_in[14], (const float*)d_in[20], (const float*)d_in[26]};
  const float* bb[3]  = {(const float*)d_in[15], (const float*)d_in[21], (const float*)d_in[27]};
  const float* linW = (const float*)d_in[28];
  const float* linb = (const float*)d_in[29];
  float* out = (float*)d_out;

  char* ws = (char*)d_ws;
  size_t off = 0;
  auto alloc = [&](size_t bytes)->char*{
    char* p = ws + off;
    off = (off + bytes + 255) & ~(size_t)255;
    return p;
  };
  unsigned short* hbA = (unsigned short*)alloc((size_t)2*N_NODES*128*2);
  unsigned short* hbB = (unsigned short*)alloc((size_t)2*N_NODES*128*2);
  float* buf0 = (float*)alloc((size_t)2*N_NODES*64*4);
  float* aS   = (float*)alloc((size_t)2*N_NODES*4);
  float* aD   = (float*)alloc((size_t)2*N_NODES*4);
  int* bcur   = (int*)alloc((size_t)2*NBUCK*CURP*4);
  int2* rowp2 = (int2*)alloc((size_t)2*N_NODES*8);
  uint2* stage = (uint2*)alloc((size_t)2*STAGEN*8);
  unsigned* final_ = (unsigned*)alloc((size_t)2*STAGEN*4);
  float* part = (float*)alloc((size_t)2*NC*4);
  int* gb     = (int*)alloc((size_t)2*257*4);
  float* scal = (float*)alloc(64);

  init_kernel<<<(2*NBUCK + 255)/256, 256, 0, stream>>>(bcur);
  binC_kernel<<<dim3(NC,2), 256, 0, stream>>>(ei1, ei2, ec1, ec2, bcur, stage, part);
  binB_kernel<<<2, 512, 0, stream>>>(part, bat1, bat2,
      We[0], ae[0], We[1], ae[1], We[2], ae[2], gb, scal);
  binD_kernel<<<dim3(NBUCK,2), 256, 0, stream>>>(stage, bcur, final_, rowp2);

  const int AGG = 2*(N_NODES/8);  // 5000 blocks, branch = bid&1, 8 dsts/block

  // layer 1: K=7 -> F=128
  node_linear1_kernel<7,128><<<dim3(1024,2), 256, 0, stream>>>(
      x1, x2, W[0], as_[0], ad_[0], hbA, aS, aD);
  aggregate_kernel<128,false><<<AGG, 256, 0, stream>>>(
      hbA, aS, aD, final_, rowp2, scal, 0, bb[0], nullptr, hbB);

  // layer 2: MFMA 128->128
  gemm_mfma_kernel<128><<<dim3((N_NODES+63)/64,2), 256, 0, stream>>>(
      hbB, W[1], as_[1], ad_[1], hbA, aS, aD);
  aggregate_kernel<128,false><<<AGG, 256, 0, stream>>>(
      hbA, aS, aD, final_, rowp2, scal, 1, bb[1], nullptr, hbB);

  // layer 3: MFMA 128->64
  gemm_mfma_kernel<64><<<dim3((N_NODES+63)/64,2), 256, 0, stream>>>(
      hbB, W[2], as_[2], ad_[2], hbA, aS, aD);
  aggregate_kernel<64,true><<<AGG, 256, 0, stream>>>(
      hbA, aS, aD, final_, rowp2, scal, 2, bb[2], buf0, nullptr);

  pool_final_kernel<<<2*N_GRAPHS, 256, 0, stream>>>(
      buf0, gb, xn1, xn2, linW, linb, out);
}

// Round 17
// 180.819 us; speedup vs baseline: 1.5737x; 1.0422x over previous
//
#include <hip/hip_runtime.h>
#include <hip/hip_bf16.h>
#include <hip/hip_fp16.h>

#define N_NODES 20000
#define N_EDGES 640000
#define N_GRAPHS 256
#define NBUCK 313                    // ceil(20000/64) buckets of 64 dsts
#define NC 160                       // binC blocks per branch
#define EPC 4000                     // edges per binC block (160*4000 = 640000)
#define DCAP 2560                    // per-bucket region capacity (mean 2045 + 11 sigma)
#define CURP 16                      // bcur padding: 16 ints = 64B per bucket
#define STAGEN ((size_t)NBUCK*DCAP)  // 801,280 records per branch

typedef short bf16v __attribute__((ext_vector_type(8)));   // 8 bf16 (4 VGPRs)
typedef float f32x4 __attribute__((ext_vector_type(4)));
typedef float f32x2 __attribute__((ext_vector_type(2)));

__device__ __forceinline__ float leaky02(float x){ return x > 0.f ? x : 0.2f*x; }
__device__ __forceinline__ float eluf(float x){ return x > 0.f ? x : (__expf(x) - 1.f); }
__device__ __forceinline__ unsigned short f2bf(float x){
  __hip_bfloat16 t = __float2bfloat16(x);
  return *reinterpret_cast<unsigned short*>(&t);
}
__device__ __forceinline__ float bflo(unsigned int u){ return __uint_as_float(u << 16); }
__device__ __forceinline__ float bfhi(unsigned int u){ return __uint_as_float(u & 0xffff0000u); }
__device__ __forceinline__ float bfs(unsigned short u){ return __uint_as_float(((unsigned)u) << 16); }
__device__ __forceinline__ void pkfma(f32x2& acc, f32x2 a, f32x2 b){
  asm volatile("v_pk_fma_f32 %0, %1, %2, %0" : "+v"(acc) : "v"(a), "v"(b));
}

// ---------- setup: bucket cursors + graph bounds + prep_c ----------
__global__ __launch_bounds__(512) void setup_kernel(
    const int* __restrict__ bat0, const int* __restrict__ bat1,
    const float* __restrict__ We1, const float* __restrict__ ae1,
    const float* __restrict__ We2, const float* __restrict__ ae2,
    const float* __restrict__ We3, const float* __restrict__ ae3,
    int* __restrict__ bcur, int* __restrict__ gb, float* __restrict__ scal)
{
  int b = blockIdx.x;
  int tid = threadIdx.x;
  if (tid < NBUCK) bcur[((size_t)b*NBUCK + tid)*CURP] = tid*DCAP;
  {
    const int* batch = b ? bat1 : bat0;
    int* gbb = gb + b*257;
    if (tid <= N_GRAPHS){
      int g = tid, lo = 0, hi = N_NODES;
      while (lo < hi){ int mid = (lo+hi) >> 1; if (batch[mid] < g) lo = mid+1; else hi = mid; }
      gbb[g] = lo;
    }
  }
  if (b == 0){
    int wv = tid >> 6, lane = tid & 63;
    if (wv < 3){
      const float* We = wv==0 ? We1 : (wv==1 ? We2 : We3);
      const float* ae = wv==0 ? ae1 : (wv==1 ? ae2 : ae3);
      int F = (wv==2) ? 64 : 128;
      float s = 0.f;
      for (int i = lane; i < F; i += 64) s += We[i]*ae[i];
      for (int o = 32; o; o >>= 1) s += __shfl_down(s, o);
      if (lane == 0) scal[2+wv] = s;
    }
  }
}

// ---------- binC: histogram-then-place LDS binning into padded regions + ec partials ----------
__global__ __launch_bounds__(256) void binC_kernel(
    const int* __restrict__ ei0, const int* __restrict__ ei1,
    const float* __restrict__ ec0, const float* __restrict__ ec1,
    int* __restrict__ bcur, uint2* __restrict__ stage, float* __restrict__ part)
{
  int b = blockIdx.y;
  const int* srcp = (b ? ei1 : ei0);
  const int* dstp = srcp + N_EDGES;
  const float* ec = b ? ec1 : ec0;
  int* bcurb = bcur + (size_t)b*NBUCK*CURP;
  uint2* stageb = stage + (size_t)b*STAGEN;
  __shared__ uint2 recs[EPC];
  __shared__ int hist[NBUCK], rbase[NBUCK], rcur[NBUCK];
  int tid = threadIdx.x;
  for (int j = tid; j < NBUCK; j += 256){ hist[j] = 0; rcur[j] = 0; }
  __syncthreads();
  int e0 = blockIdx.x*EPC;
  float v = 0.f;
  for (int r = tid; r < EPC; r += 256){
    int i = e0 + r;
    int d = dstp[i];
    int bk = d >> 6;
    uint2 rec;
    rec.x = (unsigned)srcp[i] | ((unsigned)(d & 63) << 16);
    float e = ec[i];
    v += e;
    rec.y = ((unsigned)f2bf(e) << 16) | (unsigned)bk;
    recs[r] = rec;
    atomicAdd(&hist[bk], 1);
  }
  __syncthreads();
  for (int j = tid; j < NBUCK; j += 256){
    int h = hist[j];
    rbase[j] = h ? atomicAdd(&bcurb[j*CURP], h) : 0;
  }
  __syncthreads();
  for (int r = tid; r < EPC; r += 256){
    uint2 rc = recs[r];
    int bk = (int)(rc.y & 0xFFFFu);
    int p = rbase[bk] + atomicAdd(&rcur[bk], 1);
    if (p < (bk + 1)*DCAP) stageb[p] = rc;   // overflow clamp (11-sigma margin)
  }
  // ec partial sum
  for (int o = 32; o; o >>= 1) v += __shfl_down(v, o);
  __shared__ float wr[4];
  int lane = tid & 63, wv = tid >> 6;
  if (lane == 0) wr[wv] = v;
  __syncthreads();
  if (tid == 0) part[b*NC + blockIdx.x] = wr[0]+wr[1]+wr[2]+wr[3];
}

// ---------- binD: per-bucket counting sort -> padded CSR + int2 rowp2 (+ ec total in g==0) ----------
__global__ __launch_bounds__(256) void binD_kernel(
    const uint2* __restrict__ stage, const int* __restrict__ bcur,
    const float* __restrict__ part,
    unsigned* __restrict__ final_, int2* __restrict__ rowp2, float* __restrict__ scal)
{
  int b = blockIdx.y;
  int g = blockIdx.x;
  int tid = threadIdx.x;
  if (g == 0){   // ec total for this branch
    float s = 0.f;
    for (int i = tid; i < NC; i += 256) s += part[b*NC + i];
    for (int o = 32; o; o >>= 1) s += __shfl_down(s, o);
    __shared__ float fr[4];
    if ((tid & 63) == 0) fr[tid >> 6] = s;
    __syncthreads();
    if (tid == 0) scal[b] = fr[0]+fr[1]+fr[2]+fr[3];
  }
  const uint2* stageb = stage + (size_t)b*STAGEN;
  unsigned* finb = final_ + (size_t)b*STAGEN;
  int2* rowb = rowp2 + (size_t)b*N_NODES;
  int cb = g*DCAP;
  int n = min(bcur[((size_t)b*NBUCK + g)*CURP] - cb, DCAP);
  __shared__ uint2 recs[DCAP];
  __shared__ int cnt64[64], cur64[64], off64[64];
  if (tid < 64) cnt64[tid] = 0;
  __syncthreads();
  for (int r = tid; r < n; r += 256){
    uint2 rc = stageb[cb + r];
    recs[r] = rc;
    atomicAdd(&cnt64[(rc.x >> 16) & 63], 1);
  }
  __syncthreads();
  if (tid == 0){
    int acc = 0;
    for (int dl = 0; dl < 64; ++dl){
      off64[dl] = acc; cur64[dl] = acc; acc += cnt64[dl];
    }
  }
  __syncthreads();
  int nd = min(64, N_NODES - g*64);
  if (tid < nd)
    rowb[g*64 + tid] = make_int2(cb + off64[tid], cb + off64[tid] + cnt64[tid]);
  for (int r = tid; r < n; r += 256){
    uint2 rc = recs[r];
    int dl = (rc.x >> 16) & 63;
    int p = atomicAdd(&cur64[dl], 1);
    finb[cb + p] = (rc.y & 0xFFFF0000u) | (rc.x & 0xFFFFu);
  }
}

// ---------- layer 1: K=7 scalar GEMM + att dots, bf16 out, both branches ----------
template<int K, int F>
__global__ __launch_bounds__(256) void node_linear1_kernel(
    const float* __restrict__ x0, const float* __restrict__ x1,
    const float* __restrict__ W,
    const float* __restrict__ atts, const float* __restrict__ attd,
    unsigned short* __restrict__ hbAll, float* __restrict__ aSAll, float* __restrict__ aDAll)
{
  int b = blockIdx.y;
  const float* x = b ? x1 : x0;
  unsigned short* hb = hbAll + (size_t)b*N_NODES*128;
  float* a_s = aSAll + b*N_NODES;
  float* a_d = aDAll + b*N_NODES;
  constexpr int ROWS = 256 / F; // 2
  __shared__ float Wl[K*F];
  __shared__ float xl[ROWS*K];
  __shared__ float swv[4], dwv[4];
  int tid = threadIdx.x;
  for (int i = tid; i < K*F; i += 256) Wl[i] = W[i];
  int f = tid % F;
  int lr = tid / F;
  float vs = atts[f], vd = attd[f];
  const int ntiles = (N_NODES + ROWS - 1)/ROWS;
  for (int t = blockIdx.x; t < ntiles; t += gridDim.x){
    int r0 = t*ROWS;
    __syncthreads();
    for (int i = tid; i < ROWS*K; i += 256){
      int r = i / K, k = i % K;
      int row = r0 + r;
      xl[i] = (row < N_NODES) ? x[row*K + k] : 0.f;
    }
    __syncthreads();
    float acc = 0.f;
    #pragma unroll
    for (int k = 0; k < K; ++k) acc += xl[lr*K + k] * Wl[k*F + f];
    int row = r0 + lr;
    if (row < N_NODES) hb[row*F + f] = f2bf(acc);
    float s = acc*vs, d = acc*vd;
    #pragma unroll
    for (int o = 32; o; o >>= 1){ s += __shfl_down(s, o); d += __shfl_down(d, o); }
    int wv = tid >> 6;
    if ((tid & 63) == 0){ swv[wv] = s; dwv[wv] = d; }
    __syncthreads();
    if (f == 0 && row < N_NODES){
      a_s[row] = swv[2*lr] + swv[2*lr+1];
      a_d[row] = dwv[2*lr] + dwv[2*lr+1];
    }
  }
}

// ---------- layers 2/3: MFMA GEMM (A bf16 -> bf16 out), fused att dots ----------
template<int F>
__global__ __launch_bounds__(256) void gemm_mfma_kernel(
    const unsigned short* __restrict__ AAll, const float* __restrict__ W,
    const float* __restrict__ atts, const float* __restrict__ attd,
    unsigned short* __restrict__ hbAll, float* __restrict__ aSAll, float* __restrict__ aDAll)
{
  int b = blockIdx.y;
  const unsigned short* A = AAll + (size_t)b*N_NODES*128;
  unsigned short* hb = hbAll + (size_t)b*N_NODES*128;
  float* a_s = aSAll + b*N_NODES;
  float* a_d = aDAll + b*N_NODES;
  constexpr int NT = F/16;
  constexpr int KP = 136;
  __shared__ unsigned short Wb[F*KP];
  int tid = threadIdx.x;
  for (int idx = tid; idx < 128*F; idx += 256){
    int k = idx / F, col = idx % F;
    Wb[col*KP + k] = f2bf(W[idx]);
  }
  __syncthreads();
  int wave = tid >> 6, lane = tid & 63;
  int r0w = blockIdx.x*64 + wave*16;
  int arow = r0w + (lane & 15);
  bool av = arow < N_NODES;
  f32x4 acc[NT];
  #pragma unroll
  for (int nt = 0; nt < NT; ++nt) acc[nt] = 0.f;
  #pragma unroll
  for (int step = 0; step < 4; ++step){
    int kbase = step*32 + (lane>>4)*8;
    uint4 araw = av ? *reinterpret_cast<const uint4*>(&A[(size_t)arow*128 + kbase])
                    : make_uint4(0,0,0,0);
    bf16v af = __builtin_bit_cast(bf16v, araw);
    #pragma unroll
    for (int nt = 0; nt < NT; ++nt){
      uint4 braw = *reinterpret_cast<const uint4*>(&Wb[(nt*16 + (lane&15))*KP + kbase]);
      bf16v bfr = __builtin_bit_cast(bf16v, braw);
      acc[nt] = __builtin_amdgcn_mfma_f32_16x16x32_bf16(af, bfr, acc[nt], 0, 0, 0);
    }
  }
  float ps[4] = {0,0,0,0}, pd[4] = {0,0,0,0};
  #pragma unroll
  for (int nt = 0; nt < NT; ++nt){
    int col = nt*16 + (lane&15);
    float vs = atts[col], vd = attd[col];
    #pragma unroll
    for (int reg = 0; reg < 4; ++reg){
      int row = r0w + (lane>>4)*4 + reg;
      float v = acc[nt][reg];
      if (row < N_NODES) hb[(size_t)row*F + col] = f2bf(v);
      ps[reg] += v*vs;
      pd[reg] += v*vd;
    }
  }
  #pragma unroll
  for (int reg = 0; reg < 4; ++reg){
    float s = ps[reg], d = pd[reg];
    #pragma unroll
    for (int o = 1; o < 16; o <<= 1){ s += __shfl_xor(s, o); d += __shfl_xor(d, o); }
    int row = r0w + (lane>>4)*4 + reg;
    if ((lane & 15) == 0 && row < N_NODES){ a_s[row] = s; a_d[row] = d; }
  }
}

// ---------- aggregation v7: 2 dsts/wave, edge-record prefetch, bf16 out ----------
// grid: 1-D, 2*(N_NODES/8) blocks; branch = bid&1.
template<int F>
__global__ __launch_bounds__(256) void aggregate_kernel(
    const unsigned short* __restrict__ hbAll,
    const float* __restrict__ aSAll, const float* __restrict__ aDAll,
    const unsigned* __restrict__ edgAll, const int2* __restrict__ rowp2All,
    const float* __restrict__ scal, int l,
    const float* __restrict__ bias,
    unsigned short* __restrict__ outbAll)
{
  constexpr int PERL = F/16;   // 8 (F=128) or 4 (F=64)
  constexpr int PERH = PERL/2;
  constexpr int RSH = (F == 128) ? 8 : 7;
  constexpr int SUBB = (F == 128) ? 16 : 8;
  int bid = blockIdx.x;
  int b = bid & 1;
  const unsigned short* hb = hbAll + (size_t)b*N_NODES*128;
  const float* a_s = aSAll + b*N_NODES;
  const float* a_d = aDAll + b*N_NODES;
  const unsigned* edges = edgAll + (size_t)b*STAGEN;
  const int2* rowp2 = rowp2All + (size_t)b*N_NODES;
  __shared__ uint2 sp[4][64];
  int wv = threadIdx.x >> 6;
  int lane = threadIdx.x & 63;
  int half = lane >> 5;        // 0 = dstA, 1 = dstB
  int hl = lane & 31;
  int d = (bid >> 1)*8 + wv*2 + half;   // 20000 % 8 == 0
  int sub = hl & 15, grp = hl >> 4;
  const char* hb2 = (const char*)hb + sub*SUBB;
  float c = scal[2+l];
  float ae_self = (scal[b] * (1.0f/N_EDGES)) * c;
  float add_ = a_d[d];
  float p_self = __expf(fminf(leaky02(a_s[d] + add_ + ae_self), 60.f));
  float dsum = 0.f;
  f32x2 acc[PERH];
  #pragma unroll
  for (int i = 0; i < PERH; ++i) acc[i] = (f32x2){0.f, 0.f};
  if (grp == 0){
    f32x2 pself2 = {p_self, p_self};
    if (PERL == 8){
      uint4 q = *reinterpret_cast<const uint4*>(hb2 + ((unsigned)d << RSH));
      pkfma(acc[0], (f32x2){bflo(q.x), bfhi(q.x)}, pself2);
      pkfma(acc[1], (f32x2){bflo(q.y), bfhi(q.y)}, pself2);
      pkfma(acc[2], (f32x2){bflo(q.z), bfhi(q.z)}, pself2);
      pkfma(acc[3], (f32x2){bflo(q.w), bfhi(q.w)}, pself2);
    } else {
      uint2 q = *reinterpret_cast<const uint2*>(hb2 + ((unsigned)d << RSH));
      pkfma(acc[0], (f32x2){bflo(q.x), bfhi(q.x)}, pself2);
      pkfma(acc[1], (f32x2){bflo(q.y), bfhi(q.y)}, pself2);
    }
  }
  int2 r2 = rowp2[d];
  int e0 = r2.x, deg = r2.y - r2.x;
  int degmax = max(deg, __shfl_xor(deg, 32));
  const int cap = (int)STAGEN - 1;
  unsigned eRec = edges[min(e0 + hl, cap)];          // prefetch chunk 0
  for (int ch = 0; ch < degmax; ch += 32){
    int n = deg - ch;
    unsigned eNext = edges[min(e0 + ch + 32 + hl, cap)];   // prefetch next chunk early
    unsigned s0 = eRec & 0xFFFFu;
    float aval = a_s[s0];
    unsigned off0 = 0;
    float p0 = 0.f;
    if (hl < n){
      p0 = __expf(fminf(leaky02(aval + add_ + c*bfhi(eRec)), 60.f));
      off0 = s0 << RSH;
    }
    dsum += p0;
    sp[wv][lane] = make_uint2(off0, __float_as_uint(p0));
    int nmax = min(32, degmax - ch);
    #pragma unroll 4
    for (int e8 = 0; e8 < nmax; e8 += 8){
      int base = half*32 + e8 + grp;
      uint2 r0 = sp[wv][base];
      uint2 r1 = sp[wv][base + 2];
      uint2 rr2 = sp[wv][base + 4];
      uint2 r3 = sp[wv][base + 6];
      f32x2 a0 = {__uint_as_float(r0.y), __uint_as_float(r0.y)};
      f32x2 a1 = {__uint_as_float(r1.y), __uint_as_float(r1.y)};
      f32x2 a2 = {__uint_as_float(rr2.y), __uint_as_float(rr2.y)};
      f32x2 a3 = {__uint_as_float(r3.y), __uint_as_float(r3.y)};
      if (PERL == 8){
        uint4 q0 = *reinterpret_cast<const uint4*>(hb2 + r0.x);
        uint4 q1 = *reinterpret_cast<const uint4*>(hb2 + r1.x);
        uint4 q2 = *reinterpret_cast<const uint4*>(hb2 + rr2.x);
        uint4 q3 = *reinterpret_cast<const uint4*>(hb2 + r3.x);
        pkfma(acc[0], (f32x2){bflo(q0.x), bfhi(q0.x)}, a0);
        pkfma(acc[1], (f32x2){bflo(q0.y), bfhi(q0.y)}, a0);
        pkfma(acc[2], (f32x2){bflo(q0.z), bfhi(q0.z)}, a0);
        pkfma(acc[3], (f32x2){bflo(q0.w), bfhi(q0.w)}, a0);
        pkfma(acc[0], (f32x2){bflo(q1.x), bfhi(q1.x)}, a1);
        pkfma(acc[1], (f32x2){bflo(q1.y), bfhi(q1.y)}, a1);
        pkfma(acc[2], (f32x2){bflo(q1.z), bfhi(q1.z)}, a1);
        pkfma(acc[3], (f32x2){bflo(q1.w), bfhi(q1.w)}, a1);
        pkfma(acc[0], (f32x2){bflo(q2.x), bfhi(q2.x)}, a2);
        pkfma(acc[1], (f32x2){bflo(q2.y), bfhi(q2.y)}, a2);
        pkfma(acc[2], (f32x2){bflo(q2.z), bfhi(q2.z)}, a2);
        pkfma(acc[3], (f32x2){bflo(q2.w), bfhi(q2.w)}, a2);
        pkfma(acc[0], (f32x2){bflo(q3.x), bfhi(q3.x)}, a3);
        pkfma(acc[1], (f32x2){bflo(q3.y), bfhi(q3.y)}, a3);
        pkfma(acc[2], (f32x2){bflo(q3.z), bfhi(q3.z)}, a3);
        pkfma(acc[3], (f32x2){bflo(q3.w), bfhi(q3.w)}, a3);
      } else {
        uint2 q0 = *reinterpret_cast<const uint2*>(hb2 + r0.x);
        uint2 q1 = *reinterpret_cast<const uint2*>(hb2 + r1.x);
        uint2 q2 = *reinterpret_cast<const uint2*>(hb2 + rr2.x);
        uint2 q3 = *reinterpret_cast<const uint2*>(hb2 + r3.x);
        pkfma(acc[0], (f32x2){bflo(q0.x), bfhi(q0.x)}, a0);
        pkfma(acc[1], (f32x2){bflo(q0.y), bfhi(q0.y)}, a0);
        pkfma(acc[0], (f32x2){bflo(q1.x), bfhi(q1.x)}, a1);
        pkfma(acc[1], (f32x2){bflo(q1.y), bfhi(q1.y)}, a1);
        pkfma(acc[0], (f32x2){bflo(q2.x), bfhi(q2.x)}, a2);
        pkfma(acc[1], (f32x2){bflo(q2.y), bfhi(q2.y)}, a2);
        pkfma(acc[0], (f32x2){bflo(q3.x), bfhi(q3.x)}, a3);
        pkfma(acc[1], (f32x2){bflo(q3.y), bfhi(q3.y)}, a3);
      }
    }
    eRec = eNext;
  }
  // denom reduce within 32-lane half
  #pragma unroll
  for (int o = 16; o; o >>= 1) dsum += __shfl_xor(dsum, o);
  float denom = p_self + dsum;
  float inv = 1.0f/denom;
  float vv[PERL];
  #pragma unroll
  for (int i = 0; i < PERH; ++i){
    float v0 = acc[i].x, v1 = acc[i].y;
    v0 += __shfl_xor(v0, 16);
    v1 += __shfl_xor(v1, 16);
    vv[2*i]   = eluf(v0*inv + bias[PERL*sub + 2*i]);
    vv[2*i+1] = eluf(v1*inv + bias[PERL*sub + 2*i+1]);
  }
  if (grp == 0){
    unsigned short* outb = outbAll + (size_t)b*N_NODES*F;
    if (PERL == 8){
      uint4 o;
      o.x = (unsigned int)f2bf(vv[0]) | ((unsigned int)f2bf(vv[1]) << 16);
      o.y = (unsigned int)f2bf(vv[2]) | ((unsigned int)f2bf(vv[3]) << 16);
      o.z = (unsigned int)f2bf(vv[4]) | ((unsigned int)f2bf(vv[5]) << 16);
      o.w = (unsigned int)f2bf(vv[6]) | ((unsigned int)f2bf(vv[7]) << 16);
      *reinterpret_cast<uint4*>(&outb[(size_t)d*F + 8*sub]) = o;
    } else {
      uint2 o;
      o.x = (unsigned int)f2bf(vv[0]) | ((unsigned int)f2bf(vv[1]) << 16);
      o.y = (unsigned int)f2bf(vv[2]) | ((unsigned int)f2bf(vv[3]) << 16);
      *reinterpret_cast<uint2*>(&outb[(size_t)d*F + 4*sub]) = o;
    }
  }
}

// ---------- fused mean-pool (bf16 in) + final linear ----------
__global__ __launch_bounds__(256) void pool_final_kernel(
    const unsigned short* __restrict__ buf, const int* __restrict__ gb,
    const float* __restrict__ xn0, const float* __restrict__ xn1,
    const float* __restrict__ linW, const float* __restrict__ linb,
    float* __restrict__ out)
{
  int bg = blockIdx.x;
  int b = bg >> 8, g = bg & 255;
  __shared__ float Wl[80*64];
  __shared__ float red[4][64];
  __shared__ float mf[64];
  int tid = threadIdx.x;
  for (int i = tid; i < 80*64; i += 256) Wl[i] = linW[i];
  const unsigned short* x = buf + (size_t)b*N_NODES*64;
  const int* gbb = gb + b*257;
  int s = gbb[g], e = gbb[g+1];
  int f = tid & 63, rg = tid >> 6;
  float acc = 0.f;
  for (int r = s + rg; r < e; r += 4) acc += bfs(x[(size_t)r*64 + f]);
  red[rg][f] = acc;
  __syncthreads();
  if (rg == 0)
    mf[f] = (red[0][f]+red[1][f]+red[2][f]+red[3][f]) / fmaxf((float)(e - s), 1.0f);
  __syncthreads();
  if (tid < 64){
    int j = tid;
    const float* xn = b ? xn1 : xn0;
    float a2 = linb[j];
    #pragma unroll 8
    for (int k = 0; k < 64; ++k) a2 += mf[k] * Wl[k*64 + j];
    #pragma unroll
    for (int k = 0; k < 16; ++k) a2 += xn[g*16+k] * Wl[(64+k)*64 + j];
    out[(size_t)(b*N_GRAPHS + g)*64 + j] = a2;
  }
}

extern "C" void kernel_launch(void* const* d_in, const int* in_sizes, int n_in,
                              void* d_out, int out_size, void* d_ws, size_t ws_size,
                              hipStream_t stream)
{
  const float* x1   = (const float*)d_in[0];
  const float* x2   = (const float*)d_in[1];
  const int*   ei1  = (const int*)d_in[2];
  const int*   ei2  = (const int*)d_in[3];
  const int*   bat1 = (const int*)d_in[4];
  const int*   bat2 = (const int*)d_in[5];
  const float* xn1  = (const float*)d_in[6];
  const float* xn2  = (const float*)d_in[7];
  const float* ec1  = (const float*)d_in[8];
  const float* ec2  = (const float*)d_in[9];
  const float* W[3]   = {(const float*)d_in[10], (const float*)d_in[16], (const float*)d_in[22]};
  const float* as_[3] = {(const float*)d_in[11], (const float*)d_in[17], (const float*)d_in[23]};
  const float* ad_[3] = {(const float*)d_in[12], (const float*)d_in[18], (const float*)d_in[24]};
  const float* We[3]  = {(const float*)d_in[13], (const float*)d_in[19], (const float*)d_in[25]};
  const float* ae[3]  = {(const float*)d_in[14], (const float*)d_in[20], (const float*)d_in[26]};
  const float* bb[3]  = {(const float*)d_in[15], (const float*)d_in[21], (const float*)d_in[27]};
  const float* linW = (const float*)d_in[28];
  const float* linb = (const float*)d_in[29];
  float* out = (float*)d_out;

  char* ws = (char*)d_ws;
  size_t off = 0;
  auto alloc = [&](size_t bytes)->char*{
    char* p = ws + off;
    off = (off + bytes + 255) & ~(size_t)255;
    return p;
  };
  unsigned short* hbA = (unsigned short*)alloc((size_t)2*N_NODES*128*2);
  unsigned short* hbB = (unsigned short*)alloc((size_t)2*N_NODES*128*2);
  float* aS   = (float*)alloc((size_t)2*N_NODES*4);
  float* aD   = (float*)alloc((size_t)2*N_NODES*4);
  int* bcur   = (int*)alloc((size_t)2*NBUCK*CURP*4);
  int2* rowp2 = (int2*)alloc((size_t)2*N_NODES*8);
  uint2* stage = (uint2*)alloc((size_t)2*STAGEN*8);
  unsigned* final_ = (unsigned*)alloc((size_t)2*STAGEN*4);
  float* part = (float*)alloc((size_t)2*NC*4);
  int* gb     = (int*)alloc((size_t)2*257*4);
  float* scal = (float*)alloc(64);

  setup_kernel<<<2, 512, 0, stream>>>(bat1, bat2,
      We[0], ae[0], We[1], ae[1], We[2], ae[2], bcur, gb, scal);
  binC_kernel<<<dim3(NC,2), 256, 0, stream>>>(ei1, ei2, ec1, ec2, bcur, stage, part);
  binD_kernel<<<dim3(NBUCK,2), 256, 0, stream>>>(stage, bcur, part, final_, rowp2, scal);

  const int AGG = 2*(N_NODES/8);  // 5000 blocks, branch = bid&1

  // layer 1: K=7 -> F=128
  node_linear1_kernel<7,128><<<dim3(1024,2), 256, 0, stream>>>(
      x1, x2, W[0], as_[0], ad_[0], hbA, aS, aD);
  aggregate_kernel<128><<<AGG, 256, 0, stream>>>(
      hbA, aS, aD, final_, rowp2, scal, 0, bb[0], hbB);

  // layer 2: MFMA 128->128
  gemm_mfma_kernel<128><<<dim3((N_NODES+63)/64,2), 256, 0, stream>>>(
      hbB, W[1], as_[1], ad_[1], hbA, aS, aD);
  aggregate_kernel<128><<<AGG, 256, 0, stream>>>(
      hbA, aS, aD, final_, rowp2, scal, 1, bb[1], hbB);

  // layer 3: MFMA 128->64
  gemm_mfma_kernel<64><<<dim3((N_NODES+63)/64,2), 256, 0, stream>>>(
      hbB, W[2], as_[2], ad_[2], hbA, aS, aD);
  aggregate_kernel<64><<<AGG, 256, 0, stream>>>(
      hbA, aS, aD, final_, rowp2, scal, 2, bb[2], hbB);

  pool_final_kernel<<<2*N_GRAPHS, 256, 0, stream>>>(
      hbB, gb, xn1, xn2, linW, linb, out);
}